// Round 1
// baseline (755.636 us; speedup 1.0000x reference)
//
#include <hip/hip_runtime.h>
#include <cmath>

// ============================================================================
// SpatialContextSet fused kernel for MI355X (gfx950).
// Design: one workgroup (256 thr = 4 waves) per batch element b.
//   wave w owns output columns [64w, 64w+64) for every 256-wide GEMM
//   => wave w == attention head w (DH=64), logits/z reductions stay in-wave.
// Chain per b (all in LDS, bf16 MFMA 16x16x32):
//   h0 = h_dyn@W_dyn+b  -> LN -> q = @Wq+b            (M=1 padded tiles)
//   s  = x_stat@W_stat+b -> LN (in buf)
//   k-stage: s@Wk, logits computed inline in epilogue (k never stored;
//            bias via precomputed bk.q), sigmoid-normalized weights online
//   v-stage: s@Wv+b written IN-PLACE over buf (s dead after)
//   LN -> t1 = gelu(@W1+b) in-place -> vtok-stage: @W2, z accumulated in regs
//   c = z@Wo: M=1 tile; out = h0 + rs*(c+bo);  w_mean = mean_h w.
// Weights pre-converted to bf16, TRANSPOSED [n][k] by prep kernel so B-frags
// are contiguous 16B loads; per-stage B-frags register-cached (128 VGPRs),
// each weight read once per WG.
// ============================================================================

typedef __bf16 bf16;
typedef bf16 bf16x8 __attribute__((ext_vector_type(8)));
typedef float f32x4 __attribute__((ext_vector_type(4)));

#define MFMA_B16(a, b, c) __builtin_amdgcn_mfma_f32_16x16x32_bf16((a), (b), (c), 0, 0, 0)

constexpr int SROW = 264;  // buf row stride (bf16): 256 + 8 pad -> 528B = 33*16B aligned
constexpr int XROW = 72;   // x_stat tile row stride: 64 + 8 pad -> 144B aligned

__device__ __forceinline__ bf16x8 zero8() {
  bf16x8 z;
#pragma unroll
  for (int j = 0; j < 8; ++j) z[j] = (bf16)0.0f;
  return z;
}

__device__ __forceinline__ float wave_sum(float v) {
#pragma unroll
  for (int m = 1; m < 64; m <<= 1) v += __shfl_xor(v, m, 64);
  return v;
}

// load B-fragments for a K=256 stage: bw[ks][nt], weight is [256 n][256 k] bf16
__device__ __forceinline__ void load_bfrags(const bf16* __restrict__ Wt, int w, int l16,
                                            int koff, bf16x8 (&bw)[8][4]) {
#pragma unroll
  for (int ks = 0; ks < 8; ++ks)
#pragma unroll
    for (int nt = 0; nt < 4; ++nt)
      bw[ks][nt] = *(const bf16x8*)(Wt + (size_t)(w * 64 + nt * 16 + l16) * 256 + ks * 32 + koff);
}

__device__ __forceinline__ void load_afrags(const bf16* __restrict__ buf, int row, int koff,
                                            bf16x8 (&a)[8]) {
#pragma unroll
  for (int ks = 0; ks < 8; ++ks)
    a[ks] = *(const bf16x8*)(buf + row * SROW + ks * 32 + koff);
}

__device__ __forceinline__ void mm256(const bf16x8 (&a)[8], const bf16x8 (&bw)[8][4],
                                      f32x4 (&acc)[4]) {
#pragma unroll
  for (int ks = 0; ks < 8; ++ks)
#pragma unroll
    for (int nt = 0; nt < 4; ++nt)
      acc[nt] = MFMA_B16(a[ks], bw[ks][nt], acc[nt]);
}

// rowwise LayerNorm in-place over buf rows 0..63 (256 cols), wave w does rows w+4i
__device__ __forceinline__ void ln_rows_inplace(bf16* buf, const float* __restrict__ g,
                                                const float* __restrict__ bsh, int w, int lane) {
  float gn[4], bn[4];
#pragma unroll
  for (int j = 0; j < 4; ++j) { gn[j] = g[lane + 64 * j]; bn[j] = bsh[lane + 64 * j]; }
  for (int i = 0; i < 16; ++i) {
    int row = 4 * i + w;
    bf16* rp = buf + row * SROW;
    float x[4]; float s = 0.f, ss = 0.f;
#pragma unroll
    for (int j = 0; j < 4; ++j) { x[j] = (float)rp[lane + 64 * j]; s += x[j]; ss += x[j] * x[j]; }
    s = wave_sum(s); ss = wave_sum(ss);
    float mean = s * (1.f / 256.f);
    float var = ss * (1.f / 256.f) - mean * mean;
    float rstd = 1.f / sqrtf(var + 1e-5f);
#pragma unroll
    for (int j = 0; j < 4; ++j) rp[lane + 64 * j] = (bf16)((x[j] - mean) * rstd * gn[j] + bn[j]);
  }
}

// ---------------------------------------------------------------------------
// prep: convert + transpose all weights to bf16 [n][k] into workspace
// layout (bf16 elems): Wdyn_t[256][512] @0, Wstat_t[256][64] @131072,
// then Wq,Wk,Wv,W1,W2,Wo each [256][256] (65536) starting @147456.
// ---------------------------------------------------------------------------
__global__ void prep_kernel(const float* __restrict__ Wdyn, const float* __restrict__ Wstat,
                            const float* __restrict__ Wq, const float* __restrict__ Wk,
                            const float* __restrict__ Wv, const float* __restrict__ W1,
                            const float* __restrict__ W2, const float* __restrict__ Wo,
                            bf16* __restrict__ ws) {
  int i = blockIdx.x * 256 + threadIdx.x;
  if (i < 131072) {
    int n = i >> 9, k = i & 511;
    ws[i] = (bf16)Wdyn[k * 256 + n];
  } else if (i < 147456) {
    int j = i - 131072; int n = j >> 6, k = j & 63;
    ws[i] = (bf16)Wstat[k * 256 + n];
  } else {
    int j = i - 147456; int m = j >> 16; int r = j & 65535;
    int n = r >> 8, k = r & 255;
    const float* s = (m == 0) ? Wq : (m == 1) ? Wk : (m == 2) ? Wv
                   : (m == 3) ? W1 : (m == 4) ? W2 : Wo;
    ws[i] = (bf16)s[k * 256 + n];
  }
}

// ---------------------------------------------------------------------------
// fused main kernel: grid 4096, block 256
// ---------------------------------------------------------------------------
__launch_bounds__(256, 2)
__global__ void fused_kernel(
    const float* __restrict__ h_dyn, const float* __restrict__ x_stat,
    const float* __restrict__ b_dyn, const float* __restrict__ b_stat,
    const float* __restrict__ g_ndyn, const float* __restrict__ b_ndyn,
    const float* __restrict__ g_nstat, const float* __restrict__ b_nstat,
    const float* __restrict__ bq, const float* __restrict__ bk, const float* __restrict__ bv,
    const float* __restrict__ g_mlp, const float* __restrict__ b_mlp,
    const float* __restrict__ b1, const float* __restrict__ b2, const float* __restrict__ bo,
    const float* __restrict__ res_scale_p,
    const bf16* __restrict__ Wdyn_t, const bf16* __restrict__ Wstat_t,
    const bf16* __restrict__ Wq_t, const bf16* __restrict__ Wk_t,
    const bf16* __restrict__ Wv_t, const bf16* __restrict__ W1_t,
    const bf16* __restrict__ W2_t, const bf16* __restrict__ Wo_t,
    float* __restrict__ out_c, float* __restrict__ out_wm) {

  __shared__ bf16 buf[64 * SROW];     // 33792 B: s_ln -> (in-place) v -> t_ln -> t1
  __shared__ bf16 xs[64 * XROW];      // 9216 B: x_stat tile bf16
  __shared__ bf16 hd[512];            // h_dyn row bf16
  __shared__ bf16 hln[256];           // LN(h0) bf16
  __shared__ float h0s[256];          // h0 f32 (residual)
  __shared__ float qs[256];           // q f32
  __shared__ float zs[256];           // z f32
  __shared__ float logit_s[4][64];    // raw q.k dots (no bias, no scale)
  __shared__ float watt[4][64];       // normalized attention weights
  __shared__ float bkq_s[4];          // bk . q per head
  __shared__ float swh[4];            // sum_t w[h][t]

  const int b = blockIdx.x;
  const int tid = threadIdx.x;
  const int w = tid >> 6;       // wave == head
  const int lane = tid & 63;
  const int quad = lane >> 4;
  const int l16 = lane & 15;
  const int koff = quad * 8;    // k offset within a 32-wide k-step

  // ---- phase 0: stage h_dyn row + x_stat tile as bf16 ----
  {
    const float* hr = h_dyn + (size_t)b * 512;
    hd[tid] = (bf16)hr[tid];
    hd[tid + 256] = (bf16)hr[tid + 256];
    const float* xr = x_stat + (size_t)b * 4096;
#pragma unroll
    for (int i = 0; i < 16; ++i) {
      int idx = i * 256 + tid;
      xs[(idx >> 6) * XROW + (idx & 63)] = (bf16)xr[idx];
    }
  }
  __syncthreads();

  // ---- phase 1: h0 = h_dyn @ W_dyn + b_dyn  (M=1 padded to 16, K=512) ----
  {
    f32x4 acc[4];
#pragma unroll
    for (int nt = 0; nt < 4; ++nt) { f32x4 z = {0.f, 0.f, 0.f, 0.f}; acc[nt] = z; }
#pragma unroll
    for (int ks = 0; ks < 16; ++ks) {
      bf16x8 a = zero8();
      if (l16 == 0) a = *(const bf16x8*)(hd + ks * 32 + koff);
#pragma unroll
      for (int nt = 0; nt < 4; ++nt) {
        const bf16* bp = Wdyn_t + (size_t)(w * 64 + nt * 16 + l16) * 512 + ks * 32 + koff;
        acc[nt] = MFMA_B16(a, *(const bf16x8*)bp, acc[nt]);
      }
    }
    if (quad == 0) {
#pragma unroll
      for (int nt = 0; nt < 4; ++nt) {
        int col = w * 64 + nt * 16 + l16;
        h0s[col] = acc[nt][0] + b_dyn[col];
      }
    }
  }
  __syncthreads();

  // ---- phase 2: h_ln = LN(h0) (all waves compute stats redundantly) ----
  {
    float s = 0.f, ss = 0.f;
#pragma unroll
    for (int j = 0; j < 4; ++j) { float x = h0s[lane + 64 * j]; s += x; ss += x * x; }
    s = wave_sum(s); ss = wave_sum(ss);
    float mean = s * (1.f / 256.f);
    float var = ss * (1.f / 256.f) - mean * mean;
    float rstd = 1.f / sqrtf(var + 1e-5f);
    int c = w * 64 + lane;
    hln[c] = (bf16)((h0s[c] - mean) * rstd * g_ndyn[c] + b_ndyn[c]);
  }
  __syncthreads();

  // ---- phase 3: q = h_ln @ Wq + bq (M=1 padded, K=256) ----
  {
    f32x4 acc[4];
#pragma unroll
    for (int nt = 0; nt < 4; ++nt) { f32x4 z = {0.f, 0.f, 0.f, 0.f}; acc[nt] = z; }
#pragma unroll
    for (int ks = 0; ks < 8; ++ks) {
      bf16x8 a = zero8();
      if (l16 == 0) a = *(const bf16x8*)(hln + ks * 32 + koff);
#pragma unroll
      for (int nt = 0; nt < 4; ++nt) {
        const bf16* bp = Wq_t + (size_t)(w * 64 + nt * 16 + l16) * 256 + ks * 32 + koff;
        acc[nt] = MFMA_B16(a, *(const bf16x8*)bp, acc[nt]);
      }
    }
    if (quad == 0) {
#pragma unroll
      for (int nt = 0; nt < 4; ++nt) {
        int col = w * 64 + nt * 16 + l16;
        qs[col] = acc[nt][0] + bq[col];
      }
    }
  }
  __syncthreads();

  // ---- phase 3b: bkq[h] = bk . q over head h's 64 dims ----
  {
    float v = qs[w * 64 + lane] * bk[w * 64 + lane];
    v = wave_sum(v);
    if (lane == 0) bkq_s[w] = v;
  }
  // (bkq read only after later barriers)

  // ---- phase 4: s = x_stat @ W_stat + b_stat -> buf (K=64) ----
  {
    bf16x8 bw[2][4];
#pragma unroll
    for (int ks = 0; ks < 2; ++ks)
#pragma unroll
      for (int nt = 0; nt < 4; ++nt)
        bw[ks][nt] = *(const bf16x8*)(Wstat_t + (size_t)(w * 64 + nt * 16 + l16) * 64 + ks * 32 + koff);
    float bias[4];
#pragma unroll
    for (int nt = 0; nt < 4; ++nt) bias[nt] = b_stat[w * 64 + nt * 16 + l16];
#pragma unroll
    for (int mt = 0; mt < 4; ++mt) {
      bf16x8 a[2];
      a[0] = *(const bf16x8*)(xs + (mt * 16 + l16) * XROW + koff);
      a[1] = *(const bf16x8*)(xs + (mt * 16 + l16) * XROW + 32 + koff);
      f32x4 acc[4];
#pragma unroll
      for (int nt = 0; nt < 4; ++nt) { f32x4 z = {0.f, 0.f, 0.f, 0.f}; acc[nt] = z; }
#pragma unroll
      for (int ks = 0; ks < 2; ++ks)
#pragma unroll
        for (int nt = 0; nt < 4; ++nt) acc[nt] = MFMA_B16(a[ks], bw[ks][nt], acc[nt]);
#pragma unroll
      for (int nt = 0; nt < 4; ++nt)
#pragma unroll
        for (int r = 0; r < 4; ++r)
          buf[(mt * 16 + quad * 4 + r) * SROW + w * 64 + nt * 16 + l16] =
              (bf16)(acc[nt][r] + bias[nt]);
    }
  }
  __syncthreads();

  // ---- phase 5: s_ln = LN(s) in-place ----
  ln_rows_inplace(buf, g_nstat, b_nstat, w, lane);
  __syncthreads();

  // ---- phase 6: k-stage: k = s_ln @ Wk (+bk folded into bkq); logits inline ----
  {
    bf16x8 bw[8][4];
    load_bfrags(Wk_t, w, l16, koff, bw);
    float qv[4];
#pragma unroll
    for (int nt = 0; nt < 4; ++nt) qv[nt] = qs[w * 64 + nt * 16 + l16];
#pragma unroll
    for (int mt = 0; mt < 4; ++mt) {
      bf16x8 a[8];
      load_afrags(buf, mt * 16 + l16, koff, a);
      f32x4 acc[4];
#pragma unroll
      for (int nt = 0; nt < 4; ++nt) { f32x4 z = {0.f, 0.f, 0.f, 0.f}; acc[nt] = z; }
      mm256(a, bw, acc);
#pragma unroll
      for (int r = 0; r < 4; ++r) {
        float p = acc[0][r] * qv[0] + acc[1][r] * qv[1] + acc[2][r] * qv[2] + acc[3][r] * qv[3];
        p += __shfl_xor(p, 1, 64);
        p += __shfl_xor(p, 2, 64);
        p += __shfl_xor(p, 4, 64);
        p += __shfl_xor(p, 8, 64);
        if (l16 == 0) logit_s[w][mt * 16 + quad * 4 + r] = p;
      }
    }
  }
  __syncthreads();

  // ---- phase 7: attention weights (sigmoid, online normalization) ----
  {
    float raw = logit_s[w][lane];
    float lg = (raw + bkq_s[w]) * 0.125f;    // SCALE = dh^-0.5 = 1/8
    float sig = 1.f / (1.f + expf(-lg));
    float den = wave_sum(sig);
    float dinv = 1.f / (den + 1e-6f);
    watt[w][lane] = sig * dinv;
    if (lane == 0) swh[w] = den * dinv;      // sum_t w[h][t]
  }
  __syncthreads();
  if (tid < 64) {
    out_wm[(size_t)b * 64 + tid] =
        0.25f * (watt[0][tid] + watt[1][tid] + watt[2][tid] + watt[3][tid]);
  }

  // ---- phase 8: v = s_ln @ Wv + bv, written IN-PLACE over buf ----
  {
    bf16x8 bw[8][4];
    load_bfrags(Wv_t, w, l16, koff, bw);
    float bias[4];
#pragma unroll
    for (int nt = 0; nt < 4; ++nt) bias[nt] = bv[w * 64 + nt * 16 + l16];
#pragma unroll
    for (int mt = 0; mt < 4; ++mt) {
      bf16x8 a[8];
      load_afrags(buf, mt * 16 + l16, koff, a);
      __syncthreads();   // all waves finished reading tile mt before overwrite
      f32x4 acc[4];
#pragma unroll
      for (int nt = 0; nt < 4; ++nt) { f32x4 z = {0.f, 0.f, 0.f, 0.f}; acc[nt] = z; }
      mm256(a, bw, acc);
#pragma unroll
      for (int nt = 0; nt < 4; ++nt)
#pragma unroll
        for (int r = 0; r < 4; ++r)
          buf[(mt * 16 + quad * 4 + r) * SROW + w * 64 + nt * 16 + l16] =
              (bf16)(acc[nt][r] + bias[nt]);
    }
  }
  __syncthreads();

  // ---- phase 9: t_ln = LN(v) in-place (g_mlp, b_mlp) ----
  ln_rows_inplace(buf, g_mlp, b_mlp, w, lane);
  __syncthreads();

  // ---- phase 10: t1 = gelu(t_ln @ W1 + b1), in-place ----
  {
    bf16x8 bw[8][4];
    load_bfrags(W1_t, w, l16, koff, bw);
    float bias[4];
#pragma unroll
    for (int nt = 0; nt < 4; ++nt) bias[nt] = b1[w * 64 + nt * 16 + l16];
#pragma unroll
    for (int mt = 0; mt < 4; ++mt) {
      bf16x8 a[8];
      load_afrags(buf, mt * 16 + l16, koff, a);
      __syncthreads();
      f32x4 acc[4];
#pragma unroll
      for (int nt = 0; nt < 4; ++nt) { f32x4 z = {0.f, 0.f, 0.f, 0.f}; acc[nt] = z; }
      mm256(a, bw, acc);
#pragma unroll
      for (int nt = 0; nt < 4; ++nt)
#pragma unroll
        for (int r = 0; r < 4; ++r) {
          float x = acc[nt][r] + bias[nt];
          float g = 0.5f * x * (1.f + erff(x * 0.70710678118654752f));  // exact gelu
          buf[(mt * 16 + quad * 4 + r) * SROW + w * 64 + nt * 16 + l16] = (bf16)g;
        }
    }
  }
  __syncthreads();

  // ---- phase 11: v_tok = t1 @ W2 (+b2 via swh); z accumulated in registers ----
  {
    bf16x8 bw[8][4];
    load_bfrags(W2_t, w, l16, koff, bw);
    float b2n[4];
#pragma unroll
    for (int nt = 0; nt < 4; ++nt) b2n[nt] = b2[w * 64 + nt * 16 + l16];
    float zacc[4] = {0.f, 0.f, 0.f, 0.f};
#pragma unroll
    for (int mt = 0; mt < 4; ++mt) {
      bf16x8 a[8];
      load_afrags(buf, mt * 16 + l16, koff, a);
      f32x4 acc[4];
#pragma unroll
      for (int nt = 0; nt < 4; ++nt) { f32x4 z = {0.f, 0.f, 0.f, 0.f}; acc[nt] = z; }
      mm256(a, bw, acc);
#pragma unroll
      for (int r = 0; r < 4; ++r) {
        float wt = watt[w][mt * 16 + quad * 4 + r];
#pragma unroll
        for (int nt = 0; nt < 4; ++nt) zacc[nt] += wt * acc[nt][r];
      }
    }
#pragma unroll
    for (int nt = 0; nt < 4; ++nt) {
      zacc[nt] += __shfl_xor(zacc[nt], 16, 64);
      zacc[nt] += __shfl_xor(zacc[nt], 32, 64);
    }
    if (quad == 0) {
#pragma unroll
      for (int nt = 0; nt < 4; ++nt) {
        int col = w * 64 + nt * 16 + l16;
        zs[col] = zacc[nt] + b2n[nt] * swh[w];   // Σ_t w*(v+b2) = Σ w*v + b2*Σw
      }
    }
  }
  __syncthreads();

  // ---- phase 12: c = h0 + rs*(z @ Wo + bo) (M=1 padded, K=256) ----
  {
    float rs = *res_scale_p;
    f32x4 acc[4];
#pragma unroll
    for (int nt = 0; nt < 4; ++nt) { f32x4 z = {0.f, 0.f, 0.f, 0.f}; acc[nt] = z; }
#pragma unroll
    for (int ks = 0; ks < 8; ++ks) {
      bf16x8 a = zero8();
      if (l16 == 0) {
#pragma unroll
        for (int j = 0; j < 8; ++j) a[j] = (bf16)zs[ks * 32 + koff + j];
      }
#pragma unroll
      for (int nt = 0; nt < 4; ++nt) {
        const bf16* bp = Wo_t + (size_t)(w * 64 + nt * 16 + l16) * 256 + ks * 32 + koff;
        acc[nt] = MFMA_B16(a, *(const bf16x8*)bp, acc[nt]);
      }
    }
    if (quad == 0) {
#pragma unroll
      for (int nt = 0; nt < 4; ++nt) {
        int col = w * 64 + nt * 16 + l16;
        out_c[(size_t)b * 256 + col] = h0s[col] + rs * (acc[nt][0] + bo[col]);
      }
    }
  }
}

extern "C" void kernel_launch(void* const* d_in, const int* in_sizes, int n_in,
                              void* d_out, int out_size, void* d_ws, size_t ws_size,
                              hipStream_t stream) {
  const float* h_dyn   = (const float*)d_in[0];
  const float* x_stat  = (const float*)d_in[1];
  const float* W_dyn   = (const float*)d_in[2];
  const float* b_dyn   = (const float*)d_in[3];
  const float* W_stat  = (const float*)d_in[4];
  const float* b_stat  = (const float*)d_in[5];
  const float* g_ndyn  = (const float*)d_in[6];
  const float* b_ndyn  = (const float*)d_in[7];
  const float* g_nstat = (const float*)d_in[8];
  const float* b_nstat = (const float*)d_in[9];
  const float* Wq = (const float*)d_in[10];
  const float* bq = (const float*)d_in[11];
  const float* Wk = (const float*)d_in[12];
  const float* bk = (const float*)d_in[13];
  const float* Wv = (const float*)d_in[14];
  const float* bv = (const float*)d_in[15];
  const float* g_mlp = (const float*)d_in[16];
  const float* b_mlp = (const float*)d_in[17];
  const float* W1 = (const float*)d_in[18];
  const float* b1 = (const float*)d_in[19];
  const float* W2 = (const float*)d_in[20];
  const float* b2 = (const float*)d_in[21];
  const float* Wo = (const float*)d_in[22];
  const float* bo = (const float*)d_in[23];
  const float* rs = (const float*)d_in[24];

  bf16* ws = (bf16*)d_ws;
  // total bf16 elems: 131072 + 16384 + 6*65536 = 540672 -> 2112 blocks of 256
  prep_kernel<<<2112, 256, 0, stream>>>(W_dyn, W_stat, Wq, Wk, Wv, W1, W2, Wo, ws);

  float* out_c = (float*)d_out;
  float* out_wm = out_c + (size_t)4096 * 256;
  fused_kernel<<<4096, 256, 0, stream>>>(
      h_dyn, x_stat, b_dyn, b_stat, g_ndyn, b_ndyn, g_nstat, b_nstat,
      bq, bk, bv, g_mlp, b_mlp, b1, b2, bo, rs,
      ws, ws + 131072, ws + 147456, ws + 212992, ws + 278528,
      ws + 344064, ws + 409600, ws + 475136,
      out_c, out_wm);
}

// Round 2
// 483.530 us; speedup vs baseline: 1.5627x; 1.5627x over previous
//
#include <hip/hip_runtime.h>
#include <cmath>

// ============================================================================
// SpatialContextSet — round 2.
// Split into 4 kernels on one stream:
//   prep : tiled-transpose all weights fp32[k][n] -> bf16 [n][k] in ws
//   pre  : batched M=4096 GEMMs: h0 = h_dyn@Wdyn+b ; hln = LN(h0); q = hln@Wq+b
//          (removes the per-WG M=1 phases + their 384KB/WG weight reads)
//   fused: per-batch WG (grid 4096): s -> LN -> k-logits -> sigmoid-attn ->
//          v(in-place) -> LN -> gelu-t1(in-place) -> z ; writes z bf16 + w_mean
//          Stages are ks-OUTER: bw[4] live one k-step (loaded ONCE per WG),
//          acc[4mt][4nt] persistent (64 VGPR). LDS ~37KB -> 4 blocks/CU.
//   post : c = h0 + rs*(z@Wo+bo), batched M=4096 GEMM.
// ============================================================================

typedef __bf16 bf16;
typedef bf16 bf16x8 __attribute__((ext_vector_type(8)));
typedef float f32x4 __attribute__((ext_vector_type(4)));

#define MFMA_B16(a, b, c) __builtin_amdgcn_mfma_f32_16x16x32_bf16((a), (b), (c), 0, 0, 0)

constexpr int SROW = 264;  // buf row stride bf16: 528B = 33*16B (aligned, odd*16 for banks)

// ---- workspace layout ----
// bf16 element offsets:
constexpr size_t WDYN_T  = 0;        // [256][512]
constexpr size_t WSTAT_T = 131072;   // [256][64]
constexpr size_t WQ_T    = 147456;   // [256][256]
constexpr size_t WK_T    = 212992;
constexpr size_t WV_T    = 278528;
constexpr size_t W1_T    = 344064;
constexpr size_t W2_T    = 409600;
constexpr size_t WO_T    = 475136;   // ends 540672 bf16 = 1081344 B
// float element offsets (from (float*)ws):
constexpr size_t H0_F = 270336;      // [4096][256] f32
constexpr size_t Q_F  = 1318912;     // [4096][256] f32
// bf16 element offset for z:
constexpr size_t Z_BF = 4734976;     // [4096][256] bf16   (total ws ~11.1 MB)

__device__ __forceinline__ float wave_sum(float v) {
#pragma unroll
  for (int m = 1; m < 64; m <<= 1) v += __shfl_xor(v, m, 64);
  return v;
}

__device__ __forceinline__ void zero_acc(f32x4 (&acc)[4][4]) {
#pragma unroll
  for (int mt = 0; mt < 4; ++mt)
#pragma unroll
    for (int nt = 0; nt < 4; ++nt) { f32x4 z = {0.f, 0.f, 0.f, 0.f}; acc[mt][nt] = z; }
}

// K=256 GEMM stage reading A from LDS buf rows [0,64), B from transposed weight.
// ks-outer: bw[4] short-lived (one load each per WG), acc persistent.
__device__ __forceinline__ void gemm_stage(const bf16* buf, const bf16* __restrict__ Wt,
                                           int w, int l16, int koff, f32x4 (&acc)[4][4]) {
  for (int ks = 0; ks < 8; ++ks) {
    bf16x8 bwv[4];
#pragma unroll
    for (int nt = 0; nt < 4; ++nt)
      bwv[nt] = *(const bf16x8*)(Wt + (size_t)(w * 64 + nt * 16 + l16) * 256 + ks * 32 + koff);
#pragma unroll
    for (int mt = 0; mt < 4; ++mt) {
      bf16x8 a = *(const bf16x8*)(buf + (mt * 16 + l16) * SROW + ks * 32 + koff);
#pragma unroll
      for (int nt = 0; nt < 4; ++nt) acc[mt][nt] = MFMA_B16(a, bwv[nt], acc[mt][nt]);
    }
  }
}

// rowwise LN in-place over 64 buf rows; wave w does rows w+4i
__device__ __forceinline__ void ln_rows_inplace(bf16* buf, const float* __restrict__ g,
                                                const float* __restrict__ bsh, int w, int lane) {
  float gn[4], bn[4];
#pragma unroll
  for (int j = 0; j < 4; ++j) { gn[j] = g[lane + 64 * j]; bn[j] = bsh[lane + 64 * j]; }
  for (int i = 0; i < 16; ++i) {
    int row = 4 * i + w;
    bf16* rp = buf + row * SROW;
    float x[4]; float s = 0.f, ss = 0.f;
#pragma unroll
    for (int j = 0; j < 4; ++j) { x[j] = (float)rp[lane + 64 * j]; s += x[j]; ss += x[j] * x[j]; }
    s = wave_sum(s); ss = wave_sum(ss);
    float mean = s * (1.f / 256.f);
    float var = ss * (1.f / 256.f) - mean * mean;
    float rstd = 1.f / sqrtf(var + 1e-5f);
#pragma unroll
    for (int j = 0; j < 4; ++j) rp[lane + 64 * j] = (bf16)((x[j] - mean) * rstd * gn[j] + bn[j]);
  }
}

// ---------------------------------------------------------------------------
// prep: LDS tiled transpose fp32[k][256] -> bf16 [n][k]. One 32x32 tile/block.
// ---------------------------------------------------------------------------
__global__ void prep_kernel(const float* __restrict__ Wdyn, const float* __restrict__ Wstat,
                            const float* __restrict__ Wq, const float* __restrict__ Wk,
                            const float* __restrict__ Wv, const float* __restrict__ W1,
                            const float* __restrict__ W2, const float* __restrict__ Wo,
                            bf16* __restrict__ ws) {
  __shared__ float t[32][33];
  int idx = blockIdx.x;
  const float* src; bf16* dst; int K; int tile;
  if (idx < 128)      { src = Wdyn;  dst = ws + WDYN_T;  K = 512; tile = idx; }
  else if (idx < 144) { src = Wstat; dst = ws + WSTAT_T; K = 64;  tile = idx - 128; }
  else {
    int m = (idx - 144) >> 6; tile = (idx - 144) & 63; K = 256;
    src = (m == 0) ? Wq : (m == 1) ? Wk : (m == 2) ? Wv : (m == 3) ? W1 : (m == 4) ? W2 : Wo;
    dst = ws + WQ_T + (size_t)m * 65536;
  }
  int ntk = K >> 5;
  int kt = tile % ntk, nt = tile / ntk;
  int k0 = kt * 32, n0 = nt * 32;
  int c = threadIdx.x & 31, r0 = threadIdx.x >> 5;
#pragma unroll
  for (int i = 0; i < 4; ++i) {
    int r = r0 + 8 * i;
    t[r][c] = src[(size_t)(k0 + r) * 256 + n0 + c];
  }
  __syncthreads();
#pragma unroll
  for (int i = 0; i < 4; ++i) {
    int n = n0 + r0 + 8 * i;
    dst[(size_t)n * K + k0 + c] = (bf16)t[c][r0 + 8 * i];
  }
}

// ---------------------------------------------------------------------------
// pre: h0 = h_dyn@Wdyn+b_dyn (K=512); hln = LN(h0); q = hln@Wq+bq.
// grid 256 blocks x 256 thr; each WG does 16 batch rows, wave w -> cols 64w..
// ---------------------------------------------------------------------------
__launch_bounds__(256, 2)
__global__ void pre_kernel(const float* __restrict__ h_dyn, const float* __restrict__ b_dyn,
                           const float* __restrict__ g_ndyn, const float* __restrict__ b_ndyn,
                           const float* __restrict__ bq,
                           const bf16* __restrict__ Wdyn_t, const bf16* __restrict__ Wq_t,
                           float* __restrict__ h0_out, float* __restrict__ q_out) {
  __shared__ float h0t[16][264];
  __shared__ bf16 hlnt[16][264];
  const int tid = threadIdx.x;
  const int w = tid >> 6, lane = tid & 63, quad = lane >> 4, l16 = lane & 15;
  const int koff = quad * 8;
  const int b0 = blockIdx.x * 16;

  // stage A: h0 (K=512), A streamed from global fp32
  {
    f32x4 acc[4];
#pragma unroll
    for (int nt = 0; nt < 4; ++nt) { f32x4 z = {0.f, 0.f, 0.f, 0.f}; acc[nt] = z; }
    const float* arow = h_dyn + (size_t)(b0 + l16) * 512;
    for (int ks = 0; ks < 16; ++ks) {
      float4 x0 = *(const float4*)(arow + ks * 32 + koff);
      float4 x1 = *(const float4*)(arow + ks * 32 + koff + 4);
      bf16x8 a;
      a[0] = (bf16)x0.x; a[1] = (bf16)x0.y; a[2] = (bf16)x0.z; a[3] = (bf16)x0.w;
      a[4] = (bf16)x1.x; a[5] = (bf16)x1.y; a[6] = (bf16)x1.z; a[7] = (bf16)x1.w;
#pragma unroll
      for (int nt = 0; nt < 4; ++nt) {
        bf16x8 bw = *(const bf16x8*)(Wdyn_t + (size_t)(w * 64 + nt * 16 + l16) * 512 + ks * 32 + koff);
        acc[nt] = MFMA_B16(a, bw, acc[nt]);
      }
    }
#pragma unroll
    for (int nt = 0; nt < 4; ++nt) {
      int col = w * 64 + nt * 16 + l16;
      float bb = b_dyn[col];
#pragma unroll
      for (int r = 0; r < 4; ++r) {
        int row = quad * 4 + r;
        float v = acc[nt][r] + bb;
        h0t[row][col] = v;
        h0_out[(size_t)(b0 + row) * 256 + col] = v;
      }
    }
  }
  __syncthreads();

  // LN over the 16 rows: wave w handles rows w+4i
  {
    float gn[4], bn[4];
#pragma unroll
    for (int j = 0; j < 4; ++j) { gn[j] = g_ndyn[lane + 64 * j]; bn[j] = b_ndyn[lane + 64 * j]; }
#pragma unroll
    for (int i = 0; i < 4; ++i) {
      int row = 4 * i + w;
      float x[4]; float s = 0.f, ss = 0.f;
#pragma unroll
      for (int j = 0; j < 4; ++j) { x[j] = h0t[row][lane + 64 * j]; s += x[j]; ss += x[j] * x[j]; }
      s = wave_sum(s); ss = wave_sum(ss);
      float mean = s * (1.f / 256.f);
      float var = ss * (1.f / 256.f) - mean * mean;
      float rstd = 1.f / sqrtf(var + 1e-5f);
#pragma unroll
      for (int j = 0; j < 4; ++j)
        hlnt[row][lane + 64 * j] = (bf16)((x[j] - mean) * rstd * gn[j] + bn[j]);
    }
  }
  __syncthreads();

  // stage B: q = hln@Wq + bq (K=256)
  {
    f32x4 acc[4];
#pragma unroll
    for (int nt = 0; nt < 4; ++nt) { f32x4 z = {0.f, 0.f, 0.f, 0.f}; acc[nt] = z; }
    for (int ks = 0; ks < 8; ++ks) {
      bf16x8 a = *(const bf16x8*)(&hlnt[l16][ks * 32 + koff]);
#pragma unroll
      for (int nt = 0; nt < 4; ++nt) {
        bf16x8 bw = *(const bf16x8*)(Wq_t + (size_t)(w * 64 + nt * 16 + l16) * 256 + ks * 32 + koff);
        acc[nt] = MFMA_B16(a, bw, acc[nt]);
      }
    }
#pragma unroll
    for (int nt = 0; nt < 4; ++nt) {
      int col = w * 64 + nt * 16 + l16;
      float bb = bq[col];
#pragma unroll
      for (int r = 0; r < 4; ++r)
        q_out[(size_t)(b0 + quad * 4 + r) * 256 + col] = acc[nt][r] + bb;
    }
  }
}

// ---------------------------------------------------------------------------
// fused: per-batch chain s..z. grid 4096 x 256 thr, target 4 blocks/CU.
// ---------------------------------------------------------------------------
__launch_bounds__(256, 4)
__global__ void fused_kernel(
    const float* __restrict__ x_stat, const float* __restrict__ b_stat,
    const float* __restrict__ g_nstat, const float* __restrict__ b_nstat,
    const float* __restrict__ bk, const float* __restrict__ bv,
    const float* __restrict__ g_mlp, const float* __restrict__ b_mlp,
    const float* __restrict__ b1, const float* __restrict__ b2,
    const float* __restrict__ q_in,
    const bf16* __restrict__ Wstat_t, const bf16* __restrict__ Wk_t,
    const bf16* __restrict__ Wv_t, const bf16* __restrict__ W1_t,
    const bf16* __restrict__ W2_t,
    bf16* __restrict__ z_out, float* __restrict__ out_wm) {

  __shared__ bf16 buf[64 * SROW];   // 33792 B
  __shared__ float qs[256];
  __shared__ float logit_s[4][64];
  __shared__ float watt[4][64];
  __shared__ float swh[4];

  const int b = blockIdx.x;
  const int tid = threadIdx.x;
  const int w = tid >> 6, lane = tid & 63, quad = lane >> 4, l16 = lane & 15;
  const int koff = quad * 8;

  // phase A: stage q row; bkq = bk.q per head (register, wave-uniform)
  float qown = q_in[(size_t)b * 256 + tid];
  qs[tid] = qown;
  float bkq = wave_sum(qown * bk[tid]);

  // phase B: s = x_stat @ W_stat + b_stat -> buf  (K=64, A from global)
  {
    f32x4 acc[4][4];
    zero_acc(acc);
    const float* xb = x_stat + (size_t)b * 4096;
    for (int ks = 0; ks < 2; ++ks) {
      bf16x8 bwv[4];
#pragma unroll
      for (int nt = 0; nt < 4; ++nt)
        bwv[nt] = *(const bf16x8*)(Wstat_t + (size_t)(w * 64 + nt * 16 + l16) * 64 + ks * 32 + koff);
#pragma unroll
      for (int mt = 0; mt < 4; ++mt) {
        const float* xp = xb + (mt * 16 + l16) * 64 + ks * 32 + koff;
        float4 x0 = *(const float4*)xp;
        float4 x1 = *(const float4*)(xp + 4);
        bf16x8 a;
        a[0] = (bf16)x0.x; a[1] = (bf16)x0.y; a[2] = (bf16)x0.z; a[3] = (bf16)x0.w;
        a[4] = (bf16)x1.x; a[5] = (bf16)x1.y; a[6] = (bf16)x1.z; a[7] = (bf16)x1.w;
#pragma unroll
        for (int nt = 0; nt < 4; ++nt) acc[mt][nt] = MFMA_B16(a, bwv[nt], acc[mt][nt]);
      }
    }
    float bias[4];
#pragma unroll
    for (int nt = 0; nt < 4; ++nt) bias[nt] = b_stat[w * 64 + nt * 16 + l16];
#pragma unroll
    for (int mt = 0; mt < 4; ++mt)
#pragma unroll
      for (int nt = 0; nt < 4; ++nt)
#pragma unroll
        for (int r = 0; r < 4; ++r)
          buf[(mt * 16 + quad * 4 + r) * SROW + w * 64 + nt * 16 + l16] =
              (bf16)(acc[mt][nt][r] + bias[nt]);
  }
  __syncthreads();

  // phase C: LN(s) in-place
  ln_rows_inplace(buf, g_nstat, b_nstat, w, lane);
  __syncthreads();

  // phase D: k-logits (k never materialized; bk via bkq)
  {
    f32x4 acc[4][4];
    zero_acc(acc);
    gemm_stage(buf, Wk_t, w, l16, koff, acc);
    float qv[4];
#pragma unroll
    for (int nt = 0; nt < 4; ++nt) qv[nt] = qs[w * 64 + nt * 16 + l16];
#pragma unroll
    for (int mt = 0; mt < 4; ++mt)
#pragma unroll
      for (int r = 0; r < 4; ++r) {
        float p = acc[mt][0][r] * qv[0] + acc[mt][1][r] * qv[1] +
                  acc[mt][2][r] * qv[2] + acc[mt][3][r] * qv[3];
        p += __shfl_xor(p, 1, 64);
        p += __shfl_xor(p, 2, 64);
        p += __shfl_xor(p, 4, 64);
        p += __shfl_xor(p, 8, 64);
        if (l16 == 0) logit_s[w][mt * 16 + quad * 4 + r] = p;
      }
  }

  // phase E: sigmoid attention weights (intra-wave after D)
  {
    float raw = logit_s[w][lane];
    float lg = (raw + bkq) * 0.125f;       // SCALE = 1/sqrt(64)
    float sig = 1.f / (1.f + expf(-lg));
    float den = wave_sum(sig);
    float dinv = 1.f / (den + 1e-6f);
    watt[w][lane] = sig * dinv;
    if (lane == 0) swh[w] = den * dinv;
  }
  __syncthreads();
  if (tid < 64)
    out_wm[(size_t)b * 64 + tid] =
        0.25f * (watt[0][tid] + watt[1][tid] + watt[2][tid] + watt[3][tid]);

  // phase F: v = s_ln@Wv + bv, in-place (single barrier between reads & writes)
  {
    f32x4 acc[4][4];
    zero_acc(acc);
    gemm_stage(buf, Wv_t, w, l16, koff, acc);
    __syncthreads();
    float bias[4];
#pragma unroll
    for (int nt = 0; nt < 4; ++nt) bias[nt] = bv[w * 64 + nt * 16 + l16];
#pragma unroll
    for (int mt = 0; mt < 4; ++mt)
#pragma unroll
      for (int nt = 0; nt < 4; ++nt)
#pragma unroll
        for (int r = 0; r < 4; ++r)
          buf[(mt * 16 + quad * 4 + r) * SROW + w * 64 + nt * 16 + l16] =
              (bf16)(acc[mt][nt][r] + bias[nt]);
  }
  __syncthreads();

  // phase G: LN(v) in-place (g_mlp)
  ln_rows_inplace(buf, g_mlp, b_mlp, w, lane);
  __syncthreads();

  // phase H: t1 = gelu(t_ln@W1 + b1), in-place
  {
    f32x4 acc[4][4];
    zero_acc(acc);
    gemm_stage(buf, W1_t, w, l16, koff, acc);
    __syncthreads();
    float bias[4];
#pragma unroll
    for (int nt = 0; nt < 4; ++nt) bias[nt] = b1[w * 64 + nt * 16 + l16];
#pragma unroll
    for (int mt = 0; mt < 4; ++mt)
#pragma unroll
      for (int nt = 0; nt < 4; ++nt)
#pragma unroll
        for (int r = 0; r < 4; ++r) {
          float x = acc[mt][nt][r] + bias[nt];
          float g = 0.5f * x * (1.f + erff(x * 0.70710678118654752f));
          buf[(mt * 16 + quad * 4 + r) * SROW + w * 64 + nt * 16 + l16] = (bf16)g;
        }
  }
  __syncthreads();

  // phase I: v_tok = t1@W2 (+b2 via swh); z = watt . v_tok
  {
    f32x4 acc[4][4];
    zero_acc(acc);
    gemm_stage(buf, W2_t, w, l16, koff, acc);
    float zacc[4] = {0.f, 0.f, 0.f, 0.f};
#pragma unroll
    for (int mt = 0; mt < 4; ++mt)
#pragma unroll
      for (int r = 0; r < 4; ++r) {
        float wt = watt[w][mt * 16 + quad * 4 + r];
#pragma unroll
        for (int nt = 0; nt < 4; ++nt) zacc[nt] += wt * acc[mt][nt][r];
      }
#pragma unroll
    for (int nt = 0; nt < 4; ++nt) {
      zacc[nt] += __shfl_xor(zacc[nt], 16, 64);
      zacc[nt] += __shfl_xor(zacc[nt], 32, 64);
    }
    if (quad == 0) {
#pragma unroll
      for (int nt = 0; nt < 4; ++nt) {
        int col = w * 64 + nt * 16 + l16;
        z_out[(size_t)b * 256 + col] = (bf16)(zacc[nt] + b2[col] * swh[w]);
      }
    }
  }
}

// ---------------------------------------------------------------------------
// post: c = h0 + rs*(z@Wo + bo). grid 256 x 256 thr, 16 batch rows per WG.
// ---------------------------------------------------------------------------
__launch_bounds__(256, 2)
__global__ void post_kernel(const bf16* __restrict__ z_bf, const float* __restrict__ h0,
                            const float* __restrict__ bo, const float* __restrict__ rsp,
                            const bf16* __restrict__ Wo_t, float* __restrict__ out_c) {
  const int tid = threadIdx.x;
  const int w = tid >> 6, lane = tid & 63, quad = lane >> 4, l16 = lane & 15;
  const int koff = quad * 8;
  const int b0 = blockIdx.x * 16;

  f32x4 acc[4];
#pragma unroll
  for (int nt = 0; nt < 4; ++nt) { f32x4 z = {0.f, 0.f, 0.f, 0.f}; acc[nt] = z; }
  const bf16* arow = z_bf + (size_t)(b0 + l16) * 256;
  for (int ks = 0; ks < 8; ++ks) {
    bf16x8 a = *(const bf16x8*)(arow + ks * 32 + koff);
#pragma unroll
    for (int nt = 0; nt < 4; ++nt) {
      bf16x8 bw = *(const bf16x8*)(Wo_t + (size_t)(w * 64 + nt * 16 + l16) * 256 + ks * 32 + koff);
      acc[nt] = MFMA_B16(a, bw, acc[nt]);
    }
  }
  float rs = *rsp;
#pragma unroll
  for (int nt = 0; nt < 4; ++nt) {
    int col = w * 64 + nt * 16 + l16;
    float bb = bo[col];
#pragma unroll
    for (int r = 0; r < 4; ++r) {
      size_t o = (size_t)(b0 + quad * 4 + r) * 256 + col;
      out_c[o] = h0[o] + rs * (acc[nt][r] + bb);
    }
  }
}

extern "C" void kernel_launch(void* const* d_in, const int* in_sizes, int n_in,
                              void* d_out, int out_size, void* d_ws, size_t ws_size,
                              hipStream_t stream) {
  const float* h_dyn   = (const float*)d_in[0];
  const float* x_stat  = (const float*)d_in[1];
  const float* W_dyn   = (const float*)d_in[2];
  const float* b_dyn   = (const float*)d_in[3];
  const float* W_stat  = (const float*)d_in[4];
  const float* b_stat  = (const float*)d_in[5];
  const float* g_ndyn  = (const float*)d_in[6];
  const float* b_ndyn  = (const float*)d_in[7];
  const float* g_nstat = (const float*)d_in[8];
  const float* b_nstat = (const float*)d_in[9];
  const float* Wq = (const float*)d_in[10];
  const float* bq = (const float*)d_in[11];
  const float* Wk = (const float*)d_in[12];
  const float* bk = (const float*)d_in[13];
  const float* Wv = (const float*)d_in[14];
  const float* bv = (const float*)d_in[15];
  const float* g_mlp = (const float*)d_in[16];
  const float* b_mlp = (const float*)d_in[17];
  const float* W1 = (const float*)d_in[18];
  const float* b1 = (const float*)d_in[19];
  const float* W2 = (const float*)d_in[20];
  const float* b2 = (const float*)d_in[21];
  const float* Wo = (const float*)d_in[22];
  const float* bo = (const float*)d_in[23];
  const float* rs = (const float*)d_in[24];

  bf16* ws = (bf16*)d_ws;
  float* wsf = (float*)d_ws;
  float* ws_h0 = wsf + H0_F;
  float* ws_q  = wsf + Q_F;
  bf16*  ws_z  = ws + Z_BF;

  prep_kernel<<<528, 256, 0, stream>>>(W_dyn, W_stat, Wq, Wk, Wv, W1, W2, Wo, ws);

  pre_kernel<<<256, 256, 0, stream>>>(h_dyn, b_dyn, g_ndyn, b_ndyn, bq,
                                      ws + WDYN_T, ws + WQ_T, ws_h0, ws_q);

  float* out_c = (float*)d_out;
  float* out_wm = out_c + (size_t)4096 * 256;
  fused_kernel<<<4096, 256, 0, stream>>>(
      x_stat, b_stat, g_nstat, b_nstat, bk, bv, g_mlp, b_mlp, b1, b2,
      ws_q, ws + WSTAT_T, ws + WK_T, ws + WV_T, ws + W1_T, ws + W2_T,
      ws_z, out_wm);

  post_kernel<<<256, 256, 0, stream>>>(ws_z, ws_h0, bo, rs, ws + WO_T, out_c);
}

// Round 3
// 443.960 us; speedup vs baseline: 1.7020x; 1.0891x over previous
//
#include <hip/hip_runtime.h>
#include <cmath>

// ============================================================================
// SpatialContextSet — round 3.
// Kernels: prep (transposes + Wk bf16 copy + W2o=W2@Wo fold + b2o), pre
// (h0/LN/q + kq[b,h,:]=Wk[:,hblk]@q_h + bkq[b,h]=bk_h.q_h), fused (s -> LN ->
// logits-via-kq -> sigmoid-attn -> v -> LN -> gelu(sigmoid approx) -> W2o ->
// c written directly).  Wk GEMM and post kernel algebraically eliminated.
// ============================================================================

typedef __bf16 bf16;
typedef bf16 bf16x4 __attribute__((ext_vector_type(4)));
typedef bf16 bf16x8 __attribute__((ext_vector_type(8)));
typedef float f32x4 __attribute__((ext_vector_type(4)));

#define MFMA_B16(a, b, c) __builtin_amdgcn_mfma_f32_16x16x32_bf16((a), (b), (c), 0, 0, 0)

constexpr int SROW = 264;  // buf row stride bf16 (528 B, 16B-aligned, odd*16)

// ---- workspace layout (bf16 element offsets) ----
constexpr size_t WDYN_T  = 0;         // [256][512]
constexpr size_t WSTAT_T = 131072;    // [256][64]
constexpr size_t WQ_T    = 147456;    // [256][256]
constexpr size_t WV_T    = 212992;
constexpr size_t W1_T    = 278528;
constexpr size_t W2O_T   = 344064;    // (W2@Wo)^T
constexpr size_t WK_BF   = 409600;    // straight bf16 copy of Wk [in][out]
constexpr size_t KQ_BF   = 475136;    // [4096][4][256]
// float element offsets (from (float*)ws):
constexpr size_t H0_F  = 2334720;     // [4096][256]
constexpr size_t BKQ_F = 3383296;     // [4096][4]
constexpr size_t B2O_F = 3399680;     // [256]

__device__ __forceinline__ bf16x8 zero8() {
  bf16x8 z;
#pragma unroll
  for (int j = 0; j < 8; ++j) z[j] = (bf16)0.0f;
  return z;
}

__device__ __forceinline__ float wave_sum(float v) {
#pragma unroll
  for (int m = 1; m < 64; m <<= 1) v += __shfl_xor(v, m, 64);
  return v;
}

__device__ __forceinline__ void zero_acc(f32x4 (&acc)[4][4]) {
#pragma unroll
  for (int mt = 0; mt < 4; ++mt)
#pragma unroll
    for (int nt = 0; nt < 4; ++nt) { f32x4 z = {0.f, 0.f, 0.f, 0.f}; acc[mt][nt] = z; }
}

// K=256 GEMM stage: A from LDS buf, B from transposed weight, bw double-buffered
__device__ __forceinline__ void gemm_stage(const bf16* buf, const bf16* __restrict__ Wt,
                                           int w, int l16, int koff, f32x4 (&acc)[4][4]) {
  bf16x8 bw[2][4];
#pragma unroll
  for (int nt = 0; nt < 4; ++nt)
    bw[0][nt] = *(const bf16x8*)(Wt + (size_t)(w * 64 + nt * 16 + l16) * 256 + koff);
#pragma unroll
  for (int ks = 0; ks < 8; ++ks) {
    const int cur = ks & 1, nxt = cur ^ 1;
    if (ks < 7) {
#pragma unroll
      for (int nt = 0; nt < 4; ++nt)
        bw[nxt][nt] = *(const bf16x8*)(Wt + (size_t)(w * 64 + nt * 16 + l16) * 256 +
                                       (ks + 1) * 32 + koff);
    }
#pragma unroll
    for (int mt = 0; mt < 4; ++mt) {
      bf16x8 a = *(const bf16x8*)(buf + (mt * 16 + l16) * SROW + ks * 32 + koff);
#pragma unroll
      for (int nt = 0; nt < 4; ++nt) acc[mt][nt] = MFMA_B16(a, bw[cur][nt], acc[mt][nt]);
    }
  }
}

// rowwise LN in-place, vectorized: lane owns cols [lane*4, lane*4+4)
__device__ __forceinline__ void ln_rows_inplace(bf16* buf, const float* __restrict__ g,
                                                const float* __restrict__ bsh, int w, int lane) {
  const float4 gv = *(const float4*)(g + lane * 4);
  const float4 bv = *(const float4*)(bsh + lane * 4);
  for (int i = 0; i < 16; ++i) {
    bf16* rp = buf + (4 * i + w) * SROW + lane * 4;
    bf16x4 xv = *(const bf16x4*)rp;
    float x0 = (float)xv[0], x1 = (float)xv[1], x2 = (float)xv[2], x3 = (float)xv[3];
    float s = x0 + x1 + x2 + x3;
    float ss = x0 * x0 + x1 * x1 + x2 * x2 + x3 * x3;
    s = wave_sum(s); ss = wave_sum(ss);
    float mean = s * (1.f / 256.f);
    float var = ss * (1.f / 256.f) - mean * mean;
    float rstd = 1.f / sqrtf(var + 1e-5f);
    bf16x4 o;
    o[0] = (bf16)((x0 - mean) * rstd * gv.x + bv.x);
    o[1] = (bf16)((x1 - mean) * rstd * gv.y + bv.y);
    o[2] = (bf16)((x2 - mean) * rstd * gv.z + bv.z);
    o[3] = (bf16)((x3 - mean) * rstd * gv.w + bv.w);
    *(bf16x4*)rp = o;
  }
}

// ---------------------------------------------------------------------------
// prep: blocks 0..335 transpose {Wdyn,Wstat,Wq,Wv,W1} to bf16 [n][k];
//       336..399 straight bf16 copy of Wk; 400..431 compute W2o=W2@Wo (+b2o).
// ---------------------------------------------------------------------------
__global__ void prep_kernel(const float* __restrict__ Wdyn, const float* __restrict__ Wstat,
                            const float* __restrict__ Wq, const float* __restrict__ Wk,
                            const float* __restrict__ Wv, const float* __restrict__ W1,
                            const float* __restrict__ W2, const float* __restrict__ Wo,
                            const float* __restrict__ b2,
                            bf16* __restrict__ ws, float* __restrict__ b2o_out) {
  __shared__ float t[32][33];
  __shared__ float wo_s[256][8];
  __shared__ float part[4][8];
  const int idx = blockIdx.x;
  const int tid = threadIdx.x;

  if (idx >= 400) {  // ---- W2o fold: 8 output n-columns per block ----
    const int n0 = (idx - 400) * 8;
    float4 a0 = *(const float4*)(Wo + (size_t)tid * 256 + n0);
    float4 a1 = *(const float4*)(Wo + (size_t)tid * 256 + n0 + 4);
    wo_s[tid][0] = a0.x; wo_s[tid][1] = a0.y; wo_s[tid][2] = a0.z; wo_s[tid][3] = a0.w;
    wo_s[tid][4] = a1.x; wo_s[tid][5] = a1.y; wo_s[tid][6] = a1.z; wo_s[tid][7] = a1.w;
    __syncthreads();
    float acc[8] = {0.f, 0.f, 0.f, 0.f, 0.f, 0.f, 0.f, 0.f};
    const float* row = W2 + (size_t)tid * 256;
    for (int d0 = 0; d0 < 256; d0 += 4) {
      float4 wv = *(const float4*)(row + d0);
#pragma unroll
      for (int dd = 0; dd < 4; ++dd) {
        float r = (dd == 0) ? wv.x : (dd == 1) ? wv.y : (dd == 2) ? wv.z : wv.w;
        float4 c0 = *(const float4*)&wo_s[d0 + dd][0];
        float4 c1 = *(const float4*)&wo_s[d0 + dd][4];
        acc[0] += r * c0.x; acc[1] += r * c0.y; acc[2] += r * c0.z; acc[3] += r * c0.w;
        acc[4] += r * c1.x; acc[5] += r * c1.y; acc[6] += r * c1.z; acc[7] += r * c1.w;
      }
    }
    bf16* dst = ws + W2O_T;
#pragma unroll
    for (int j = 0; j < 8; ++j) dst[(size_t)(n0 + j) * 256 + tid] = (bf16)acc[j];
    // b2o = b2 @ Wo for these columns
    const int w = tid >> 6, lane = tid & 63;
    float bval = b2[tid];
#pragma unroll
    for (int j = 0; j < 8; ++j) {
      float p = wave_sum(bval * wo_s[tid][j]);
      if (lane == 0) part[w][j] = p;
    }
    __syncthreads();
    if (tid < 8) b2o_out[n0 + tid] = part[0][tid] + part[1][tid] + part[2][tid] + part[3][tid];
    return;
  }

  if (idx >= 336) {  // ---- Wk straight copy fp32 -> bf16 ----
    const int base = (idx - 336) * 1024 + tid * 4;
    float4 v = *(const float4*)(Wk + base);
    bf16* dst = ws + WK_BF + base;
    dst[0] = (bf16)v.x; dst[1] = (bf16)v.y; dst[2] = (bf16)v.z; dst[3] = (bf16)v.w;
    return;
  }

  // ---- transposes ----
  const float* src; bf16* dst; int K; int tile;
  if (idx < 128)      { src = Wdyn;  dst = ws + WDYN_T;  K = 512; tile = idx; }
  else if (idx < 144) { src = Wstat; dst = ws + WSTAT_T; K = 64;  tile = idx - 128; }
  else if (idx < 208) { src = Wq;    dst = ws + WQ_T;    K = 256; tile = idx - 144; }
  else if (idx < 272) { src = Wv;    dst = ws + WV_T;    K = 256; tile = idx - 208; }
  else                { src = W1;    dst = ws + W1_T;    K = 256; tile = idx - 272; }
  const int ntk = K >> 5;
  const int kt = tile % ntk, nt = tile / ntk;
  const int k0 = kt * 32, n0 = nt * 32;
  const int c = tid & 31, r0 = tid >> 5;
#pragma unroll
  for (int i = 0; i < 4; ++i)
    t[r0 + 8 * i][c] = src[(size_t)(k0 + r0 + 8 * i) * 256 + n0 + c];
  __syncthreads();
#pragma unroll
  for (int i = 0; i < 4; ++i)
    dst[(size_t)(n0 + r0 + 8 * i) * K + k0 + c] = (bf16)t[c][r0 + 8 * i];
}

// ---------------------------------------------------------------------------
// pre: h0 = h_dyn@Wdyn+b (K=512); hln = LN(h0); q = hln@Wq+bq (kept in LDS);
//      kq[b,h,:] = Wk[:,hblk]@q_h ; bkq[b,h] = bk_h . q_h.
// grid 256 x 256 thr; 16 batch rows per WG.
// ---------------------------------------------------------------------------
__launch_bounds__(256, 2)
__global__ void pre_kernel(const float* __restrict__ h_dyn, const float* __restrict__ b_dyn,
                           const float* __restrict__ g_ndyn, const float* __restrict__ b_ndyn,
                           const float* __restrict__ bq, const float* __restrict__ bk,
                           const bf16* __restrict__ Wdyn_t, const bf16* __restrict__ Wq_t,
                           const bf16* __restrict__ Wk_bf,
                           float* __restrict__ h0_out, bf16* __restrict__ kq_out,
                           float* __restrict__ bkq_out) {
  __shared__ float h0t[16][264];
  __shared__ bf16 hlnt[16][264];
  __shared__ bf16 qt[16][264];
  const int tid = threadIdx.x;
  const int w = tid >> 6, lane = tid & 63, quad = lane >> 4, l16 = lane & 15;
  const int koff = quad * 8;
  const int b0 = blockIdx.x * 16;

  // h0 (K=512), A streamed from global fp32
  {
    f32x4 acc[4];
#pragma unroll
    for (int nt = 0; nt < 4; ++nt) { f32x4 z = {0.f, 0.f, 0.f, 0.f}; acc[nt] = z; }
    const float* arow = h_dyn + (size_t)(b0 + l16) * 512;
    for (int ks = 0; ks < 16; ++ks) {
      float4 x0 = *(const float4*)(arow + ks * 32 + koff);
      float4 x1 = *(const float4*)(arow + ks * 32 + koff + 4);
      bf16x8 a;
      a[0] = (bf16)x0.x; a[1] = (bf16)x0.y; a[2] = (bf16)x0.z; a[3] = (bf16)x0.w;
      a[4] = (bf16)x1.x; a[5] = (bf16)x1.y; a[6] = (bf16)x1.z; a[7] = (bf16)x1.w;
#pragma unroll
      for (int nt = 0; nt < 4; ++nt) {
        bf16x8 bw = *(const bf16x8*)(Wdyn_t + (size_t)(w * 64 + nt * 16 + l16) * 512 + ks * 32 + koff);
        acc[nt] = MFMA_B16(a, bw, acc[nt]);
      }
    }
#pragma unroll
    for (int nt = 0; nt < 4; ++nt) {
      int col = w * 64 + nt * 16 + l16;
      float bb = b_dyn[col];
#pragma unroll
      for (int r = 0; r < 4; ++r) {
        int row = quad * 4 + r;
        float v = acc[nt][r] + bb;
        h0t[row][col] = v;
        h0_out[(size_t)(b0 + row) * 256 + col] = v;
      }
    }
  }
  __syncthreads();

  // LN
  {
    float gn[4], bn[4];
#pragma unroll
    for (int j = 0; j < 4; ++j) { gn[j] = g_ndyn[lane + 64 * j]; bn[j] = b_ndyn[lane + 64 * j]; }
#pragma unroll
    for (int i = 0; i < 4; ++i) {
      int row = 4 * i + w;
      float x[4]; float s = 0.f, ss = 0.f;
#pragma unroll
      for (int j = 0; j < 4; ++j) { x[j] = h0t[row][lane + 64 * j]; s += x[j]; ss += x[j] * x[j]; }
      s = wave_sum(s); ss = wave_sum(ss);
      float mean = s * (1.f / 256.f);
      float var = ss * (1.f / 256.f) - mean * mean;
      float rstd = 1.f / sqrtf(var + 1e-5f);
#pragma unroll
      for (int j = 0; j < 4; ++j)
        hlnt[row][lane + 64 * j] = (bf16)((x[j] - mean) * rstd * gn[j] + bn[j]);
    }
  }
  __syncthreads();

  // q = hln@Wq + bq -> qt (LDS, bf16)
  {
    f32x4 acc[4];
#pragma unroll
    for (int nt = 0; nt < 4; ++nt) { f32x4 z = {0.f, 0.f, 0.f, 0.f}; acc[nt] = z; }
    for (int ks = 0; ks < 8; ++ks) {
      bf16x8 a = *(const bf16x8*)(&hlnt[l16][ks * 32 + koff]);
#pragma unroll
      for (int nt = 0; nt < 4; ++nt) {
        bf16x8 bw = *(const bf16x8*)(Wq_t + (size_t)(w * 64 + nt * 16 + l16) * 256 + ks * 32 + koff);
        acc[nt] = MFMA_B16(a, bw, acc[nt]);
      }
    }
#pragma unroll
    for (int nt = 0; nt < 4; ++nt) {
      int col = w * 64 + nt * 16 + l16;
      float bb = bq[col];
#pragma unroll
      for (int r = 0; r < 4; ++r)
        qt[quad * 4 + r][col] = (bf16)(acc[nt][r] + bb);
    }
  }
  __syncthreads();

  // bkq[b,h] = bk_h . q_h  (4 threads per (row,h) pair)
  {
    const int pair = tid >> 2;        // 0..63
    const int row = pair >> 2, h = pair & 3, sub = tid & 3;
    float p = 0.f;
#pragma unroll
    for (int j = 0; j < 16; ++j) {
      int e = sub * 16 + j;
      p += (float)qt[row][h * 64 + e] * bk[h * 64 + e];
    }
    p += __shfl_xor(p, 1, 64);
    p += __shfl_xor(p, 2, 64);
    if (sub == 0) bkq_out[(size_t)(b0 + row) * 4 + h] = p;
  }

  // kq GEMM per head: M=16(b), K=64(e), N=256(din); wave w -> din slice 64w..
  for (int h = 0; h < 4; ++h) {
    f32x4 acc[4];
#pragma unroll
    for (int nt = 0; nt < 4; ++nt) { f32x4 z = {0.f, 0.f, 0.f, 0.f}; acc[nt] = z; }
#pragma unroll
    for (int ks = 0; ks < 2; ++ks) {
      bf16x8 a = *(const bf16x8*)(&qt[l16][h * 64 + ks * 32 + koff]);
#pragma unroll
      for (int nt = 0; nt < 4; ++nt) {
        bf16x8 bw = *(const bf16x8*)(Wk_bf + (size_t)(w * 64 + nt * 16 + l16) * 256 +
                                     h * 64 + ks * 32 + koff);
        acc[nt] = MFMA_B16(a, bw, acc[nt]);
      }
    }
#pragma unroll
    for (int nt = 0; nt < 4; ++nt)
#pragma unroll
      for (int r = 0; r < 4; ++r)
        kq_out[(size_t)(b0 + quad * 4 + r) * 1024 + h * 256 + w * 64 + nt * 16 + l16] =
            (bf16)acc[nt][r];
  }
}

// ---------------------------------------------------------------------------
// fused: per-batch chain s..c. grid 4096 x 256 thr.
// ---------------------------------------------------------------------------
__launch_bounds__(256, 4)
__global__ void fused_kernel(
    const float* __restrict__ x_stat, const float* __restrict__ b_stat,
    const float* __restrict__ g_nstat, const float* __restrict__ b_nstat,
    const float* __restrict__ bv, const float* __restrict__ g_mlp,
    const float* __restrict__ b_mlp, const float* __restrict__ b1,
    const float* __restrict__ bo, const float* __restrict__ res_scale_p,
    const float* __restrict__ h0g, const float* __restrict__ bkq_g,
    const float* __restrict__ b2o_g,
    const bf16* __restrict__ Wstat_t, const bf16* __restrict__ Wv_t,
    const bf16* __restrict__ W1_t, const bf16* __restrict__ W2o_t,
    const bf16* __restrict__ kq_g,
    float* __restrict__ out_c, float* __restrict__ out_wm) {

  __shared__ bf16 buf[64 * SROW];   // 33792 B
  __shared__ float watt[4][64];
  __shared__ float swh[4];

  const int b = blockIdx.x;
  const int tid = threadIdx.x;
  const int w = tid >> 6, lane = tid & 63, quad = lane >> 4, l16 = lane & 15;
  const int koff = quad * 8;

  // ---- P1: s = x_stat @ W_stat + b_stat -> buf (K=64, A from global fp32) ----
  {
    f32x4 acc[4][4];
    zero_acc(acc);
    const float* xb = x_stat + (size_t)b * 4096;
#pragma unroll
    for (int ks = 0; ks < 2; ++ks) {
      bf16x8 bwv[4];
#pragma unroll
      for (int nt = 0; nt < 4; ++nt)
        bwv[nt] = *(const bf16x8*)(Wstat_t + (size_t)(w * 64 + nt * 16 + l16) * 64 + ks * 32 + koff);
#pragma unroll
      for (int mt = 0; mt < 4; ++mt) {
        const float* xp = xb + (mt * 16 + l16) * 64 + ks * 32 + koff;
        float4 x0 = *(const float4*)xp;
        float4 x1 = *(const float4*)(xp + 4);
        bf16x8 a;
        a[0] = (bf16)x0.x; a[1] = (bf16)x0.y; a[2] = (bf16)x0.z; a[3] = (bf16)x0.w;
        a[4] = (bf16)x1.x; a[5] = (bf16)x1.y; a[6] = (bf16)x1.z; a[7] = (bf16)x1.w;
#pragma unroll
        for (int nt = 0; nt < 4; ++nt) acc[mt][nt] = MFMA_B16(a, bwv[nt], acc[mt][nt]);
      }
    }
    float bias[4];
#pragma unroll
    for (int nt = 0; nt < 4; ++nt) bias[nt] = b_stat[w * 64 + nt * 16 + l16];
#pragma unroll
    for (int mt = 0; mt < 4; ++mt)
#pragma unroll
      for (int nt = 0; nt < 4; ++nt)
#pragma unroll
        for (int r = 0; r < 4; ++r)
          buf[(mt * 16 + quad * 4 + r) * SROW + w * 64 + nt * 16 + l16] =
              (bf16)(acc[mt][nt][r] + bias[nt]);
  }
  __syncthreads();

  // ---- P2: LN(s) in-place ----
  ln_rows_inplace(buf, g_nstat, b_nstat, w, lane);
  __syncthreads();

  // ---- P3a: logits via kq; wave w -> tokens [16w,16w+16); head = l16 (<4) ----
  {
    const bf16* kq_b = kq_g + (size_t)b * 1024;
    f32x4 accL = {0.f, 0.f, 0.f, 0.f};
#pragma unroll
    for (int ks = 0; ks < 8; ++ks) {
      bf16x8 a = *(const bf16x8*)(buf + (w * 16 + l16) * SROW + ks * 32 + koff);
      bf16x8 kf = zero8();
      if (l16 < 4) kf = *(const bf16x8*)(kq_b + l16 * 256 + ks * 32 + koff);
      accL = MFMA_B16(a, kf, accL);
    }
    float bkqv = (l16 < 4) ? bkq_g[(size_t)b * 4 + l16] : 0.f;
#pragma unroll
    for (int r = 0; r < 4; ++r) {
      float lg = (accL[r] + bkqv) * 0.125f;
      float sig = 1.f / (1.f + __expf(-lg));
      if (l16 < 4) watt[l16][w * 16 + quad * 4 + r] = sig;   // un-normalized
    }
  }

  // ---- P3b: v = s_ln @ Wv + bv (compute; stores after barrier) ----
  {
    f32x4 acc[4][4];
    zero_acc(acc);
    gemm_stage(buf, Wv_t, w, l16, koff, acc);
    __syncthreads();   // all buf reads (P3a+P3b) done; watt(sig) visible
    // ---- P3c: normalize attention weights (wave w == head w) ----
    {
      float v = watt[w][lane];
      float den = wave_sum(v);
      float dinv = 1.f / (den + 1e-6f);
      watt[w][lane] = v * dinv;
      if (lane == 0) swh[w] = den * dinv;
    }
    float bias[4];
#pragma unroll
    for (int nt = 0; nt < 4; ++nt) bias[nt] = bv[w * 64 + nt * 16 + l16];
#pragma unroll
    for (int mt = 0; mt < 4; ++mt)
#pragma unroll
      for (int nt = 0; nt < 4; ++nt)
#pragma unroll
        for (int r = 0; r < 4; ++r)
          buf[(mt * 16 + quad * 4 + r) * SROW + w * 64 + nt * 16 + l16] =
              (bf16)(acc[mt][nt][r] + bias[nt]);
  }
  __syncthreads();

  // ---- P4: w_mean output + LN(v) in-place ----
  if (tid < 64)
    out_wm[(size_t)b * 64 + tid] =
        0.25f * (watt[0][tid] + watt[1][tid] + watt[2][tid] + watt[3][tid]);
  ln_rows_inplace(buf, g_mlp, b_mlp, w, lane);
  __syncthreads();

  // ---- P5: t1 = gelu(t_ln@W1 + b1) in-place (gelu ~ x*sigmoid(1.702x)) ----
  {
    f32x4 acc[4][4];
    zero_acc(acc);
    gemm_stage(buf, W1_t, w, l16, koff, acc);
    __syncthreads();
    float bias[4];
#pragma unroll
    for (int nt = 0; nt < 4; ++nt) bias[nt] = b1[w * 64 + nt * 16 + l16];
#pragma unroll
    for (int mt = 0; mt < 4; ++mt)
#pragma unroll
      for (int nt = 0; nt < 4; ++nt)
#pragma unroll
        for (int r = 0; r < 4; ++r) {
          float x = acc[mt][nt][r] + bias[nt];
          float g = x / (1.f + __expf(-1.702f * x));
          buf[(mt * 16 + quad * 4 + r) * SROW + w * 64 + nt * 16 + l16] = (bf16)g;
        }
  }
  __syncthreads();

  // ---- P6: t1 @ W2o; z' = watt . rows; c written directly ----
  {
    f32x4 acc[4][4];
    zero_acc(acc);
    gemm_stage(buf, W2o_t, w, l16, koff, acc);
    float zacc[4] = {0.f, 0.f, 0.f, 0.f};
#pragma unroll
    for (int mt = 0; mt < 4; ++mt)
#pragma unroll
      for (int r = 0; r < 4; ++r) {
        float wt = watt[w][mt * 16 + quad * 4 + r];
#pragma unroll
        for (int nt = 0; nt < 4; ++nt) zacc[nt] += wt * acc[mt][nt][r];
      }
#pragma unroll
    for (int nt = 0; nt < 4; ++nt) {
      zacc[nt] += __shfl_xor(zacc[nt], 16, 64);
      zacc[nt] += __shfl_xor(zacc[nt], 32, 64);
    }
    if (quad == 0) {
      float rs = *res_scale_p;
#pragma unroll
      for (int nt = 0; nt < 4; ++nt) {
        int col = w * 64 + nt * 16 + l16;
        float res = zacc[nt] + swh[w] * b2o_g[col] + bo[col];
        out_c[(size_t)b * 256 + col] = h0g[(size_t)b * 256 + col] + rs * res;
      }
    }
  }
}

extern "C" void kernel_launch(void* const* d_in, const int* in_sizes, int n_in,
                              void* d_out, int out_size, void* d_ws, size_t ws_size,
                              hipStream_t stream) {
  const float* h_dyn   = (const float*)d_in[0];
  const float* x_stat  = (const float*)d_in[1];
  const float* W_dyn   = (const float*)d_in[2];
  const float* b_dyn   = (const float*)d_in[3];
  const float* W_stat  = (const float*)d_in[4];
  const float* b_stat  = (const float*)d_in[5];
  const float* g_ndyn  = (const float*)d_in[6];
  const float* b_ndyn  = (const float*)d_in[7];
  const float* g_nstat = (const float*)d_in[8];
  const float* b_nstat = (const float*)d_in[9];
  const float* Wq = (const float*)d_in[10];
  const float* bq = (const float*)d_in[11];
  const float* Wk = (const float*)d_in[12];
  const float* bk = (const float*)d_in[13];
  const float* Wv = (const float*)d_in[14];
  const float* bv = (const float*)d_in[15];
  const float* g_mlp = (const float*)d_in[16];
  const float* b_mlp = (const float*)d_in[17];
  const float* W1 = (const float*)d_in[18];
  const float* b1 = (const float*)d_in[19];
  const float* W2 = (const float*)d_in[20];
  const float* b2 = (const float*)d_in[21];
  const float* Wo = (const float*)d_in[22];
  const float* bo = (const float*)d_in[23];
  const float* rs = (const float*)d_in[24];

  bf16* ws = (bf16*)d_ws;
  float* wsf = (float*)d_ws;
  float* ws_h0  = wsf + H0_F;
  float* ws_bkq = wsf + BKQ_F;
  float* ws_b2o = wsf + B2O_F;

  prep_kernel<<<432, 256, 0, stream>>>(W_dyn, W_stat, Wq, Wk, Wv, W1, W2, Wo, b2,
                                       ws, ws_b2o);

  pre_kernel<<<256, 256, 0, stream>>>(h_dyn, b_dyn, g_ndyn, b_ndyn, bq, bk,
                                      ws + WDYN_T, ws + WQ_T, ws + WK_BF,
                                      ws_h0, ws + KQ_BF, ws_bkq);

  float* out_c = (float*)d_out;
  float* out_wm = out_c + (size_t)4096 * 256;
  fused_kernel<<<4096, 256, 0, stream>>>(
      x_stat, b_stat, g_nstat, b_nstat, bv, g_mlp, b_mlp, b1, bo, rs,
      ws_h0, ws_bkq, ws_b2o,
      ws + WSTAT_T, ws + WV_T, ws + W1_T, ws + W2O_T, ws + KQ_BF,
      out_c, out_wm);
}

// Round 4
// 432.745 us; speedup vs baseline: 1.7461x; 1.0259x over previous
//
#include <hip/hip_runtime.h>
#include <cmath>

// ============================================================================
// SpatialContextSet — round 4.
// prep : transposes {Wdyn,Wstat,Wq,Wv,W1} -> bf16 [n][k]; Wk bf16 copy;
//        W2o = W2@Wo fold (+b2o).
// pre  : grid 512, 8 rows/WG: h0=h_dyn@Wdyn+b; LN; q=hln@Wq+bq;
//        kq[b,h,:]=Wk[:,hblk]@q_h; bkq[b,h]=bk_h.q_h.
// fused: grid 4096 (1 batch/WG): s -> LN -> logits-via-kq -> sigmoid-attn ->
//        v(in-place) -> LN -> gelu(t@W1) -> (t1@W2o) . watt -> c.
//   NEW: buf-writing GEMMs use OPERAND-SWAPPED MFMA (A=W^T, B=s-rows) so the
//        D-layout gives each lane 4 consecutive dims of one token ->
//        vectorized b64 epilogue stores; LN stats computed from epilogue
//        registers (partials + 2 shfl), LN passes are apply-only.
// ============================================================================

typedef __bf16 bf16;
typedef bf16 bf16x4 __attribute__((ext_vector_type(4)));
typedef bf16 bf16x8 __attribute__((ext_vector_type(8)));
typedef float f32x4 __attribute__((ext_vector_type(4)));

#define MFMA_B16(a, b, c) __builtin_amdgcn_mfma_f32_16x16x32_bf16((a), (b), (c), 0, 0, 0)

constexpr int SROW = 264;  // buf row stride bf16 (528 B, 16B-aligned, odd*16)

// ---- workspace layout (bf16 element offsets) ----
constexpr size_t WDYN_T  = 0;         // [256][512]
constexpr size_t WSTAT_T = 131072;    // [256][64]
constexpr size_t WQ_T    = 147456;    // [256][256]
constexpr size_t WV_T    = 212992;
constexpr size_t W1_T    = 278528;
constexpr size_t W2O_T   = 344064;    // (W2@Wo)^T
constexpr size_t WK_BF   = 409600;    // straight bf16 copy of Wk [in][out]
constexpr size_t KQ_BF   = 475136;    // [4096][4][256]
// float element offsets (from (float*)ws):
constexpr size_t H0_F  = 2334720;     // [4096][256]
constexpr size_t BKQ_F = 3383296;     // [4096][4]
constexpr size_t B2O_F = 3399680;     // [256]

__device__ __forceinline__ bf16x8 zero8() {
  bf16x8 z;
#pragma unroll
  for (int j = 0; j < 8; ++j) z[j] = (bf16)0.0f;
  return z;
}

__device__ __forceinline__ float wave_sum(float v) {
#pragma unroll
  for (int m = 1; m < 64; m <<= 1) v += __shfl_xor(v, m, 64);
  return v;
}

__device__ __forceinline__ void zero_acc(f32x4 (&acc)[4][4]) {
#pragma unroll
  for (int mt = 0; mt < 4; ++mt)
#pragma unroll
    for (int nt = 0; nt < 4; ++nt) { f32x4 z = {0.f, 0.f, 0.f, 0.f}; acc[mt][nt] = z; }
}

// ---- swapped-operand K=256 GEMM: A=W^T rows (global), B=buf token rows (LDS)
// acc[dt][tt] -> value at (dim = w*64+dt*16+quad*4+r, token = tt*16+l16)
__device__ __forceinline__ void gemm_swapped(const bf16* buf, const bf16* __restrict__ Wt,
                                             int w, int l16, int koff, f32x4 (&acc)[4][4]) {
#pragma unroll
  for (int ks = 0; ks < 8; ++ks) {
    bf16x8 aw[4];
#pragma unroll
    for (int dt = 0; dt < 4; ++dt)
      aw[dt] = *(const bf16x8*)(Wt + (size_t)(w * 64 + dt * 16 + l16) * 256 + ks * 32 + koff);
#pragma unroll
    for (int tt = 0; tt < 4; ++tt) {
      bf16x8 bfrag = *(const bf16x8*)(buf + (tt * 16 + l16) * SROW + ks * 32 + koff);
#pragma unroll
      for (int dt = 0; dt < 4; ++dt) acc[dt][tt] = MFMA_B16(aw[dt], bfrag, acc[dt][tt]);
    }
  }
}

// ---- original-orientation K=256 GEMM (P6): A=buf token rows, B=W^T rows
__device__ __forceinline__ void gemm_orig(const bf16* buf, const bf16* __restrict__ Wt,
                                          int w, int l16, int koff, f32x4 (&acc)[4][4]) {
#pragma unroll
  for (int ks = 0; ks < 8; ++ks) {
    bf16x8 bw[4];
#pragma unroll
    for (int nt = 0; nt < 4; ++nt)
      bw[nt] = *(const bf16x8*)(Wt + (size_t)(w * 64 + nt * 16 + l16) * 256 + ks * 32 + koff);
#pragma unroll
    for (int mt = 0; mt < 4; ++mt) {
      bf16x8 a = *(const bf16x8*)(buf + (mt * 16 + l16) * SROW + ks * 32 + koff);
#pragma unroll
      for (int nt = 0; nt < 4; ++nt) acc[mt][nt] = MFMA_B16(a, bw[nt], acc[mt][nt]);
    }
  }
}

// ---- swapped epilogue: store (acc+bias) as bf16x4 per (dt,tt), accumulate
// per-token partial sum/sumsq, reduce over quads, park in part arrays.
__device__ __forceinline__ void store_swapped_stats(bf16* buf, const float* __restrict__ bsrc,
                                                    f32x4 (&acc)[4][4], int w, int quad, int l16,
                                                    float (*part_s)[64], float (*part_ss)[64]) {
  float ps[4] = {0.f, 0.f, 0.f, 0.f}, pq[4] = {0.f, 0.f, 0.f, 0.f};
#pragma unroll
  for (int dt = 0; dt < 4; ++dt) {
    const float4 bb = *(const float4*)(bsrc + w * 64 + dt * 16 + quad * 4);
#pragma unroll
    for (int tt = 0; tt < 4; ++tt) {
      float v0 = acc[dt][tt][0] + bb.x;
      float v1 = acc[dt][tt][1] + bb.y;
      float v2 = acc[dt][tt][2] + bb.z;
      float v3 = acc[dt][tt][3] + bb.w;
      ps[tt] += (v0 + v1) + (v2 + v3);
      pq[tt] += v0 * v0 + v1 * v1 + v2 * v2 + v3 * v3;
      bf16x4 o;
      o[0] = (bf16)v0; o[1] = (bf16)v1; o[2] = (bf16)v2; o[3] = (bf16)v3;
      *(bf16x4*)(buf + (tt * 16 + l16) * SROW + w * 64 + dt * 16 + quad * 4) = o;
    }
  }
#pragma unroll
  for (int tt = 0; tt < 4; ++tt) {
    ps[tt] += __shfl_xor(ps[tt], 16, 64); ps[tt] += __shfl_xor(ps[tt], 32, 64);
    pq[tt] += __shfl_xor(pq[tt], 16, 64); pq[tt] += __shfl_xor(pq[tt], 32, 64);
  }
  if (quad == 0) {
#pragma unroll
    for (int tt = 0; tt < 4; ++tt) {
      part_s[w][tt * 16 + l16] = ps[tt];
      part_ss[w][tt * 16 + l16] = pq[tt];
    }
  }
}

// ---- apply-only LN: finalize stats per lane-token, shfl-broadcast per row
__device__ __forceinline__ void ln_finalize_apply(bf16* buf, const float* __restrict__ g,
                                                  const float* __restrict__ bsh,
                                                  const float (*part_s)[64],
                                                  const float (*part_ss)[64], int w, int lane) {
  float psum = (part_s[0][lane] + part_s[1][lane]) + (part_s[2][lane] + part_s[3][lane]);
  float pqq  = (part_ss[0][lane] + part_ss[1][lane]) + (part_ss[2][lane] + part_ss[3][lane]);
  float mean = psum * (1.f / 256.f);
  float var  = pqq * (1.f / 256.f) - mean * mean;
  float rstd = 1.f / sqrtf(var + 1e-5f);
  const float4 gv = *(const float4*)(g + lane * 4);
  const float4 bv4 = *(const float4*)(bsh + lane * 4);
#pragma unroll
  for (int i = 0; i < 16; ++i) {
    const int row = 4 * i + w;
    const float mb = __shfl(mean, row, 64);
    const float rb = __shfl(rstd, row, 64);
    bf16* rp = buf + row * SROW + lane * 4;
    bf16x4 xv = *(const bf16x4*)rp;
    bf16x4 o;
    o[0] = (bf16)(((float)xv[0] - mb) * rb * gv.x + bv4.x);
    o[1] = (bf16)(((float)xv[1] - mb) * rb * gv.y + bv4.y);
    o[2] = (bf16)(((float)xv[2] - mb) * rb * gv.z + bv4.z);
    o[3] = (bf16)(((float)xv[3] - mb) * rb * gv.w + bv4.w);
    *(bf16x4*)rp = o;
  }
}

// ---------------------------------------------------------------------------
// prep: blocks 0..335 transpose; 336..399 Wk copy; 400..431 W2o fold
// ---------------------------------------------------------------------------
__global__ void prep_kernel(const float* __restrict__ Wdyn, const float* __restrict__ Wstat,
                            const float* __restrict__ Wq, const float* __restrict__ Wk,
                            const float* __restrict__ Wv, const float* __restrict__ W1,
                            const float* __restrict__ W2, const float* __restrict__ Wo,
                            const float* __restrict__ b2,
                            bf16* __restrict__ ws, float* __restrict__ b2o_out) {
  __shared__ float t[32][33];
  __shared__ float wo_s[256][8];
  __shared__ float part[4][8];
  const int idx = blockIdx.x;
  const int tid = threadIdx.x;

  if (idx >= 400) {  // ---- W2o fold ----
    const int n0 = (idx - 400) * 8;
    float4 a0 = *(const float4*)(Wo + (size_t)tid * 256 + n0);
    float4 a1 = *(const float4*)(Wo + (size_t)tid * 256 + n0 + 4);
    wo_s[tid][0] = a0.x; wo_s[tid][1] = a0.y; wo_s[tid][2] = a0.z; wo_s[tid][3] = a0.w;
    wo_s[tid][4] = a1.x; wo_s[tid][5] = a1.y; wo_s[tid][6] = a1.z; wo_s[tid][7] = a1.w;
    __syncthreads();
    float acc[8] = {0.f, 0.f, 0.f, 0.f, 0.f, 0.f, 0.f, 0.f};
    const float* row = W2 + (size_t)tid * 256;
    for (int d0 = 0; d0 < 256; d0 += 4) {
      float4 wv = *(const float4*)(row + d0);
#pragma unroll
      for (int dd = 0; dd < 4; ++dd) {
        float r = (dd == 0) ? wv.x : (dd == 1) ? wv.y : (dd == 2) ? wv.z : wv.w;
        float4 c0 = *(const float4*)&wo_s[d0 + dd][0];
        float4 c1 = *(const float4*)&wo_s[d0 + dd][4];
        acc[0] += r * c0.x; acc[1] += r * c0.y; acc[2] += r * c0.z; acc[3] += r * c0.w;
        acc[4] += r * c1.x; acc[5] += r * c1.y; acc[6] += r * c1.z; acc[7] += r * c1.w;
      }
    }
    bf16* dst = ws + W2O_T;
#pragma unroll
    for (int j = 0; j < 8; ++j) dst[(size_t)(n0 + j) * 256 + tid] = (bf16)acc[j];
    const int w = tid >> 6, lane = tid & 63;
    float bval = b2[tid];
#pragma unroll
    for (int j = 0; j < 8; ++j) {
      float p = wave_sum(bval * wo_s[tid][j]);
      if (lane == 0) part[w][j] = p;
    }
    __syncthreads();
    if (tid < 8) b2o_out[n0 + tid] = part[0][tid] + part[1][tid] + part[2][tid] + part[3][tid];
    return;
  }

  if (idx >= 336) {  // ---- Wk copy fp32 -> bf16 ----
    const int base = (idx - 336) * 1024 + tid * 4;
    float4 v = *(const float4*)(Wk + base);
    bf16* dst = ws + WK_BF + base;
    dst[0] = (bf16)v.x; dst[1] = (bf16)v.y; dst[2] = (bf16)v.z; dst[3] = (bf16)v.w;
    return;
  }

  // ---- transposes ----
  const float* src; bf16* dst; int K; int tile;
  if (idx < 128)      { src = Wdyn;  dst = ws + WDYN_T;  K = 512; tile = idx; }
  else if (idx < 144) { src = Wstat; dst = ws + WSTAT_T; K = 64;  tile = idx - 128; }
  else if (idx < 208) { src = Wq;    dst = ws + WQ_T;    K = 256; tile = idx - 144; }
  else if (idx < 272) { src = Wv;    dst = ws + WV_T;    K = 256; tile = idx - 208; }
  else                { src = W1;    dst = ws + W1_T;    K = 256; tile = idx - 272; }
  const int ntk = K >> 5;
  const int kt = tile % ntk, nt = tile / ntk;
  const int k0 = kt * 32, n0 = nt * 32;
  const int c = tid & 31, r0 = tid >> 5;
#pragma unroll
  for (int i = 0; i < 4; ++i)
    t[r0 + 8 * i][c] = src[(size_t)(k0 + r0 + 8 * i) * 256 + n0 + c];
  __syncthreads();
#pragma unroll
  for (int i = 0; i < 4; ++i)
    dst[(size_t)(n0 + r0 + 8 * i) * K + k0 + c] = (bf16)t[c][r0 + 8 * i];
}

// ---------------------------------------------------------------------------
// pre: grid 512, 8 batch rows per WG (M=8 in 16-padded MFMA tiles).
// ---------------------------------------------------------------------------
__launch_bounds__(256, 2)
__global__ void pre_kernel(const float* __restrict__ h_dyn, const float* __restrict__ b_dyn,
                           const float* __restrict__ g_ndyn, const float* __restrict__ b_ndyn,
                           const float* __restrict__ bq, const float* __restrict__ bk,
                           const bf16* __restrict__ Wdyn_t, const bf16* __restrict__ Wq_t,
                           const bf16* __restrict__ Wk_bf,
                           float* __restrict__ h0_out, bf16* __restrict__ kq_out,
                           float* __restrict__ bkq_out) {
  __shared__ float h0t[8][264];
  __shared__ bf16 hlnt[8][264];
  __shared__ bf16 qt[8][264];
  const int tid = threadIdx.x;
  const int w = tid >> 6, lane = tid & 63, quad = lane >> 4, l16 = lane & 15;
  const int koff = quad * 8;
  const int b0 = blockIdx.x * 8;
  const int mrow = l16 & 7;  // duplicated A rows for the M=8 tile

  // h0 (K=512)
  {
    f32x4 acc[4];
#pragma unroll
    for (int nt = 0; nt < 4; ++nt) { f32x4 z = {0.f, 0.f, 0.f, 0.f}; acc[nt] = z; }
    const float* arow = h_dyn + (size_t)(b0 + mrow) * 512;
    for (int ks = 0; ks < 16; ++ks) {
      float4 x0 = *(const float4*)(arow + ks * 32 + koff);
      float4 x1 = *(const float4*)(arow + ks * 32 + koff + 4);
      bf16x8 a;
      a[0] = (bf16)x0.x; a[1] = (bf16)x0.y; a[2] = (bf16)x0.z; a[3] = (bf16)x0.w;
      a[4] = (bf16)x1.x; a[5] = (bf16)x1.y; a[6] = (bf16)x1.z; a[7] = (bf16)x1.w;
#pragma unroll
      for (int nt = 0; nt < 4; ++nt) {
        bf16x8 bw = *(const bf16x8*)(Wdyn_t + (size_t)(w * 64 + nt * 16 + l16) * 512 + ks * 32 + koff);
        acc[nt] = MFMA_B16(a, bw, acc[nt]);
      }
    }
    if (quad < 2) {
#pragma unroll
      for (int nt = 0; nt < 4; ++nt) {
        int col = w * 64 + nt * 16 + l16;
        float bb = b_dyn[col];
#pragma unroll
        for (int r = 0; r < 4; ++r) {
          int row = quad * 4 + r;
          float v = acc[nt][r] + bb;
          h0t[row][col] = v;
          h0_out[(size_t)(b0 + row) * 256 + col] = v;
        }
      }
    }
  }
  __syncthreads();

  // LN over 8 rows: wave w handles rows w and w+4
  {
    float gn[4], bn[4];
#pragma unroll
    for (int j = 0; j < 4; ++j) { gn[j] = g_ndyn[lane + 64 * j]; bn[j] = b_ndyn[lane + 64 * j]; }
#pragma unroll
    for (int i = 0; i < 2; ++i) {
      int row = 4 * i + w;
      float x[4]; float s = 0.f, ss = 0.f;
#pragma unroll
      for (int j = 0; j < 4; ++j) { x[j] = h0t[row][lane + 64 * j]; s += x[j]; ss += x[j] * x[j]; }
      s = wave_sum(s); ss = wave_sum(ss);
      float mean = s * (1.f / 256.f);
      float var = ss * (1.f / 256.f) - mean * mean;
      float rstd = 1.f / sqrtf(var + 1e-5f);
#pragma unroll
      for (int j = 0; j < 4; ++j)
        hlnt[row][lane + 64 * j] = (bf16)((x[j] - mean) * rstd * gn[j] + bn[j]);
    }
  }
  __syncthreads();

  // q = hln@Wq + bq -> qt
  {
    f32x4 acc[4];
#pragma unroll
    for (int nt = 0; nt < 4; ++nt) { f32x4 z = {0.f, 0.f, 0.f, 0.f}; acc[nt] = z; }
    for (int ks = 0; ks < 8; ++ks) {
      bf16x8 a = *(const bf16x8*)(&hlnt[mrow][ks * 32 + koff]);
#pragma unroll
      for (int nt = 0; nt < 4; ++nt) {
        bf16x8 bw = *(const bf16x8*)(Wq_t + (size_t)(w * 64 + nt * 16 + l16) * 256 + ks * 32 + koff);
        acc[nt] = MFMA_B16(a, bw, acc[nt]);
      }
    }
    if (quad < 2) {
#pragma unroll
      for (int nt = 0; nt < 4; ++nt) {
        int col = w * 64 + nt * 16 + l16;
        float bb = bq[col];
#pragma unroll
        for (int r = 0; r < 4; ++r)
          qt[quad * 4 + r][col] = (bf16)(acc[nt][r] + bb);
      }
    }
  }
  __syncthreads();

  // bkq[b,h] = bk_h . q_h
  {
    const int pair = tid >> 2;  // 0..63: row = pair>>2 (0..15), h = pair&3
    const int row = pair >> 2, h = pair & 3, sub = tid & 3;
    if (row < 8) {
      float p = 0.f;
#pragma unroll
      for (int j = 0; j < 16; ++j) {
        int e = sub * 16 + j;
        p += (float)qt[row][h * 64 + e] * bk[h * 64 + e];
      }
      p += __shfl_xor(p, 1, 64);
      p += __shfl_xor(p, 2, 64);
      if (sub == 0) bkq_out[(size_t)(b0 + row) * 4 + h] = p;
    }
  }

  // kq per head: M=8(b) K=64 N=256
  for (int h = 0; h < 4; ++h) {
    f32x4 acc[4];
#pragma unroll
    for (int nt = 0; nt < 4; ++nt) { f32x4 z = {0.f, 0.f, 0.f, 0.f}; acc[nt] = z; }
#pragma unroll
    for (int ks = 0; ks < 2; ++ks) {
      bf16x8 a = *(const bf16x8*)(&qt[mrow][h * 64 + ks * 32 + koff]);
#pragma unroll
      for (int nt = 0; nt < 4; ++nt) {
        bf16x8 bw = *(const bf16x8*)(Wk_bf + (size_t)(w * 64 + nt * 16 + l16) * 256 +
                                     h * 64 + ks * 32 + koff);
        acc[nt] = MFMA_B16(a, bw, acc[nt]);
      }
    }
    if (quad < 2) {
#pragma unroll
      for (int nt = 0; nt < 4; ++nt)
#pragma unroll
        for (int r = 0; r < 4; ++r)
          kq_out[(size_t)(b0 + quad * 4 + r) * 1024 + h * 256 + w * 64 + nt * 16 + l16] =
              (bf16)acc[nt][r];
    }
  }
}

// ---------------------------------------------------------------------------
// fused: per-batch chain s..c. grid 4096 x 256 thr, 4 blocks/CU.
// ---------------------------------------------------------------------------
__launch_bounds__(256, 4)
__global__ void fused_kernel(
    const float* __restrict__ x_stat, const float* __restrict__ b_stat,
    const float* __restrict__ g_nstat, const float* __restrict__ b_nstat,
    const float* __restrict__ bv, const float* __restrict__ g_mlp,
    const float* __restrict__ b_mlp, const float* __restrict__ b1,
    const float* __restrict__ bo, const float* __restrict__ res_scale_p,
    const float* __restrict__ h0g, const float* __restrict__ bkq_g,
    const float* __restrict__ b2o_g,
    const bf16* __restrict__ Wstat_t, const bf16* __restrict__ Wv_t,
    const bf16* __restrict__ W1_t, const bf16* __restrict__ W2o_t,
    const bf16* __restrict__ kq_g,
    float* __restrict__ out_c, float* __restrict__ out_wm) {

  __shared__ bf16 buf[64 * SROW];      // 33792 B
  __shared__ float part_s[4][64];
  __shared__ float part_ss[4][64];
  __shared__ float watt[4][64];
  __shared__ float swh[4];

  const int b = blockIdx.x;
  const int tid = threadIdx.x;
  const int w = tid >> 6, lane = tid & 63, quad = lane >> 4, l16 = lane & 15;
  const int koff = quad * 8;

  // ---- P1: s = x_stat @ W_stat + b_stat (swapped; K=64) ----
  {
    f32x4 acc[4][4];
    zero_acc(acc);
    const float* xb = x_stat + (size_t)b * 4096;
#pragma unroll
    for (int ks = 0; ks < 2; ++ks) {
      bf16x8 aw[4];
#pragma unroll
      for (int dt = 0; dt < 4; ++dt)
        aw[dt] = *(const bf16x8*)(Wstat_t + (size_t)(w * 64 + dt * 16 + l16) * 64 + ks * 32 + koff);
#pragma unroll
      for (int tt = 0; tt < 4; ++tt) {
        const float* xp = xb + (tt * 16 + l16) * 64 + ks * 32 + koff;
        float4 x0 = *(const float4*)xp;
        float4 x1 = *(const float4*)(xp + 4);
        bf16x8 bfrag;
        bfrag[0] = (bf16)x0.x; bfrag[1] = (bf16)x0.y; bfrag[2] = (bf16)x0.z; bfrag[3] = (bf16)x0.w;
        bfrag[4] = (bf16)x1.x; bfrag[5] = (bf16)x1.y; bfrag[6] = (bf16)x1.z; bfrag[7] = (bf16)x1.w;
#pragma unroll
        for (int dt = 0; dt < 4; ++dt) acc[dt][tt] = MFMA_B16(aw[dt], bfrag, acc[dt][tt]);
      }
    }
    store_swapped_stats(buf, b_stat, acc, w, quad, l16, part_s, part_ss);
  }
  __syncthreads();

  // ---- P2: LN(s) apply-only ----
  ln_finalize_apply(buf, g_nstat, b_nstat, part_s, part_ss, w, lane);
  __syncthreads();

  // ---- P3a: logits via kq (orig orientation; wave w -> tokens 16w..) ----
  {
    const bf16* kq_b = kq_g + (size_t)b * 1024;
    f32x4 accL = {0.f, 0.f, 0.f, 0.f};
#pragma unroll
    for (int ks = 0; ks < 8; ++ks) {
      bf16x8 a = *(const bf16x8*)(buf + (w * 16 + l16) * SROW + ks * 32 + koff);
      bf16x8 kf = zero8();
      if (l16 < 4) kf = *(const bf16x8*)(kq_b + l16 * 256 + ks * 32 + koff);
      accL = MFMA_B16(a, kf, accL);
    }
    float bkqv = (l16 < 4) ? bkq_g[(size_t)b * 4 + l16] : 0.f;
#pragma unroll
    for (int r = 0; r < 4; ++r) {
      float lg = (accL[r] + bkqv) * 0.125f;
      float sig = 1.f / (1.f + __expf(-lg));
      if (l16 < 4) watt[l16][w * 16 + quad * 4 + r] = sig;  // un-normalized
    }
  }

  // ---- P3b: v = s_ln @ Wv + bv (swapped), in-place ----
  {
    f32x4 acc[4][4];
    zero_acc(acc);
    gemm_swapped(buf, Wv_t, w, l16, koff, acc);
    __syncthreads();  // all s reads (P3a+P3b) done; watt(sig) visible
    // normalize attention weights (wave w == head w)
    {
      float v = watt[w][lane];
      float den = wave_sum(v);
      float dinv = 1.f / (den + 1e-6f);
      watt[w][lane] = v * dinv;
      if (lane == 0) swh[w] = den * dinv;
    }
    store_swapped_stats(buf, bv, acc, w, quad, l16, part_s, part_ss);
  }
  __syncthreads();

  // ---- P4: w_mean output + LN(v) apply-only ----
  if (tid < 64)
    out_wm[(size_t)b * 64 + tid] =
        0.25f * (watt[0][tid] + watt[1][tid] + watt[2][tid] + watt[3][tid]);
  ln_finalize_apply(buf, g_mlp, b_mlp, part_s, part_ss, w, lane);
  __syncthreads();

  // ---- P5: t1 = gelu(t_ln@W1 + b1) (swapped), in-place ----
  {
    f32x4 acc[4][4];
    zero_acc(acc);
    gemm_swapped(buf, W1_t, w, l16, koff, acc);
    __syncthreads();
#pragma unroll
    for (int dt = 0; dt < 4; ++dt) {
      const float4 bb = *(const float4*)(b1 + w * 64 + dt * 16 + quad * 4);
#pragma unroll
      for (int tt = 0; tt < 4; ++tt) {
        float v0 = acc[dt][tt][0] + bb.x;
        float v1 = acc[dt][tt][1] + bb.y;
        float v2 = acc[dt][tt][2] + bb.z;
        float v3 = acc[dt][tt][3] + bb.w;
        bf16x4 o;
        o[0] = (bf16)(v0 / (1.f + __expf(-1.702f * v0)));
        o[1] = (bf16)(v1 / (1.f + __expf(-1.702f * v1)));
        o[2] = (bf16)(v2 / (1.f + __expf(-1.702f * v2)));
        o[3] = (bf16)(v3 / (1.f + __expf(-1.702f * v3)));
        *(bf16x4*)(buf + (tt * 16 + l16) * SROW + w * 64 + dt * 16 + quad * 4) = o;
      }
    }
  }
  __syncthreads();

  // ---- P6: t1 @ W2o (orig orientation); z = watt . rows; c written ----
  {
    f32x4 acc[4][4];
    zero_acc(acc);
    gemm_orig(buf, W2o_t, w, l16, koff, acc);
    float zacc[4] = {0.f, 0.f, 0.f, 0.f};
#pragma unroll
    for (int mt = 0; mt < 4; ++mt)
#pragma unroll
      for (int r = 0; r < 4; ++r) {
        float wt = watt[w][mt * 16 + quad * 4 + r];
#pragma unroll
        for (int nt = 0; nt < 4; ++nt) zacc[nt] += wt * acc[mt][nt][r];
      }
#pragma unroll
    for (int nt = 0; nt < 4; ++nt) {
      zacc[nt] += __shfl_xor(zacc[nt], 16, 64);
      zacc[nt] += __shfl_xor(zacc[nt], 32, 64);
    }
    if (quad == 0) {
      float rs = *res_scale_p;
#pragma unroll
      for (int nt = 0; nt < 4; ++nt) {
        int col = w * 64 + nt * 16 + l16;
        float res = zacc[nt] + swh[w] * b2o_g[col] + bo[col];
        out_c[(size_t)b * 256 + col] = h0g[(size_t)b * 256 + col] + rs * res;
      }
    }
  }
}

extern "C" void kernel_launch(void* const* d_in, const int* in_sizes, int n_in,
                              void* d_out, int out_size, void* d_ws, size_t ws_size,
                              hipStream_t stream) {
  const float* h_dyn   = (const float*)d_in[0];
  const float* x_stat  = (const float*)d_in[1];
  const float* W_dyn   = (const float*)d_in[2];
  const float* b_dyn   = (const float*)d_in[3];
  const float* W_stat  = (const float*)d_in[4];
  const float* b_stat  = (const float*)d_in[5];
  const float* g_ndyn  = (const float*)d_in[6];
  const float* b_ndyn  = (const float*)d_in[7];
  const float* g_nstat = (const float*)d_in[8];
  const float* b_nstat = (const float*)d_in[9];
  const float* Wq = (const float*)d_in[10];
  const float* bq = (const float*)d_in[11];
  const float* Wk = (const float*)d_in[12];
  const float* bk = (const float*)d_in[13];
  const float* Wv = (const float*)d_in[14];
  const float* bv = (const float*)d_in[15];
  const float* g_mlp = (const float*)d_in[16];
  const float* b_mlp = (const float*)d_in[17];
  const float* W1 = (const float*)d_in[18];
  const float* b1 = (const float*)d_in[19];
  const float* W2 = (const float*)d_in[20];
  const float* b2 = (const float*)d_in[21];
  const float* Wo = (const float*)d_in[22];
  const float* bo = (const float*)d_in[23];
  const float* rs = (const float*)d_in[24];

  bf16* ws = (bf16*)d_ws;
  float* wsf = (float*)d_ws;
  float* ws_h0  = wsf + H0_F;
  float* ws_bkq = wsf + BKQ_F;
  float* ws_b2o = wsf + B2O_F;

  prep_kernel<<<432, 256, 0, stream>>>(W_dyn, W_stat, Wq, Wk, Wv, W1, W2, Wo, b2,
                                       ws, ws_b2o);

  pre_kernel<<<512, 256, 0, stream>>>(h_dyn, b_dyn, g_ndyn, b_ndyn, bq, bk,
                                      ws + WDYN_T, ws + WQ_T, ws + WK_BF,
                                      ws_h0, ws + KQ_BF, ws_bkq);

  float* out_c = (float*)d_out;
  float* out_wm = out_c + (size_t)4096 * 256;
  fused_kernel<<<4096, 256, 0, stream>>>(
      x_stat, b_stat, g_nstat, b_nstat, bv, g_mlp, b_mlp, b1, bo, rs,
      ws_h0, ws_bkq, ws_b2o,
      ws + WSTAT_T, ws + WV_T, ws + W1_T, ws + W2O_T, ws + KQ_BF,
      out_c, out_wm);
}

// Round 5
// 340.038 us; speedup vs baseline: 2.2222x; 1.2726x over previous
//
#include <hip/hip_runtime.h>
#include <cmath>

// ============================================================================
// SpatialContextSet — round 5.
// Key change vs r4: ALL MFMA operands streamed from global are pre-packed in
// fragment order ([w][ks][x][lane][8] bf16) so every load is one coalesced
// 1KB wave-load with uniform base + lane*16 addressing, register
// double-buffered across ks. x_stat is pre-packed per batch (8KB contiguous
// bf16) removing inner-loop fp32->bf16 cvt.
// Kernels: prep1 (xpack + W2o=W2@Wo fold + pack all weights except W2o),
//          prep2 (pack W2o), pre (h0/LN/q/kq/bkq), fused (s..c).
// ============================================================================

typedef __bf16 bf16;
typedef bf16 bf16x4 __attribute__((ext_vector_type(4)));
typedef bf16 bf16x8 __attribute__((ext_vector_type(8)));
typedef float f32x4 __attribute__((ext_vector_type(4)));

#define MFMA_B16(a, b, c) __builtin_amdgcn_mfma_f32_16x16x32_bf16((a), (b), (c), 0, 0, 0)

constexpr int SROW = 264;  // LDS buf row stride bf16 (528 B)

// ---- workspace layout (bf16 element offsets) ----
constexpr size_t WSTAT_P = 0;          // packed, 4w*2ks*2048 = 16384
constexpr size_t WV_P    = 16384;      // 4w*8ks*2048 = 65536
constexpr size_t W1_P    = 81920;      // 65536
constexpr size_t W2O_P   = 147456;     // 65536
constexpr size_t WDYN_P  = 212992;     // 4w*16ks*2048 = 131072
constexpr size_t WQ_P    = 344064;     // 65536
constexpr size_t WK_P    = 409600;     // 65536 (trans-packed)
constexpr size_t KQ_BF   = 475136;     // [4096][4][256] = 4194304
constexpr size_t XP_BF   = 4669440;    // [4096][4096] = 16777216 -> ends 21446656
// float element offsets (from (float*)ws):
constexpr size_t H0_F   = 10723328;    // [4096][256]
constexpr size_t BKQ_F  = 11771904;    // [4096][4]
constexpr size_t B2O_F  = 11788288;    // [256]
constexpr size_t W2OS_F = 11788544;    // fp32 scratch W2o [256][256]

__device__ __forceinline__ bf16x8 zero8() {
  bf16x8 z;
#pragma unroll
  for (int j = 0; j < 8; ++j) z[j] = (bf16)0.0f;
  return z;
}

__device__ __forceinline__ float wave_sum(float v) {
#pragma unroll
  for (int m = 1; m < 64; m <<= 1) v += __shfl_xor(v, m, 64);
  return v;
}

__device__ __forceinline__ void zero_acc(f32x4 (&acc)[4][4]) {
#pragma unroll
  for (int mt = 0; mt < 4; ++mt)
#pragma unroll
    for (int nt = 0; nt < 4; ++nt) { f32x4 z = {0.f, 0.f, 0.f, 0.f}; acc[mt][nt] = z; }
}

// ---- packed swapped GEMM (K=256): A=packed W frags (global), B=buf rows (LDS)
// acc[dt][tt] -> (dim = w*64+dt*16+quad*4+r, token = tt*16+l16)
__device__ __forceinline__ void gemm_swapped_p(const bf16* buf, const bf16* __restrict__ Wp,
                                               int w, int lane, int l16, int koff,
                                               f32x4 (&acc)[4][4]) {
  const bf16* base = Wp + (size_t)w * 8 * 2048 + lane * 8;
  bf16x8 aw[2][4];
#pragma unroll
  for (int dt = 0; dt < 4; ++dt) aw[0][dt] = *(const bf16x8*)(base + dt * 512);
#pragma unroll
  for (int ks = 0; ks < 8; ++ks) {
    const int cur = ks & 1;
    if (ks < 7) {
#pragma unroll
      for (int dt = 0; dt < 4; ++dt)
        aw[cur ^ 1][dt] = *(const bf16x8*)(base + (ks + 1) * 2048 + dt * 512);
    }
#pragma unroll
    for (int tt = 0; tt < 4; ++tt) {
      bf16x8 bfrag = *(const bf16x8*)(buf + (tt * 16 + l16) * SROW + ks * 32 + koff);
#pragma unroll
      for (int dt = 0; dt < 4; ++dt) acc[dt][tt] = MFMA_B16(aw[cur][dt], bfrag, acc[dt][tt]);
    }
  }
}

// ---- packed original-orientation GEMM (P6): A=buf rows (LDS), B=packed W frags
__device__ __forceinline__ void gemm_orig_p(const bf16* buf, const bf16* __restrict__ Wp,
                                            int w, int lane, int l16, int koff,
                                            f32x4 (&acc)[4][4]) {
  const bf16* base = Wp + (size_t)w * 8 * 2048 + lane * 8;
  bf16x8 bw[2][4];
#pragma unroll
  for (int nt = 0; nt < 4; ++nt) bw[0][nt] = *(const bf16x8*)(base + nt * 512);
#pragma unroll
  for (int ks = 0; ks < 8; ++ks) {
    const int cur = ks & 1;
    if (ks < 7) {
#pragma unroll
      for (int nt = 0; nt < 4; ++nt)
        bw[cur ^ 1][nt] = *(const bf16x8*)(base + (ks + 1) * 2048 + nt * 512);
    }
#pragma unroll
    for (int mt = 0; mt < 4; ++mt) {
      bf16x8 a = *(const bf16x8*)(buf + (mt * 16 + l16) * SROW + ks * 32 + koff);
#pragma unroll
      for (int nt = 0; nt < 4; ++nt) acc[mt][nt] = MFMA_B16(a, bw[cur][nt], acc[mt][nt]);
    }
  }
}

// ---- swapped epilogue: b64 stores + per-token LN partials
__device__ __forceinline__ void store_swapped_stats(bf16* buf, const float* __restrict__ bsrc,
                                                    f32x4 (&acc)[4][4], int w, int quad, int l16,
                                                    float (*part_s)[64], float (*part_ss)[64]) {
  float ps[4] = {0.f, 0.f, 0.f, 0.f}, pq[4] = {0.f, 0.f, 0.f, 0.f};
#pragma unroll
  for (int dt = 0; dt < 4; ++dt) {
    const float4 bb = *(const float4*)(bsrc + w * 64 + dt * 16 + quad * 4);
#pragma unroll
    for (int tt = 0; tt < 4; ++tt) {
      float v0 = acc[dt][tt][0] + bb.x;
      float v1 = acc[dt][tt][1] + bb.y;
      float v2 = acc[dt][tt][2] + bb.z;
      float v3 = acc[dt][tt][3] + bb.w;
      ps[tt] += (v0 + v1) + (v2 + v3);
      pq[tt] += v0 * v0 + v1 * v1 + v2 * v2 + v3 * v3;
      bf16x4 o;
      o[0] = (bf16)v0; o[1] = (bf16)v1; o[2] = (bf16)v2; o[3] = (bf16)v3;
      *(bf16x4*)(buf + (tt * 16 + l16) * SROW + w * 64 + dt * 16 + quad * 4) = o;
    }
  }
#pragma unroll
  for (int tt = 0; tt < 4; ++tt) {
    ps[tt] += __shfl_xor(ps[tt], 16, 64); ps[tt] += __shfl_xor(ps[tt], 32, 64);
    pq[tt] += __shfl_xor(pq[tt], 16, 64); pq[tt] += __shfl_xor(pq[tt], 32, 64);
  }
  if (quad == 0) {
#pragma unroll
    for (int tt = 0; tt < 4; ++tt) {
      part_s[w][tt * 16 + l16] = ps[tt];
      part_ss[w][tt * 16 + l16] = pq[tt];
    }
  }
}

// ---- apply-only LN
__device__ __forceinline__ void ln_finalize_apply(bf16* buf, const float* __restrict__ g,
                                                  const float* __restrict__ bsh,
                                                  const float (*part_s)[64],
                                                  const float (*part_ss)[64], int w, int lane) {
  float psum = (part_s[0][lane] + part_s[1][lane]) + (part_s[2][lane] + part_s[3][lane]);
  float pqq  = (part_ss[0][lane] + part_ss[1][lane]) + (part_ss[2][lane] + part_ss[3][lane]);
  float mean = psum * (1.f / 256.f);
  float var  = pqq * (1.f / 256.f) - mean * mean;
  float rstd = 1.f / sqrtf(var + 1e-5f);
  const float4 gv = *(const float4*)(g + lane * 4);
  const float4 bv4 = *(const float4*)(bsh + lane * 4);
#pragma unroll
  for (int i = 0; i < 16; ++i) {
    const int row = 4 * i + w;
    const float mb = __shfl(mean, row, 64);
    const float rb = __shfl(rstd, row, 64);
    bf16* rp = buf + row * SROW + lane * 4;
    bf16x4 xv = *(const bf16x4*)rp;
    bf16x4 o;
    o[0] = (bf16)(((float)xv[0] - mb) * rb * gv.x + bv4.x);
    o[1] = (bf16)(((float)xv[1] - mb) * rb * gv.y + bv4.y);
    o[2] = (bf16)(((float)xv[2] - mb) * rb * gv.z + bv4.z);
    o[3] = (bf16)(((float)xv[3] - mb) * rb * gv.w + bv4.w);
    *(bf16x4*)rp = o;
  }
}

// ---- generic fragment packer: one (w,ks) slice -> 2048 bf16
// value(x,quad,l16,j) = trans ? src[n*256+k] : src[k*256+n],
//   k = ks*32+quad*8+j, n = w*64+x*16+l16.  dst_block = dst + (w*KS+ks)*2048
template <typename SrcT>
__device__ __forceinline__ void pack_slice(const SrcT* __restrict__ src, bf16* __restrict__ dstb,
                                           int w, int ks, bool trans, float* sh, int tid) {
  if (!trans) {
#pragma unroll
    for (int i = 0; i < 8; ++i) {
      int r = i * 4 + (tid >> 6), c = tid & 63;
      sh[r * 65 + c] = (float)src[(size_t)(ks * 32 + r) * 256 + w * 64 + c];
    }
  } else {
    int c = tid >> 2, j8 = tid & 3;
#pragma unroll
    for (int jj = 0; jj < 8; ++jj) {
      int r = j8 * 8 + jj;
      sh[r * 65 + c] = (float)src[(size_t)(w * 64 + c) * 256 + ks * 32 + r];
    }
  }
  __syncthreads();
  const int x = tid >> 6, quad = (tid >> 4) & 3, l16 = tid & 15;
  bf16x8 o;
#pragma unroll
  for (int j = 0; j < 8; ++j) o[j] = (bf16)sh[(quad * 8 + j) * 65 + x * 16 + l16];
  *(bf16x8*)(dstb + tid * 8) = o;
}

// ---------------------------------------------------------------------------
// prep1: blocks [0,4096)=xpack, [4096,4128)=W2o fold, [4128,4328)=weight pack
// ---------------------------------------------------------------------------
__global__ void prep1_kernel(const float* __restrict__ x_stat,
                             const float* __restrict__ Wdyn, const float* __restrict__ Wstat,
                             const float* __restrict__ Wq, const float* __restrict__ Wk,
                             const float* __restrict__ Wv, const float* __restrict__ W1,
                             const float* __restrict__ W2, const float* __restrict__ Wo,
                             const float* __restrict__ b2,
                             bf16* __restrict__ ws, float* __restrict__ wsf) {
  __shared__ float sh[64 * 65];
  __shared__ float part[4][8];
  const int idx = blockIdx.x;
  const int tid = threadIdx.x;

  if (idx < 4096) {  // ---- xpack: x[b] -> fragment-ordered bf16 ----
    const float* xb = x_stat + (size_t)idx * 4096;
#pragma unroll
    for (int j = 0; j < 4; ++j) {
      int lin = j * 1024 + tid * 4;
      float4 v = *(const float4*)(xb + lin);
      int r = lin >> 6, c = lin & 63;
      sh[r * 65 + c] = v.x; sh[r * 65 + c + 1] = v.y;
      sh[r * 65 + c + 2] = v.z; sh[r * 65 + c + 3] = v.w;
    }
    __syncthreads();
    bf16* xp = ws + XP_BF + (size_t)idx * 4096;
#pragma unroll
    for (int half = 0; half < 2; ++half) {
      int s = half * 256 + tid;
      int ksq = s >> 6, lane = s & 63;
      int token = (ksq & 3) * 16 + (lane & 15);
      int f0 = (ksq >> 2) * 32 + (lane >> 4) * 8;
      bf16x8 o;
#pragma unroll
      for (int j = 0; j < 8; ++j) o[j] = (bf16)sh[token * 65 + f0 + j];
      *(bf16x8*)(xp + s * 8) = o;
    }
    return;
  }

  if (idx < 4128) {  // ---- W2o = W2@Wo fold -> fp32 scratch [k][n]; b2o ----
    const int n0 = (idx - 4096) * 8;
    float4 a0 = *(const float4*)(Wo + (size_t)tid * 256 + n0);
    float4 a1 = *(const float4*)(Wo + (size_t)tid * 256 + n0 + 4);
    sh[tid * 8 + 0] = a0.x; sh[tid * 8 + 1] = a0.y; sh[tid * 8 + 2] = a0.z; sh[tid * 8 + 3] = a0.w;
    sh[tid * 8 + 4] = a1.x; sh[tid * 8 + 5] = a1.y; sh[tid * 8 + 6] = a1.z; sh[tid * 8 + 7] = a1.w;
    __syncthreads();
    float acc[8] = {0.f, 0.f, 0.f, 0.f, 0.f, 0.f, 0.f, 0.f};
    const float* row = W2 + (size_t)tid * 256;
    for (int d0 = 0; d0 < 256; d0 += 4) {
      float4 wv = *(const float4*)(row + d0);
#pragma unroll
      for (int dd = 0; dd < 4; ++dd) {
        float r = (dd == 0) ? wv.x : (dd == 1) ? wv.y : (dd == 2) ? wv.z : wv.w;
        const float* cc = &sh[(d0 + dd) * 8];
#pragma unroll
        for (int j = 0; j < 8; ++j) acc[j] += r * cc[j];
      }
    }
    float* dst = wsf + W2OS_F;
#pragma unroll
    for (int j = 0; j < 8; ++j) dst[(size_t)tid * 256 + n0 + j] = acc[j];
    const int w = tid >> 6, lane = tid & 63;
    float bval = b2[tid];
#pragma unroll
    for (int j = 0; j < 8; ++j) {
      float p = wave_sum(bval * sh[tid * 8 + j]);
      if (lane == 0) part[w][j] = p;
    }
    __syncthreads();
    if (tid < 8)
      wsf[B2O_F + n0 + tid] = part[0][tid] + part[1][tid] + part[2][tid] + part[3][tid];
    return;
  }

  // ---- weight packing ----
  int t = idx - 4128;
  const float* src; bf16* dst; int KS; bool trans = false;
  if (t < 64)       { src = Wdyn;  dst = ws + WDYN_P;  KS = 16; }
  else if (t < 72)  { src = Wstat; dst = ws + WSTAT_P; KS = 2;  t -= 64; }
  else if (t < 104) { src = Wq;    dst = ws + WQ_P;    KS = 8;  t -= 72; }
  else if (t < 136) { src = Wv;    dst = ws + WV_P;    KS = 8;  t -= 104; }
  else if (t < 168) { src = W1;    dst = ws + W1_P;    KS = 8;  t -= 136; }
  else              { src = Wk;    dst = ws + WK_P;    KS = 8;  t -= 168; trans = true; }
  const int w = t / KS, ks = t % KS;
  pack_slice<float>(src, dst + (size_t)(w * KS + ks) * 2048, w, ks, trans, sh, tid);
}

// prep2: pack W2o from fp32 scratch (32 blocks)
__global__ void prep2_kernel(const float* __restrict__ wsf_scr, bf16* __restrict__ ws) {
  __shared__ float sh[64 * 65];
  const int t = blockIdx.x;
  const int w = t >> 3, ks = t & 7;
  pack_slice<float>(wsf_scr, ws + W2O_P + (size_t)(w * 8 + ks) * 2048, w, ks, false, sh,
                    threadIdx.x);
}

// ---------------------------------------------------------------------------
// pre: grid 512, 8 batch rows per WG.
// ---------------------------------------------------------------------------
__launch_bounds__(256, 2)
__global__ void pre_kernel(const float* __restrict__ h_dyn, const float* __restrict__ b_dyn,
                           const float* __restrict__ g_ndyn, const float* __restrict__ b_ndyn,
                           const float* __restrict__ bq, const float* __restrict__ bk,
                           const bf16* __restrict__ Wdyn_p, const bf16* __restrict__ Wq_p,
                           const bf16* __restrict__ Wk_p,
                           float* __restrict__ h0_out, bf16* __restrict__ kq_out,
                           float* __restrict__ bkq_out) {
  __shared__ float h0t[8][264];
  __shared__ bf16 hlnt[8][264];
  __shared__ bf16 qt[8][264];
  const int tid = threadIdx.x;
  const int w = tid >> 6, lane = tid & 63, quad = lane >> 4, l16 = lane & 15;
  const int koff = quad * 8;
  const int b0 = blockIdx.x * 8;
  const int mrow = l16 & 7;

  // h0 (K=512), packed weights
  {
    f32x4 acc[4];
#pragma unroll
    for (int nt = 0; nt < 4; ++nt) { f32x4 z = {0.f, 0.f, 0.f, 0.f}; acc[nt] = z; }
    const float* arow = h_dyn + (size_t)(b0 + mrow) * 512;
    const bf16* base = Wdyn_p + (size_t)w * 16 * 2048 + lane * 8;
    for (int ks = 0; ks < 16; ++ks) {
      float4 x0 = *(const float4*)(arow + ks * 32 + koff);
      float4 x1 = *(const float4*)(arow + ks * 32 + koff + 4);
      bf16x8 a;
      a[0] = (bf16)x0.x; a[1] = (bf16)x0.y; a[2] = (bf16)x0.z; a[3] = (bf16)x0.w;
      a[4] = (bf16)x1.x; a[5] = (bf16)x1.y; a[6] = (bf16)x1.z; a[7] = (bf16)x1.w;
#pragma unroll
      for (int nt = 0; nt < 4; ++nt) {
        bf16x8 bw = *(const bf16x8*)(base + ks * 2048 + nt * 512);
        acc[nt] = MFMA_B16(a, bw, acc[nt]);
      }
    }
    if (quad < 2) {
#pragma unroll
      for (int nt = 0; nt < 4; ++nt) {
        int col = w * 64 + nt * 16 + l16;
        float bb = b_dyn[col];
#pragma unroll
        for (int r = 0; r < 4; ++r) {
          int row = quad * 4 + r;
          float v = acc[nt][r] + bb;
          h0t[row][col] = v;
          h0_out[(size_t)(b0 + row) * 256 + col] = v;
        }
      }
    }
  }
  __syncthreads();

  // LN over 8 rows
  {
    float gn[4], bn[4];
#pragma unroll
    for (int j = 0; j < 4; ++j) { gn[j] = g_ndyn[lane + 64 * j]; bn[j] = b_ndyn[lane + 64 * j]; }
#pragma unroll
    for (int i = 0; i < 2; ++i) {
      int row = 4 * i + w;
      float x[4]; float s = 0.f, ss = 0.f;
#pragma unroll
      for (int j = 0; j < 4; ++j) { x[j] = h0t[row][lane + 64 * j]; s += x[j]; ss += x[j] * x[j]; }
      s = wave_sum(s); ss = wave_sum(ss);
      float mean = s * (1.f / 256.f);
      float var = ss * (1.f / 256.f) - mean * mean;
      float rstd = 1.f / sqrtf(var + 1e-5f);
#pragma unroll
      for (int j = 0; j < 4; ++j)
        hlnt[row][lane + 64 * j] = (bf16)((x[j] - mean) * rstd * gn[j] + bn[j]);
    }
  }
  __syncthreads();

  // q = hln@Wq + bq (packed)
  {
    f32x4 acc[4];
#pragma unroll
    for (int nt = 0; nt < 4; ++nt) { f32x4 z = {0.f, 0.f, 0.f, 0.f}; acc[nt] = z; }
    const bf16* base = Wq_p + (size_t)w * 8 * 2048 + lane * 8;
    for (int ks = 0; ks < 8; ++ks) {
      bf16x8 a = *(const bf16x8*)(&hlnt[mrow][ks * 32 + koff]);
#pragma unroll
      for (int nt = 0; nt < 4; ++nt) {
        bf16x8 bw = *(const bf16x8*)(base + ks * 2048 + nt * 512);
        acc[nt] = MFMA_B16(a, bw, acc[nt]);
      }
    }
    if (quad < 2) {
#pragma unroll
      for (int nt = 0; nt < 4; ++nt) {
        int col = w * 64 + nt * 16 + l16;
        float bb = bq[col];
#pragma unroll
        for (int r = 0; r < 4; ++r)
          qt[quad * 4 + r][col] = (bf16)(acc[nt][r] + bb);
      }
    }
  }
  __syncthreads();

  // bkq[b,h] = bk_h . q_h
  {
    const int pair = tid >> 2;
    const int row = pair >> 2, h = pair & 3, sub = tid & 3;
    if (row < 8) {
      float p = 0.f;
#pragma unroll
      for (int j = 0; j < 16; ++j) {
        int e = sub * 16 + j;
        p += (float)qt[row][h * 64 + e] * bk[h * 64 + e];
      }
      p += __shfl_xor(p, 1, 64);
      p += __shfl_xor(p, 2, 64);
      if (sub == 0) bkq_out[(size_t)(b0 + row) * 4 + h] = p;
    }
  }

  // kq per head (packed Wk: kslot = h*2+ks)
  for (int h = 0; h < 4; ++h) {
    f32x4 acc[4];
#pragma unroll
    for (int nt = 0; nt < 4; ++nt) { f32x4 z = {0.f, 0.f, 0.f, 0.f}; acc[nt] = z; }
    const bf16* base = Wk_p + (size_t)w * 8 * 2048 + lane * 8;
#pragma unroll
    for (int ks = 0; ks < 2; ++ks) {
      bf16x8 a = *(const bf16x8*)(&qt[mrow][h * 64 + ks * 32 + koff]);
#pragma unroll
      for (int nt = 0; nt < 4; ++nt) {
        bf16x8 bw = *(const bf16x8*)(base + (h * 2 + ks) * 2048 + nt * 512);
        acc[nt] = MFMA_B16(a, bw, acc[nt]);
      }
    }
    if (quad < 2) {
#pragma unroll
      for (int nt = 0; nt < 4; ++nt)
#pragma unroll
        for (int r = 0; r < 4; ++r)
          kq_out[(size_t)(b0 + quad * 4 + r) * 1024 + h * 256 + w * 64 + nt * 16 + l16] =
              (bf16)acc[nt][r];
    }
  }
}

// ---------------------------------------------------------------------------
// fused: per-batch chain s..c. grid 4096 x 256 thr, 4 blocks/CU.
// ---------------------------------------------------------------------------
__launch_bounds__(256, 4)
__global__ void fused_kernel(
    const float* __restrict__ b_stat,
    const float* __restrict__ g_nstat, const float* __restrict__ b_nstat,
    const float* __restrict__ bv, const float* __restrict__ g_mlp,
    const float* __restrict__ b_mlp, const float* __restrict__ b1,
    const float* __restrict__ bo, const float* __restrict__ res_scale_p,
    const float* __restrict__ h0g, const float* __restrict__ bkq_g,
    const float* __restrict__ b2o_g,
    const bf16* __restrict__ Wstat_p, const bf16* __restrict__ Wv_p,
    const bf16* __restrict__ W1_p, const bf16* __restrict__ W2o_p,
    const bf16* __restrict__ kq_g, const bf16* __restrict__ xp_g,
    float* __restrict__ out_c, float* __restrict__ out_wm) {

  __shared__ bf16 buf[64 * SROW];
  __shared__ float part_s[4][64];
  __shared__ float part_ss[4][64];
  __shared__ float watt[4][64];
  __shared__ float swh[4];

  const int b = blockIdx.x;
  const int tid = threadIdx.x;
  const int w = tid >> 6, lane = tid & 63, quad = lane >> 4, l16 = lane & 15;
  const int koff = quad * 8;

  // ---- P1: s = x @ W_stat + b_stat (swapped; K=64; all operands packed) ----
  {
    f32x4 acc[4][4];
    zero_acc(acc);
    const bf16* xp_b = xp_g + (size_t)b * 4096 + lane * 8;
    const bf16* wsb = Wstat_p + (size_t)w * 2 * 2048 + lane * 8;
#pragma unroll
    for (int ks = 0; ks < 2; ++ks) {
      bf16x8 aw[4];
#pragma unroll
      for (int dt = 0; dt < 4; ++dt)
        aw[dt] = *(const bf16x8*)(wsb + ks * 2048 + dt * 512);
#pragma unroll
      for (int tt = 0; tt < 4; ++tt) {
        bf16x8 bfrag = *(const bf16x8*)(xp_b + (ks * 4 + tt) * 512);
#pragma unroll
        for (int dt = 0; dt < 4; ++dt) acc[dt][tt] = MFMA_B16(aw[dt], bfrag, acc[dt][tt]);
      }
    }
    store_swapped_stats(buf, b_stat, acc, w, quad, l16, part_s, part_ss);
  }
  __syncthreads();

  // ---- P2: LN(s) apply-only ----
  ln_finalize_apply(buf, g_nstat, b_nstat, part_s, part_ss, w, lane);
  __syncthreads();

  // ---- P3a: logits via kq ----
  {
    const bf16* kq_b = kq_g + (size_t)b * 1024;
    f32x4 accL = {0.f, 0.f, 0.f, 0.f};
#pragma unroll
    for (int ks = 0; ks < 8; ++ks) {
      bf16x8 a = *(const bf16x8*)(buf + (w * 16 + l16) * SROW + ks * 32 + koff);
      bf16x8 kf = zero8();
      if (l16 < 4) kf = *(const bf16x8*)(kq_b + l16 * 256 + ks * 32 + koff);
      accL = MFMA_B16(a, kf, accL);
    }
    float bkqv = (l16 < 4) ? bkq_g[(size_t)b * 4 + l16] : 0.f;
#pragma unroll
    for (int r = 0; r < 4; ++r) {
      float lg = (accL[r] + bkqv) * 0.125f;
      float sig = 1.f / (1.f + __expf(-lg));
      if (l16 < 4) watt[l16][w * 16 + quad * 4 + r] = sig;  // un-normalized
    }
  }

  // ---- P3b: v = s_ln @ Wv + bv (swapped, packed), in-place ----
  {
    f32x4 acc[4][4];
    zero_acc(acc);
    gemm_swapped_p(buf, Wv_p, w, lane, l16, koff, acc);
    __syncthreads();
    {
      float v = watt[w][lane];
      float den = wave_sum(v);
      float dinv = 1.f / (den + 1e-6f);
      watt[w][lane] = v * dinv;
      if (lane == 0) swh[w] = den * dinv;
    }
    store_swapped_stats(buf, bv, acc, w, quad, l16, part_s, part_ss);
  }
  __syncthreads();

  // ---- P4: w_mean + LN(v) apply-only ----
  if (tid < 64)
    out_wm[(size_t)b * 64 + tid] =
        0.25f * (watt[0][tid] + watt[1][tid] + watt[2][tid] + watt[3][tid]);
  ln_finalize_apply(buf, g_mlp, b_mlp, part_s, part_ss, w, lane);
  __syncthreads();

  // ---- P5: t1 = gelu(t_ln@W1 + b1) (swapped, packed), in-place ----
  {
    f32x4 acc[4][4];
    zero_acc(acc);
    gemm_swapped_p(buf, W1_p, w, lane, l16, koff, acc);
    __syncthreads();
#pragma unroll
    for (int dt = 0; dt < 4; ++dt) {
      const float4 bb = *(const float4*)(b1 + w * 64 + dt * 16 + quad * 4);
#pragma unroll
      for (int tt = 0; tt < 4; ++tt) {
        float v0 = acc[dt][tt][0] + bb.x;
        float v1 = acc[dt][tt][1] + bb.y;
        float v2 = acc[dt][tt][2] + bb.z;
        float v3 = acc[dt][tt][3] + bb.w;
        bf16x4 o;
        o[0] = (bf16)(v0 / (1.f + __expf(-1.702f * v0)));
        o[1] = (bf16)(v1 / (1.f + __expf(-1.702f * v1)));
        o[2] = (bf16)(v2 / (1.f + __expf(-1.702f * v2)));
        o[3] = (bf16)(v3 / (1.f + __expf(-1.702f * v3)));
        *(bf16x4*)(buf + (tt * 16 + l16) * SROW + w * 64 + dt * 16 + quad * 4) = o;
      }
    }
  }
  __syncthreads();

  // ---- P6: t1 @ W2o (orig, packed); z = watt . rows; c written ----
  {
    f32x4 acc[4][4];
    zero_acc(acc);
    gemm_orig_p(buf, W2o_p, w, lane, l16, koff, acc);
    float zacc[4] = {0.f, 0.f, 0.f, 0.f};
#pragma unroll
    for (int mt = 0; mt < 4; ++mt)
#pragma unroll
      for (int r = 0; r < 4; ++r) {
        float wt = watt[w][mt * 16 + quad * 4 + r];
#pragma unroll
        for (int nt = 0; nt < 4; ++nt) zacc[nt] += wt * acc[mt][nt][r];
      }
#pragma unroll
    for (int nt = 0; nt < 4; ++nt) {
      zacc[nt] += __shfl_xor(zacc[nt], 16, 64);
      zacc[nt] += __shfl_xor(zacc[nt], 32, 64);
    }
    if (quad == 0) {
      float rs = *res_scale_p;
#pragma unroll
      for (int nt = 0; nt < 4; ++nt) {
        int col = w * 64 + nt * 16 + l16;
        float res = zacc[nt] + swh[w] * b2o_g[col] + bo[col];
        out_c[(size_t)b * 256 + col] = h0g[(size_t)b * 256 + col] + rs * res;
      }
    }
  }
}

extern "C" void kernel_launch(void* const* d_in, const int* in_sizes, int n_in,
                              void* d_out, int out_size, void* d_ws, size_t ws_size,
                              hipStream_t stream) {
  const float* h_dyn   = (const float*)d_in[0];
  const float* x_stat  = (const float*)d_in[1];
  const float* W_dyn   = (const float*)d_in[2];
  const float* b_dyn   = (const float*)d_in[3];
  const float* W_stat  = (const float*)d_in[4];
  const float* b_stat  = (const float*)d_in[5];
  const float* g_ndyn  = (const float*)d_in[6];
  const float* b_ndyn  = (const float*)d_in[7];
  const float* g_nstat = (const float*)d_in[8];
  const float* b_nstat = (const float*)d_in[9];
  const float* Wq = (const float*)d_in[10];
  const float* bq = (const float*)d_in[11];
  const float* Wk = (const float*)d_in[12];
  const float* bk = (const float*)d_in[13];
  const float* Wv = (const float*)d_in[14];
  const float* bv = (const float*)d_in[15];
  const float* g_mlp = (const float*)d_in[16];
  const float* b_mlp = (const float*)d_in[17];
  const float* W1 = (const float*)d_in[18];
  const float* b1 = (const float*)d_in[19];
  const float* W2 = (const float*)d_in[20];
  const float* b2 = (const float*)d_in[21];
  const float* Wo = (const float*)d_in[22];
  const float* bo = (const float*)d_in[23];
  const float* rs = (const float*)d_in[24];

  bf16* ws = (bf16*)d_ws;
  float* wsf = (float*)d_ws;

  prep1_kernel<<<4328, 256, 0, stream>>>(x_stat, W_dyn, W_stat, Wq, Wk, Wv, W1, W2, Wo, b2,
                                         ws, wsf);
  prep2_kernel<<<32, 256, 0, stream>>>(wsf + W2OS_F, ws);

  pre_kernel<<<512, 256, 0, stream>>>(h_dyn, b_dyn, g_ndyn, b_ndyn, bq, bk,
                                      ws + WDYN_P, ws + WQ_P, ws + WK_P,
                                      wsf + H0_F, ws + KQ_BF, wsf + BKQ_F);

  float* out_c = (float*)d_out;
  float* out_wm = out_c + (size_t)4096 * 256;
  fused_kernel<<<4096, 256, 0, stream>>>(
      b_stat, g_nstat, b_nstat, bv, g_mlp, b_mlp, b1, bo, rs,
      wsf + H0_F, wsf + BKQ_F, wsf + B2O_F,
      ws + WSTAT_P, ws + WV_P, ws + W1_P, ws + W2O_P,
      ws + KQ_BF, ws + XP_BF,
      out_c, out_wm);
}

// Round 6
// 328.273 us; speedup vs baseline: 2.3019x; 1.0358x over previous
//
#include <hip/hip_runtime.h>
#include <cmath>

// ============================================================================
// SpatialContextSet — round 6.
// vs r5: (1) 2 batches per fused WG (grid 2048): packed-weight L2 traffic and
// barrier count per batch halved, per-wave MFMA ILP doubled (acc[4][8]).
// (2) xpack prep removed; fused stages x fp32->bf16 into LDS (coalesced
// float4) aliased into buf's pre-P1 dead space. (3) pre GEMMs register-dbuf.
// Kernels: prep1 (W2o fold + packs), prep2 (pack W2o), pre, fused.
// ============================================================================

typedef __bf16 bf16;
typedef bf16 bf16x4 __attribute__((ext_vector_type(4)));
typedef bf16 bf16x8 __attribute__((ext_vector_type(8)));
typedef float f32x4 __attribute__((ext_vector_type(4)));

#define MFMA_B16(a, b, c) __builtin_amdgcn_mfma_f32_16x16x32_bf16((a), (b), (c), 0, 0, 0)

constexpr int SROW = 264;  // LDS buf row stride bf16 (528 B)
constexpr int XROW = 72;   // x staging row stride bf16 (144 B)

// ---- workspace layout (bf16 element offsets) ----
constexpr size_t WSTAT_P = 0;          // 4w*2ks*2048 = 16384
constexpr size_t WV_P    = 16384;      // 65536
constexpr size_t W1_P    = 81920;      // 65536
constexpr size_t W2O_P   = 147456;     // 65536
constexpr size_t WDYN_P  = 212992;     // 131072
constexpr size_t WQ_P    = 344064;     // 65536
constexpr size_t WK_P    = 409600;     // 65536 (trans-packed)
constexpr size_t KQ_BF   = 475136;     // [4096][4][256] -> ends 4669440
// float element offsets (from (float*)ws):
constexpr size_t H0_F   = 2334720;     // [4096][256]
constexpr size_t BKQ_F  = 3383296;     // [4096][4]
constexpr size_t B2O_F  = 3399680;     // [256]
constexpr size_t W2OS_F = 3399936;     // fp32 scratch W2o [256][256]

__device__ __forceinline__ bf16x8 zero8() {
  bf16x8 z;
#pragma unroll
  for (int j = 0; j < 8; ++j) z[j] = (bf16)0.0f;
  return z;
}

__device__ __forceinline__ float wave_sum(float v) {
#pragma unroll
  for (int m = 1; m < 64; m <<= 1) v += __shfl_xor(v, m, 64);
  return v;
}

// ---- swapped K=256 GEMM over 8 token tiles (2 batches): A=packed W frags,
// B=buf rows. acc[dt][tt] -> (dim=w*64+dt*16+quad*4+r, tokenrow=tt*16+l16)
__device__ __forceinline__ void gemm_swapped8(const bf16* buf, const bf16* __restrict__ Wp,
                                              int w, int lane, int l16, int koff,
                                              f32x4 (&acc)[4][8]) {
  const bf16* base = Wp + (size_t)w * 8 * 2048 + lane * 8;
  bf16x8 aw[2][4];
#pragma unroll
  for (int dt = 0; dt < 4; ++dt) aw[0][dt] = *(const bf16x8*)(base + dt * 512);
#pragma unroll
  for (int ks = 0; ks < 8; ++ks) {
    const int cur = ks & 1;
    if (ks < 7) {
#pragma unroll
      for (int dt = 0; dt < 4; ++dt)
        aw[cur ^ 1][dt] = *(const bf16x8*)(base + (ks + 1) * 2048 + dt * 512);
    }
#pragma unroll
    for (int tt = 0; tt < 8; ++tt) {
      bf16x8 bfrag = *(const bf16x8*)(buf + (tt * 16 + l16) * SROW + ks * 32 + koff);
#pragma unroll
      for (int dt = 0; dt < 4; ++dt) acc[dt][tt] = MFMA_B16(aw[cur][dt], bfrag, acc[dt][tt]);
    }
  }
}

// ---- original-orientation K=256 GEMM over 8 token tiles (P6)
__device__ __forceinline__ void gemm_orig8(const bf16* buf, const bf16* __restrict__ Wp,
                                           int w, int lane, int l16, int koff,
                                           f32x4 (&acc)[8][4]) {
  const bf16* base = Wp + (size_t)w * 8 * 2048 + lane * 8;
  bf16x8 bw[2][4];
#pragma unroll
  for (int nt = 0; nt < 4; ++nt) bw[0][nt] = *(const bf16x8*)(base + nt * 512);
#pragma unroll
  for (int ks = 0; ks < 8; ++ks) {
    const int cur = ks & 1;
    if (ks < 7) {
#pragma unroll
      for (int nt = 0; nt < 4; ++nt)
        bw[cur ^ 1][nt] = *(const bf16x8*)(base + (ks + 1) * 2048 + nt * 512);
    }
#pragma unroll
    for (int mt = 0; mt < 8; ++mt) {
      bf16x8 a = *(const bf16x8*)(buf + (mt * 16 + l16) * SROW + ks * 32 + koff);
#pragma unroll
      for (int nt = 0; nt < 4; ++nt) acc[mt][nt] = MFMA_B16(a, bw[cur][nt], acc[mt][nt]);
    }
  }
}

// ---- swapped epilogue for 8 tiles: b64 stores + per-token LN partials
__device__ __forceinline__ void store_stats8(bf16* buf, const float* __restrict__ bsrc,
                                             f32x4 (&acc)[4][8], int w, int quad, int l16,
                                             float (*part_s)[4][64], float (*part_ss)[4][64]) {
  float ps[8], pq[8];
#pragma unroll
  for (int tt = 0; tt < 8; ++tt) { ps[tt] = 0.f; pq[tt] = 0.f; }
#pragma unroll
  for (int dt = 0; dt < 4; ++dt) {
    const float4 bb = *(const float4*)(bsrc + w * 64 + dt * 16 + quad * 4);
#pragma unroll
    for (int tt = 0; tt < 8; ++tt) {
      float v0 = acc[dt][tt][0] + bb.x;
      float v1 = acc[dt][tt][1] + bb.y;
      float v2 = acc[dt][tt][2] + bb.z;
      float v3 = acc[dt][tt][3] + bb.w;
      ps[tt] += (v0 + v1) + (v2 + v3);
      pq[tt] += v0 * v0 + v1 * v1 + v2 * v2 + v3 * v3;
      bf16x4 o;
      o[0] = (bf16)v0; o[1] = (bf16)v1; o[2] = (bf16)v2; o[3] = (bf16)v3;
      *(bf16x4*)(buf + (tt * 16 + l16) * SROW + w * 64 + dt * 16 + quad * 4) = o;
    }
  }
#pragma unroll
  for (int tt = 0; tt < 8; ++tt) {
    ps[tt] += __shfl_xor(ps[tt], 16, 64); ps[tt] += __shfl_xor(ps[tt], 32, 64);
    pq[tt] += __shfl_xor(pq[tt], 16, 64); pq[tt] += __shfl_xor(pq[tt], 32, 64);
  }
  if (quad == 0) {
#pragma unroll
    for (int tt = 0; tt < 8; ++tt) {
      part_s[tt >> 2][w][(tt & 3) * 16 + l16] = ps[tt];
      part_ss[tt >> 2][w][(tt & 3) * 16 + l16] = pq[tt];
    }
  }
}

// ---- apply-only LN over 128 rows (2 batches)
__device__ __forceinline__ void ln_apply2(bf16* buf, const float* __restrict__ g,
                                          const float* __restrict__ bsh,
                                          const float (*ps)[4][64], const float (*pss)[4][64],
                                          int w, int lane) {
  float mean[2], rstd[2];
#pragma unroll
  for (int bb = 0; bb < 2; ++bb) {
    float s = (ps[bb][0][lane] + ps[bb][1][lane]) + (ps[bb][2][lane] + ps[bb][3][lane]);
    float q = (pss[bb][0][lane] + pss[bb][1][lane]) + (pss[bb][2][lane] + pss[bb][3][lane]);
    mean[bb] = s * (1.f / 256.f);
    float var = q * (1.f / 256.f) - mean[bb] * mean[bb];
    rstd[bb] = 1.f / sqrtf(var + 1e-5f);
  }
  const float4 gv = *(const float4*)(g + lane * 4);
  const float4 bv4 = *(const float4*)(bsh + lane * 4);
#pragma unroll
  for (int bb = 0; bb < 2; ++bb) {
#pragma unroll
    for (int i = 0; i < 16; ++i) {
      const int r64 = 4 * i + w;
      const float mb = __shfl(mean[bb], r64, 64);
      const float rb = __shfl(rstd[bb], r64, 64);
      bf16* rp = buf + (bb * 64 + r64) * SROW + lane * 4;
      bf16x4 xv = *(const bf16x4*)rp;
      bf16x4 o;
      o[0] = (bf16)(((float)xv[0] - mb) * rb * gv.x + bv4.x);
      o[1] = (bf16)(((float)xv[1] - mb) * rb * gv.y + bv4.y);
      o[2] = (bf16)(((float)xv[2] - mb) * rb * gv.z + bv4.z);
      o[3] = (bf16)(((float)xv[3] - mb) * rb * gv.w + bv4.w);
      *(bf16x4*)rp = o;
    }
  }
}

// ---- fragment packer (one (w,ks) slice -> 2048 bf16)
__device__ __forceinline__ void pack_slice(const float* __restrict__ src, bf16* __restrict__ dstb,
                                           int w, int ks, bool trans, float* sh, int tid) {
  if (!trans) {
#pragma unroll
    for (int i = 0; i < 8; ++i) {
      int r = i * 4 + (tid >> 6), c = tid & 63;
      sh[r * 65 + c] = src[(size_t)(ks * 32 + r) * 256 + w * 64 + c];
    }
  } else {
    int c = tid >> 2, j8 = tid & 3;
#pragma unroll
    for (int jj = 0; jj < 8; ++jj) {
      int r = j8 * 8 + jj;
      sh[r * 65 + c] = src[(size_t)(w * 64 + c) * 256 + ks * 32 + r];
    }
  }
  __syncthreads();
  const int x = tid >> 6, quad = (tid >> 4) & 3, l16 = tid & 15;
  bf16x8 o;
#pragma unroll
  for (int j = 0; j < 8; ++j) o[j] = (bf16)sh[(quad * 8 + j) * 65 + x * 16 + l16];
  *(bf16x8*)(dstb + tid * 8) = o;
}

// ---------------------------------------------------------------------------
// prep1: blocks [0,32)=W2o fold (+b2o), [32,232)=weight packs
// ---------------------------------------------------------------------------
__global__ void prep1_kernel(const float* __restrict__ Wdyn, const float* __restrict__ Wstat,
                             const float* __restrict__ Wq, const float* __restrict__ Wk,
                             const float* __restrict__ Wv, const float* __restrict__ W1,
                             const float* __restrict__ W2, const float* __restrict__ Wo,
                             const float* __restrict__ b2,
                             bf16* __restrict__ ws, float* __restrict__ wsf) {
  __shared__ float sh[64 * 65];
  __shared__ float part[4][8];
  const int idx = blockIdx.x;
  const int tid = threadIdx.x;

  if (idx < 32) {  // ---- W2o = W2@Wo -> fp32 scratch [k][n]; b2o ----
    const int n0 = idx * 8;
    float4 a0 = *(const float4*)(Wo + (size_t)tid * 256 + n0);
    float4 a1 = *(const float4*)(Wo + (size_t)tid * 256 + n0 + 4);
    sh[tid * 8 + 0] = a0.x; sh[tid * 8 + 1] = a0.y; sh[tid * 8 + 2] = a0.z; sh[tid * 8 + 3] = a0.w;
    sh[tid * 8 + 4] = a1.x; sh[tid * 8 + 5] = a1.y; sh[tid * 8 + 6] = a1.z; sh[tid * 8 + 7] = a1.w;
    __syncthreads();
    float acc[8] = {0.f, 0.f, 0.f, 0.f, 0.f, 0.f, 0.f, 0.f};
    const float* row = W2 + (size_t)tid * 256;
    for (int d0 = 0; d0 < 256; d0 += 4) {
      float4 wv = *(const float4*)(row + d0);
#pragma unroll
      for (int dd = 0; dd < 4; ++dd) {
        float r = (dd == 0) ? wv.x : (dd == 1) ? wv.y : (dd == 2) ? wv.z : wv.w;
        const float* cc = &sh[(d0 + dd) * 8];
#pragma unroll
        for (int j = 0; j < 8; ++j) acc[j] += r * cc[j];
      }
    }
    float* dst = wsf + W2OS_F;
#pragma unroll
    for (int j = 0; j < 8; ++j) dst[(size_t)tid * 256 + n0 + j] = acc[j];
    const int w = tid >> 6, lane = tid & 63;
    float bval = b2[tid];
#pragma unroll
    for (int j = 0; j < 8; ++j) {
      float p = wave_sum(bval * sh[tid * 8 + j]);
      if (lane == 0) part[w][j] = p;
    }
    __syncthreads();
    if (tid < 8)
      wsf[B2O_F + n0 + tid] = part[0][tid] + part[1][tid] + part[2][tid] + part[3][tid];
    return;
  }

  int t = idx - 32;
  const float* src; bf16* dst; int KS; bool trans = false;
  if (t < 64)       { src = Wdyn;  dst = ws + WDYN_P;  KS = 16; }
  else if (t < 72)  { src = Wstat; dst = ws + WSTAT_P; KS = 2;  t -= 64; }
  else if (t < 104) { src = Wq;    dst = ws + WQ_P;    KS = 8;  t -= 72; }
  else if (t < 136) { src = Wv;    dst = ws + WV_P;    KS = 8;  t -= 104; }
  else if (t < 168) { src = W1;    dst = ws + W1_P;    KS = 8;  t -= 136; }
  else              { src = Wk;    dst = ws + WK_P;    KS = 8;  t -= 168; trans = true; }
  const int w = t / KS, ks = t % KS;
  pack_slice(src, dst + (size_t)(w * KS + ks) * 2048, w, ks, trans, sh, tid);
}

// prep2: pack W2o from fp32 scratch
__global__ void prep2_kernel(const float* __restrict__ wsf_scr, bf16* __restrict__ ws) {
  __shared__ float sh[64 * 65];
  const int t = blockIdx.x;
  pack_slice(wsf_scr, ws + W2O_P + (size_t)t * 2048, t >> 3, t & 7, false, sh, threadIdx.x);
}

// ---------------------------------------------------------------------------
// pre: grid 512, 8 batch rows per WG. GEMMs register-double-buffered.
// ---------------------------------------------------------------------------
__launch_bounds__(256, 2)
__global__ void pre_kernel(const float* __restrict__ h_dyn, const float* __restrict__ b_dyn,
                           const float* __restrict__ g_ndyn, const float* __restrict__ b_ndyn,
                           const float* __restrict__ bq, const float* __restrict__ bk,
                           const bf16* __restrict__ Wdyn_p, const bf16* __restrict__ Wq_p,
                           const bf16* __restrict__ Wk_p,
                           float* __restrict__ h0_out, bf16* __restrict__ kq_out,
                           float* __restrict__ bkq_out) {
  __shared__ float h0t[8][264];
  __shared__ bf16 hlnt[8][264];
  __shared__ bf16 qt[8][264];
  const int tid = threadIdx.x;
  const int w = tid >> 6, lane = tid & 63, quad = lane >> 4, l16 = lane & 15;
  const int koff = quad * 8;
  const int b0 = blockIdx.x * 8;
  const int mrow = l16 & 7;

  // h0 (K=512), dbuf weights
  {
    f32x4 acc[4];
#pragma unroll
    for (int nt = 0; nt < 4; ++nt) { f32x4 z = {0.f, 0.f, 0.f, 0.f}; acc[nt] = z; }
    const float* arow = h_dyn + (size_t)(b0 + mrow) * 512;
    const bf16* base = Wdyn_p + (size_t)w * 16 * 2048 + lane * 8;
    bf16x8 bw[2][4];
#pragma unroll
    for (int nt = 0; nt < 4; ++nt) bw[0][nt] = *(const bf16x8*)(base + nt * 512);
    for (int ks = 0; ks < 16; ++ks) {
      const int cur = ks & 1;
      if (ks < 15) {
#pragma unroll
        for (int nt = 0; nt < 4; ++nt)
          bw[cur ^ 1][nt] = *(const bf16x8*)(base + (ks + 1) * 2048 + nt * 512);
      }
      float4 x0 = *(const float4*)(arow + ks * 32 + koff);
      float4 x1 = *(const float4*)(arow + ks * 32 + koff + 4);
      bf16x8 a;
      a[0] = (bf16)x0.x; a[1] = (bf16)x0.y; a[2] = (bf16)x0.z; a[3] = (bf16)x0.w;
      a[4] = (bf16)x1.x; a[5] = (bf16)x1.y; a[6] = (bf16)x1.z; a[7] = (bf16)x1.w;
#pragma unroll
      for (int nt = 0; nt < 4; ++nt) acc[nt] = MFMA_B16(a, bw[cur][nt], acc[nt]);
    }
    if (quad < 2) {
#pragma unroll
      for (int nt = 0; nt < 4; ++nt) {
        int col = w * 64 + nt * 16 + l16;
        float bb = b_dyn[col];
#pragma unroll
        for (int r = 0; r < 4; ++r) {
          int row = quad * 4 + r;
          float v = acc[nt][r] + bb;
          h0t[row][col] = v;
          h0_out[(size_t)(b0 + row) * 256 + col] = v;
        }
      }
    }
  }
  __syncthreads();

  // LN over 8 rows
  {
    float gn[4], bn[4];
#pragma unroll
    for (int j = 0; j < 4; ++j) { gn[j] = g_ndyn[lane + 64 * j]; bn[j] = b_ndyn[lane + 64 * j]; }
#pragma unroll
    for (int i = 0; i < 2; ++i) {
      int row = 4 * i + w;
      float x[4]; float s = 0.f, ss = 0.f;
#pragma unroll
      for (int j = 0; j < 4; ++j) { x[j] = h0t[row][lane + 64 * j]; s += x[j]; ss += x[j] * x[j]; }
      s = wave_sum(s); ss = wave_sum(ss);
      float mean = s * (1.f / 256.f);
      float var = ss * (1.f / 256.f) - mean * mean;
      float rstd = 1.f / sqrtf(var + 1e-5f);
#pragma unroll
      for (int j = 0; j < 4; ++j)
        hlnt[row][lane + 64 * j] = (bf16)((x[j] - mean) * rstd * gn[j] + bn[j]);
    }
  }
  __syncthreads();

  // q = hln@Wq + bq (dbuf)
  {
    f32x4 acc[4];
#pragma unroll
    for (int nt = 0; nt < 4; ++nt) { f32x4 z = {0.f, 0.f, 0.f, 0.f}; acc[nt] = z; }
    const bf16* base = Wq_p + (size_t)w * 8 * 2048 + lane * 8;
    bf16x8 bw[2][4];
#pragma unroll
    for (int nt = 0; nt < 4; ++nt) bw[0][nt] = *(const bf16x8*)(base + nt * 512);
    for (int ks = 0; ks < 8; ++ks) {
      const int cur = ks & 1;
      if (ks < 7) {
#pragma unroll
        for (int nt = 0; nt < 4; ++nt)
          bw[cur ^ 1][nt] = *(const bf16x8*)(base + (ks + 1) * 2048 + nt * 512);
      }
      bf16x8 a = *(const bf16x8*)(&hlnt[mrow][ks * 32 + koff]);
#pragma unroll
      for (int nt = 0; nt < 4; ++nt) acc[nt] = MFMA_B16(a, bw[cur][nt], acc[nt]);
    }
    if (quad < 2) {
#pragma unroll
      for (int nt = 0; nt < 4; ++nt) {
        int col = w * 64 + nt * 16 + l16;
        float bb = bq[col];
#pragma unroll
        for (int r = 0; r < 4; ++r)
          qt[quad * 4 + r][col] = (bf16)(acc[nt][r] + bb);
      }
    }
  }
  __syncthreads();

  // bkq[b,h] = bk_h . q_h
  {
    const int pair = tid >> 2;
    const int row = pair >> 2, h = pair & 3, sub = tid & 3;
    if (row < 8) {
      float p = 0.f;
#pragma unroll
      for (int j = 0; j < 16; ++j) {
        int e = sub * 16 + j;
        p += (float)qt[row][h * 64 + e] * bk[h * 64 + e];
      }
      p += __shfl_xor(p, 1, 64);
      p += __shfl_xor(p, 2, 64);
      if (sub == 0) bkq_out[(size_t)(b0 + row) * 4 + h] = p;
    }
  }

  // kq per head
  for (int h = 0; h < 4; ++h) {
    f32x4 acc[4];
#pragma unroll
    for (int nt = 0; nt < 4; ++nt) { f32x4 z = {0.f, 0.f, 0.f, 0.f}; acc[nt] = z; }
    const bf16* base = Wk_p + (size_t)w * 8 * 2048 + lane * 8;
#pragma unroll
    for (int ks = 0; ks < 2; ++ks) {
      bf16x8 a = *(const bf16x8*)(&qt[mrow][h * 64 + ks * 32 + koff]);
#pragma unroll
      for (int nt = 0; nt < 4; ++nt) {
        bf16x8 bw = *(const bf16x8*)(base + (h * 2 + ks) * 2048 + nt * 512);
        acc[nt] = MFMA_B16(a, bw, acc[nt]);
      }
    }
    if (quad < 2) {
#pragma unroll
      for (int nt = 0; nt < 4; ++nt)
#pragma unroll
        for (int r = 0; r < 4; ++r)
          kq_out[(size_t)(b0 + quad * 4 + r) * 1024 + h * 256 + w * 64 + nt * 16 + l16] =
              (bf16)acc[nt][r];
    }
  }
}

// ---------------------------------------------------------------------------
// fused: 2 batches per WG. grid 2048 x 256 thr, 2 blocks/CU.
// ---------------------------------------------------------------------------
__launch_bounds__(256, 2)
__global__ void fused_kernel(
    const float* __restrict__ x_stat, const float* __restrict__ b_stat,
    const float* __restrict__ g_nstat, const float* __restrict__ b_nstat,
    const float* __restrict__ bv, const float* __restrict__ g_mlp,
    const float* __restrict__ b_mlp, const float* __restrict__ b1,
    const float* __restrict__ bo, const float* __restrict__ res_scale_p,
    const float* __restrict__ h0g, const float* __restrict__ bkq_g,
    const float* __restrict__ b2o_g,
    const bf16* __restrict__ Wstat_p, const bf16* __restrict__ Wv_p,
    const bf16* __restrict__ W1_p, const bf16* __restrict__ W2o_p,
    const bf16* __restrict__ kq_g,
    float* __restrict__ out_c, float* __restrict__ out_wm) {

  __shared__ bf16 buf[128 * SROW];        // 67584 B; first 128*72 doubles as xs
  __shared__ float part_s[2][4][64];
  __shared__ float part_ss[2][4][64];
  __shared__ float watt[2][4][64];
  __shared__ float swh[2][4];

  const int b0 = blockIdx.x * 2;
  const int tid = threadIdx.x;
  const int w = tid >> 6, lane = tid & 63, quad = lane >> 4, l16 = lane & 15;
  const int koff = quad * 8;

  // ---- P0: stage x (2 batches) fp32 -> bf16 LDS, fully coalesced ----
  bf16* xs = buf;  // alias: dead before P1 epilogue stores
  {
    const float* xb = x_stat + (size_t)b0 * 4096;
#pragma unroll
    for (int j = 0; j < 8; ++j) {
      int idx = j * 1024 + tid * 4;
      float4 v = *(const float4*)(xb + idx);
      bf16x4 o;
      o[0] = (bf16)v.x; o[1] = (bf16)v.y; o[2] = (bf16)v.z; o[3] = (bf16)v.w;
      *(bf16x4*)(xs + (idx >> 6) * XROW + (idx & 63)) = o;
    }
  }
  __syncthreads();

  // ---- P1: s = x @ W_stat + b_stat (swapped; K=64) ----
  {
    f32x4 acc[4][8];
#pragma unroll
    for (int dt = 0; dt < 4; ++dt)
#pragma unroll
      for (int tt = 0; tt < 8; ++tt) { f32x4 z = {0.f, 0.f, 0.f, 0.f}; acc[dt][tt] = z; }
    const bf16* wsb = Wstat_p + (size_t)w * 2 * 2048 + lane * 8;
    bf16x8 aw[2][4];
#pragma unroll
    for (int ks = 0; ks < 2; ++ks)
#pragma unroll
      for (int dt = 0; dt < 4; ++dt)
        aw[ks][dt] = *(const bf16x8*)(wsb + ks * 2048 + dt * 512);
#pragma unroll
    for (int ks = 0; ks < 2; ++ks)
#pragma unroll
      for (int tt = 0; tt < 8; ++tt) {
        bf16x8 bfrag = *(const bf16x8*)(xs + (tt * 16 + l16) * XROW + ks * 32 + koff);
#pragma unroll
        for (int dt = 0; dt < 4; ++dt) acc[dt][tt] = MFMA_B16(aw[ks][dt], bfrag, acc[dt][tt]);
      }
    __syncthreads();  // xs reads done before buf (alias) stores
    store_stats8(buf, b_stat, acc, w, quad, l16, part_s, part_ss);
  }
  __syncthreads();

  // ---- P2: LN(s) apply-only ----
  ln_apply2(buf, g_nstat, b_nstat, part_s, part_ss, w, lane);
  __syncthreads();

  // ---- P3a: logits via kq (per batch) ----
#pragma unroll
  for (int bb = 0; bb < 2; ++bb) {
    const bf16* kq_b = kq_g + (size_t)(b0 + bb) * 1024;
    f32x4 accL = {0.f, 0.f, 0.f, 0.f};
#pragma unroll
    for (int ks = 0; ks < 8; ++ks) {
      bf16x8 a = *(const bf16x8*)(buf + (bb * 64 + w * 16 + l16) * SROW + ks * 32 + koff);
      bf16x8 kf = zero8();
      if (l16 < 4) kf = *(const bf16x8*)(kq_b + l16 * 256 + ks * 32 + koff);
      accL = MFMA_B16(a, kf, accL);
    }
    float bkqv = (l16 < 4) ? bkq_g[(size_t)(b0 + bb) * 4 + l16] : 0.f;
#pragma unroll
    for (int r = 0; r < 4; ++r) {
      float lg = (accL[r] + bkqv) * 0.125f;
      float sig = 1.f / (1.f + __expf(-lg));
      if (l16 < 4) watt[bb][l16][w * 16 + quad * 4 + r] = sig;  // un-normalized
    }
  }

  // ---- P3b: v = s_ln @ Wv + bv (swapped), in-place ----
  {
    f32x4 acc[4][8];
#pragma unroll
    for (int dt = 0; dt < 4; ++dt)
#pragma unroll
      for (int tt = 0; tt < 8; ++tt) { f32x4 z = {0.f, 0.f, 0.f, 0.f}; acc[dt][tt] = z; }
    gemm_swapped8(buf, Wv_p, w, lane, l16, koff, acc);
    __syncthreads();  // all s reads done; watt(sig) visible
#pragma unroll
    for (int bb = 0; bb < 2; ++bb) {
      float v = watt[bb][w][lane];
      float den = wave_sum(v);
      float dinv = 1.f / (den + 1e-6f);
      watt[bb][w][lane] = v * dinv;
      if (lane == 0) swh[bb][w] = den * dinv;
    }
    store_stats8(buf, bv, acc, w, quad, l16, part_s, part_ss);
  }
  __syncthreads();

  // ---- P4: w_mean + LN(v) apply-only ----
  if (tid < 128) {
    int bb = tid >> 6, t = tid & 63;
    out_wm[(size_t)(b0 + bb) * 64 + t] =
        0.25f * ((watt[bb][0][t] + watt[bb][1][t]) + (watt[bb][2][t] + watt[bb][3][t]));
  }
  ln_apply2(buf, g_mlp, b_mlp, part_s, part_ss, w, lane);
  __syncthreads();

  // ---- P5: t1 = gelu(t_ln@W1 + b1) (swapped), in-place ----
  {
    f32x4 acc[4][8];
#pragma unroll
    for (int dt = 0; dt < 4; ++dt)
#pragma unroll
      for (int tt = 0; tt < 8; ++tt) { f32x4 z = {0.f, 0.f, 0.f, 0.f}; acc[dt][tt] = z; }
    gemm_swapped8(buf, W1_p, w, lane, l16, koff, acc);
    __syncthreads();
#pragma unroll
    for (int dt = 0; dt < 4; ++dt) {
      const float4 bb = *(const float4*)(b1 + w * 64 + dt * 16 + quad * 4);
#pragma unroll
      for (int tt = 0; tt < 8; ++tt) {
        float v0 = acc[dt][tt][0] + bb.x;
        float v1 = acc[dt][tt][1] + bb.y;
        float v2 = acc[dt][tt][2] + bb.z;
        float v3 = acc[dt][tt][3] + bb.w;
        bf16x4 o;
        o[0] = (bf16)(v0 / (1.f + __expf(-1.702f * v0)));
        o[1] = (bf16)(v1 / (1.f + __expf(-1.702f * v1)));
        o[2] = (bf16)(v2 / (1.f + __expf(-1.702f * v2)));
        o[3] = (bf16)(v3 / (1.f + __expf(-1.702f * v3)));
        *(bf16x4*)(buf + (tt * 16 + l16) * SROW + w * 64 + dt * 16 + quad * 4) = o;
      }
    }
  }
  __syncthreads();

  // ---- P6: t1 @ W2o (orig); z per batch; c written ----
  {
    f32x4 acc[8][4];
#pragma unroll
    for (int mt = 0; mt < 8; ++mt)
#pragma unroll
      for (int nt = 0; nt < 4; ++nt) { f32x4 z = {0.f, 0.f, 0.f, 0.f}; acc[mt][nt] = z; }
    gemm_orig8(buf, W2o_p, w, lane, l16, koff, acc);
    float zacc[2][4];
#pragma unroll
    for (int bb = 0; bb < 2; ++bb)
#pragma unroll
      for (int nt = 0; nt < 4; ++nt) zacc[bb][nt] = 0.f;
#pragma unroll
    for (int mt = 0; mt < 8; ++mt) {
      const int bb = mt >> 2;
#pragma unroll
      for (int r = 0; r < 4; ++r) {
        float wt = watt[bb][w][(mt & 3) * 16 + quad * 4 + r];
#pragma unroll
        for (int nt = 0; nt < 4; ++nt) zacc[bb][nt] += wt * acc[mt][nt][r];
      }
    }
#pragma unroll
    for (int bb = 0; bb < 2; ++bb)
#pragma unroll
      for (int nt = 0; nt < 4; ++nt) {
        zacc[bb][nt] += __shfl_xor(zacc[bb][nt], 16, 64);
        zacc[bb][nt] += __shfl_xor(zacc[bb][nt], 32, 64);
      }
    if (quad == 0) {
      float rs = *res_scale_p;
#pragma unroll
      for (int bb = 0; bb < 2; ++bb)
#pragma unroll
        for (int nt = 0; nt < 4; ++nt) {
          int col = w * 64 + nt * 16 + l16;
          float res = zacc[bb][nt] + swh[bb][w] * b2o_g[col] + bo[col];
          out_c[(size_t)(b0 + bb) * 256 + col] = h0g[(size_t)(b0 + bb) * 256 + col] + rs * res;
        }
    }
  }
}

extern "C" void kernel_launch(void* const* d_in, const int* in_sizes, int n_in,
                              void* d_out, int out_size, void* d_ws, size_t ws_size,
                              hipStream_t stream) {
  const float* h_dyn   = (const float*)d_in[0];
  const float* x_stat  = (const float*)d_in[1];
  const float* W_dyn   = (const float*)d_in[2];
  const float* b_dyn   = (const float*)d_in[3];
  const float* W_stat  = (const float*)d_in[4];
  const float* b_stat  = (const float*)d_in[5];
  const float* g_ndyn  = (const float*)d_in[6];
  const float* b_ndyn  = (const float*)d_in[7];
  const float* g_nstat = (const float*)d_in[8];
  const float* b_nstat = (const float*)d_in[9];
  const float* Wq = (const float*)d_in[10];
  const float* bq = (const float*)d_in[11];
  const float* Wk = (const float*)d_in[12];
  const float* bk = (const float*)d_in[13];
  const float* Wv = (const float*)d_in[14];
  const float* bv = (const float*)d_in[15];
  const float* g_mlp = (const float*)d_in[16];
  const float* b_mlp = (const float*)d_in[17];
  const float* W1 = (const float*)d_in[18];
  const float* b1 = (const float*)d_in[19];
  const float* W2 = (const float*)d_in[20];
  const float* b2 = (const float*)d_in[21];
  const float* Wo = (const float*)d_in[22];
  const float* bo = (const float*)d_in[23];
  const float* rs = (const float*)d_in[24];

  bf16* ws = (bf16*)d_ws;
  float* wsf = (float*)d_ws;

  prep1_kernel<<<232, 256, 0, stream>>>(W_dyn, W_stat, Wq, Wk, Wv, W1, W2, Wo, b2, ws, wsf);
  prep2_kernel<<<32, 256, 0, stream>>>(wsf + W2OS_F, ws);

  pre_kernel<<<512, 256, 0, stream>>>(h_dyn, b_dyn, g_ndyn, b_ndyn, bq, bk,
                                      ws + WDYN_P, ws + WQ_P, ws + WK_P,
                                      wsf + H0_F, ws + KQ_BF, wsf + BKQ_F);

  float* out_c = (float*)d_out;
  float* out_wm = out_c + (size_t)4096 * 256;
  fused_kernel<<<2048, 256, 0, stream>>>(
      x_stat, b_stat, g_nstat, b_nstat, bv, g_mlp, b_mlp, b1, bo, rs,
      wsf + H0_F, wsf + BKQ_F, wsf + B2O_F,
      ws + WSTAT_P, ws + WV_P, ws + W1_P, ws + W2O_P, ws + KQ_BF,
      out_c, out_wm);
}

// Round 7
// 311.511 us; speedup vs baseline: 2.4257x; 1.0538x over previous
//
#include <hip/hip_runtime.h>
#include <cmath>

// ============================================================================
// SpatialContextSet — round 7.
// = r5 fused structure (1 batch/WG, 4 blocks/CU) + r6 lean prep, plus:
//  (a) x staged fp32->bf16 in-kernel into LDS aliased over buf (coalesced),
//  (b) LN fused into producer epilogues: partials -> barrier -> finalize +
//      apply to REGISTER values -> single bf16 store (kills both LN passes),
//  (c) all fp32 divides -> v_rcp, 1/sqrt -> v_rsq (gelu, sigmoid, dinv).
// Kernels: prep1 (W2o fold + packs), prep2 (pack W2o), pre, fused.
// ============================================================================

typedef __bf16 bf16;
typedef bf16 bf16x4 __attribute__((ext_vector_type(4)));
typedef bf16 bf16x8 __attribute__((ext_vector_type(8)));
typedef float f32x4 __attribute__((ext_vector_type(4)));

#define MFMA_B16(a, b, c) __builtin_amdgcn_mfma_f32_16x16x32_bf16((a), (b), (c), 0, 0, 0)
#define RCP(x) __builtin_amdgcn_rcpf(x)
#define RSQ(x) __builtin_amdgcn_rsqf(x)

constexpr int SROW = 264;  // LDS buf row stride bf16 (528 B)
constexpr int XROW = 72;   // x staging row stride bf16 (144 B)

// ---- workspace layout (bf16 element offsets) ----
constexpr size_t WSTAT_P = 0;          // 4w*2ks*2048 = 16384
constexpr size_t WV_P    = 16384;      // 65536
constexpr size_t W1_P    = 81920;      // 65536
constexpr size_t W2O_P   = 147456;     // 65536
constexpr size_t WDYN_P  = 212992;     // 131072
constexpr size_t WQ_P    = 344064;     // 65536
constexpr size_t WK_P    = 409600;     // 65536 (trans-packed)
constexpr size_t KQ_BF   = 475136;     // [4096][4][256]
// float element offsets (from (float*)ws):
constexpr size_t H0_F   = 2334720;     // [4096][256]
constexpr size_t BKQ_F  = 3383296;     // [4096][4]
constexpr size_t B2O_F  = 3399680;     // [256]
constexpr size_t W2OS_F = 3399936;     // fp32 scratch W2o [256][256]

__device__ __forceinline__ bf16x8 zero8() {
  bf16x8 z;
#pragma unroll
  for (int j = 0; j < 8; ++j) z[j] = (bf16)0.0f;
  return z;
}

__device__ __forceinline__ float wave_sum(float v) {
#pragma unroll
  for (int m = 1; m < 64; m <<= 1) v += __shfl_xor(v, m, 64);
  return v;
}

__device__ __forceinline__ void zero_acc(f32x4 (&acc)[4][4]) {
#pragma unroll
  for (int mt = 0; mt < 4; ++mt)
#pragma unroll
    for (int nt = 0; nt < 4; ++nt) { f32x4 z = {0.f, 0.f, 0.f, 0.f}; acc[mt][nt] = z; }
}

// ---- packed swapped GEMM (K=256): A=packed W frags (global), B=buf rows (LDS)
// acc[dt][tt] -> (dim = w*64+dt*16+quad*4+r, token = tt*16+l16)
__device__ __forceinline__ void gemm_swapped_p(const bf16* buf, const bf16* __restrict__ Wp,
                                               int w, int lane, int l16, int koff,
                                               f32x4 (&acc)[4][4]) {
  const bf16* base = Wp + (size_t)w * 8 * 2048 + lane * 8;
  bf16x8 aw[2][4];
#pragma unroll
  for (int dt = 0; dt < 4; ++dt) aw[0][dt] = *(const bf16x8*)(base + dt * 512);
#pragma unroll
  for (int ks = 0; ks < 8; ++ks) {
    const int cur = ks & 1;
    if (ks < 7) {
#pragma unroll
      for (int dt = 0; dt < 4; ++dt)
        aw[cur ^ 1][dt] = *(const bf16x8*)(base + (ks + 1) * 2048 + dt * 512);
    }
#pragma unroll
    for (int tt = 0; tt < 4; ++tt) {
      bf16x8 bfrag = *(const bf16x8*)(buf + (tt * 16 + l16) * SROW + ks * 32 + koff);
#pragma unroll
      for (int dt = 0; dt < 4; ++dt) acc[dt][tt] = MFMA_B16(aw[cur][dt], bfrag, acc[dt][tt]);
    }
  }
}

// ---- packed original-orientation GEMM (P6)
__device__ __forceinline__ void gemm_orig_p(const bf16* buf, const bf16* __restrict__ Wp,
                                            int w, int lane, int l16, int koff,
                                            f32x4 (&acc)[4][4]) {
  const bf16* base = Wp + (size_t)w * 8 * 2048 + lane * 8;
  bf16x8 bw[2][4];
#pragma unroll
  for (int nt = 0; nt < 4; ++nt) bw[0][nt] = *(const bf16x8*)(base + nt * 512);
#pragma unroll
  for (int ks = 0; ks < 8; ++ks) {
    const int cur = ks & 1;
    if (ks < 7) {
#pragma unroll
      for (int nt = 0; nt < 4; ++nt)
        bw[cur ^ 1][nt] = *(const bf16x8*)(base + (ks + 1) * 2048 + nt * 512);
    }
#pragma unroll
    for (int mt = 0; mt < 4; ++mt) {
      bf16x8 a = *(const bf16x8*)(buf + (mt * 16 + l16) * SROW + ks * 32 + koff);
#pragma unroll
      for (int nt = 0; nt < 4; ++nt) acc[mt][nt] = MFMA_B16(a, bw[cur][nt], acc[mt][nt]);
    }
  }
}

// ---- add bias into acc + per-token LN partials -> LDS (values stay in regs)
__device__ __forceinline__ void bias_stats(f32x4 (&acc)[4][4], const float* __restrict__ bsrc,
                                           int w, int quad, int l16,
                                           float (*part_s)[64], float (*part_ss)[64]) {
  float ps[4] = {0.f, 0.f, 0.f, 0.f}, pq[4] = {0.f, 0.f, 0.f, 0.f};
#pragma unroll
  for (int dt = 0; dt < 4; ++dt) {
    const float4 bb = *(const float4*)(bsrc + w * 64 + dt * 16 + quad * 4);
#pragma unroll
    for (int tt = 0; tt < 4; ++tt) {
      float v0 = acc[dt][tt][0] + bb.x;
      float v1 = acc[dt][tt][1] + bb.y;
      float v2 = acc[dt][tt][2] + bb.z;
      float v3 = acc[dt][tt][3] + bb.w;
      acc[dt][tt][0] = v0; acc[dt][tt][1] = v1; acc[dt][tt][2] = v2; acc[dt][tt][3] = v3;
      ps[tt] += (v0 + v1) + (v2 + v3);
      pq[tt] += v0 * v0 + v1 * v1 + v2 * v2 + v3 * v3;
    }
  }
#pragma unroll
  for (int tt = 0; tt < 4; ++tt) {
    ps[tt] += __shfl_xor(ps[tt], 16, 64); ps[tt] += __shfl_xor(ps[tt], 32, 64);
    pq[tt] += __shfl_xor(pq[tt], 16, 64); pq[tt] += __shfl_xor(pq[tt], 32, 64);
  }
  if (quad == 0) {
#pragma unroll
    for (int tt = 0; tt < 4; ++tt) {
      part_s[w][tt * 16 + l16] = ps[tt];
      part_ss[w][tt * 16 + l16] = pq[tt];
    }
  }
}

// ---- after barrier: finalize LN stats, apply to register values, store bf16
__device__ __forceinline__ void ln_apply_store(f32x4 (&acc)[4][4], const float* __restrict__ g,
                                               const float* __restrict__ bsh, bf16* buf,
                                               const float (*part_s)[64],
                                               const float (*part_ss)[64],
                                               int w, int quad, int l16) {
  float mean[4], rstd[4];
#pragma unroll
  for (int tt = 0; tt < 4; ++tt) {
    const int tok = tt * 16 + l16;
    float s = (part_s[0][tok] + part_s[1][tok]) + (part_s[2][tok] + part_s[3][tok]);
    float q = (part_ss[0][tok] + part_ss[1][tok]) + (part_ss[2][tok] + part_ss[3][tok]);
    mean[tt] = s * (1.f / 256.f);
    float var = q * (1.f / 256.f) - mean[tt] * mean[tt];
    rstd[tt] = RSQ(var + 1e-5f);
  }
#pragma unroll
  for (int dt = 0; dt < 4; ++dt) {
    const float4 gv = *(const float4*)(g + w * 64 + dt * 16 + quad * 4);
    const float4 bv = *(const float4*)(bsh + w * 64 + dt * 16 + quad * 4);
#pragma unroll
    for (int tt = 0; tt < 4; ++tt) {
      float t0 = (acc[dt][tt][0] - mean[tt]) * rstd[tt];
      float t1 = (acc[dt][tt][1] - mean[tt]) * rstd[tt];
      float t2 = (acc[dt][tt][2] - mean[tt]) * rstd[tt];
      float t3 = (acc[dt][tt][3] - mean[tt]) * rstd[tt];
      bf16x4 o;
      o[0] = (bf16)(t0 * gv.x + bv.x);
      o[1] = (bf16)(t1 * gv.y + bv.y);
      o[2] = (bf16)(t2 * gv.z + bv.z);
      o[3] = (bf16)(t3 * gv.w + bv.w);
      *(bf16x4*)(buf + (tt * 16 + l16) * SROW + w * 64 + dt * 16 + quad * 4) = o;
    }
  }
}

// ---- fragment packer (one (w,ks) slice -> 2048 bf16)
__device__ __forceinline__ void pack_slice(const float* __restrict__ src, bf16* __restrict__ dstb,
                                           int w, int ks, bool trans, float* sh, int tid) {
  if (!trans) {
#pragma unroll
    for (int i = 0; i < 8; ++i) {
      int r = i * 4 + (tid >> 6), c = tid & 63;
      sh[r * 65 + c] = src[(size_t)(ks * 32 + r) * 256 + w * 64 + c];
    }
  } else {
    int c = tid >> 2, j8 = tid & 3;
#pragma unroll
    for (int jj = 0; jj < 8; ++jj) {
      int r = j8 * 8 + jj;
      sh[r * 65 + c] = src[(size_t)(w * 64 + c) * 256 + ks * 32 + r];
    }
  }
  __syncthreads();
  const int x = tid >> 6, quad = (tid >> 4) & 3, l16 = tid & 15;
  bf16x8 o;
#pragma unroll
  for (int j = 0; j < 8; ++j) o[j] = (bf16)sh[(quad * 8 + j) * 65 + x * 16 + l16];
  *(bf16x8*)(dstb + tid * 8) = o;
}

// ---------------------------------------------------------------------------
// prep1: blocks [0,32)=W2o fold (+b2o), [32,232)=weight packs
// ---------------------------------------------------------------------------
__global__ void prep1_kernel(const float* __restrict__ Wdyn, const float* __restrict__ Wstat,
                             const float* __restrict__ Wq, const float* __restrict__ Wk,
                             const float* __restrict__ Wv, const float* __restrict__ W1,
                             const float* __restrict__ W2, const float* __restrict__ Wo,
                             const float* __restrict__ b2,
                             bf16* __restrict__ ws, float* __restrict__ wsf) {
  __shared__ float sh[64 * 65];
  __shared__ float part[4][8];
  const int idx = blockIdx.x;
  const int tid = threadIdx.x;

  if (idx < 32) {  // ---- W2o = W2@Wo -> fp32 scratch [k][n]; b2o ----
    const int n0 = idx * 8;
    float4 a0 = *(const float4*)(Wo + (size_t)tid * 256 + n0);
    float4 a1 = *(const float4*)(Wo + (size_t)tid * 256 + n0 + 4);
    sh[tid * 8 + 0] = a0.x; sh[tid * 8 + 1] = a0.y; sh[tid * 8 + 2] = a0.z; sh[tid * 8 + 3] = a0.w;
    sh[tid * 8 + 4] = a1.x; sh[tid * 8 + 5] = a1.y; sh[tid * 8 + 6] = a1.z; sh[tid * 8 + 7] = a1.w;
    __syncthreads();
    float acc[8] = {0.f, 0.f, 0.f, 0.f, 0.f, 0.f, 0.f, 0.f};
    const float* row = W2 + (size_t)tid * 256;
    for (int d0 = 0; d0 < 256; d0 += 4) {
      float4 wv = *(const float4*)(row + d0);
#pragma unroll
      for (int dd = 0; dd < 4; ++dd) {
        float r = (dd == 0) ? wv.x : (dd == 1) ? wv.y : (dd == 2) ? wv.z : wv.w;
        const float* cc = &sh[(d0 + dd) * 8];
#pragma unroll
        for (int j = 0; j < 8; ++j) acc[j] += r * cc[j];
      }
    }
    float* dst = wsf + W2OS_F;
#pragma unroll
    for (int j = 0; j < 8; ++j) dst[(size_t)tid * 256 + n0 + j] = acc[j];
    const int w = tid >> 6, lane = tid & 63;
    float bval = b2[tid];
#pragma unroll
    for (int j = 0; j < 8; ++j) {
      float p = wave_sum(bval * sh[tid * 8 + j]);
      if (lane == 0) part[w][j] = p;
    }
    __syncthreads();
    if (tid < 8)
      wsf[B2O_F + n0 + tid] = part[0][tid] + part[1][tid] + part[2][tid] + part[3][tid];
    return;
  }

  int t = idx - 32;
  const float* src; bf16* dst; int KS; bool trans = false;
  if (t < 64)       { src = Wdyn;  dst = ws + WDYN_P;  KS = 16; }
  else if (t < 72)  { src = Wstat; dst = ws + WSTAT_P; KS = 2;  t -= 64; }
  else if (t < 104) { src = Wq;    dst = ws + WQ_P;    KS = 8;  t -= 72; }
  else if (t < 136) { src = Wv;    dst = ws + WV_P;    KS = 8;  t -= 104; }
  else if (t < 168) { src = W1;    dst = ws + W1_P;    KS = 8;  t -= 136; }
  else              { src = Wk;    dst = ws + WK_P;    KS = 8;  t -= 168; trans = true; }
  const int w = t / KS, ks = t % KS;
  pack_slice(src, dst + (size_t)(w * KS + ks) * 2048, w, ks, trans, sh, tid);
}

// prep2: pack W2o from fp32 scratch
__global__ void prep2_kernel(const float* __restrict__ wsf_scr, bf16* __restrict__ ws) {
  __shared__ float sh[64 * 65];
  const int t = blockIdx.x;
  pack_slice(wsf_scr, ws + W2O_P + (size_t)t * 2048, t >> 3, t & 7, false, sh, threadIdx.x);
}

// ---------------------------------------------------------------------------
// pre: grid 512, 8 batch rows per WG. GEMMs register-double-buffered.
// ---------------------------------------------------------------------------
__launch_bounds__(256, 2)
__global__ void pre_kernel(const float* __restrict__ h_dyn, const float* __restrict__ b_dyn,
                           const float* __restrict__ g_ndyn, const float* __restrict__ b_ndyn,
                           const float* __restrict__ bq, const float* __restrict__ bk,
                           const bf16* __restrict__ Wdyn_p, const bf16* __restrict__ Wq_p,
                           const bf16* __restrict__ Wk_p,
                           float* __restrict__ h0_out, bf16* __restrict__ kq_out,
                           float* __restrict__ bkq_out) {
  __shared__ float h0t[8][264];
  __shared__ bf16 hlnt[8][264];
  __shared__ bf16 qt[8][264];
  const int tid = threadIdx.x;
  const int w = tid >> 6, lane = tid & 63, quad = lane >> 4, l16 = lane & 15;
  const int koff = quad * 8;
  const int b0 = blockIdx.x * 8;
  const int mrow = l16 & 7;

  // h0 (K=512), dbuf weights
  {
    f32x4 acc[4];
#pragma unroll
    for (int nt = 0; nt < 4; ++nt) { f32x4 z = {0.f, 0.f, 0.f, 0.f}; acc[nt] = z; }
    const float* arow = h_dyn + (size_t)(b0 + mrow) * 512;
    const bf16* base = Wdyn_p + (size_t)w * 16 * 2048 + lane * 8;
    bf16x8 bw[2][4];
#pragma unroll
    for (int nt = 0; nt < 4; ++nt) bw[0][nt] = *(const bf16x8*)(base + nt * 512);
    for (int ks = 0; ks < 16; ++ks) {
      const int cur = ks & 1;
      if (ks < 15) {
#pragma unroll
        for (int nt = 0; nt < 4; ++nt)
          bw[cur ^ 1][nt] = *(const bf16x8*)(base + (ks + 1) * 2048 + nt * 512);
      }
      float4 x0 = *(const float4*)(arow + ks * 32 + koff);
      float4 x1 = *(const float4*)(arow + ks * 32 + koff + 4);
      bf16x8 a;
      a[0] = (bf16)x0.x; a[1] = (bf16)x0.y; a[2] = (bf16)x0.z; a[3] = (bf16)x0.w;
      a[4] = (bf16)x1.x; a[5] = (bf16)x1.y; a[6] = (bf16)x1.z; a[7] = (bf16)x1.w;
#pragma unroll
      for (int nt = 0; nt < 4; ++nt) acc[nt] = MFMA_B16(a, bw[cur][nt], acc[nt]);
    }
    if (quad < 2) {
#pragma unroll
      for (int nt = 0; nt < 4; ++nt) {
        int col = w * 64 + nt * 16 + l16;
        float bb = b_dyn[col];
#pragma unroll
        for (int r = 0; r < 4; ++r) {
          int row = quad * 4 + r;
          float v = acc[nt][r] + bb;
          h0t[row][col] = v;
          h0_out[(size_t)(b0 + row) * 256 + col] = v;
        }
      }
    }
  }
  __syncthreads();

  // LN over 8 rows
  {
    float gn[4], bn[4];
#pragma unroll
    for (int j = 0; j < 4; ++j) { gn[j] = g_ndyn[lane + 64 * j]; bn[j] = b_ndyn[lane + 64 * j]; }
#pragma unroll
    for (int i = 0; i < 2; ++i) {
      int row = 4 * i + w;
      float x[4]; float s = 0.f, ss = 0.f;
#pragma unroll
      for (int j = 0; j < 4; ++j) { x[j] = h0t[row][lane + 64 * j]; s += x[j]; ss += x[j] * x[j]; }
      s = wave_sum(s); ss = wave_sum(ss);
      float mean = s * (1.f / 256.f);
      float var = ss * (1.f / 256.f) - mean * mean;
      float rstd = RSQ(var + 1e-5f);
#pragma unroll
      for (int j = 0; j < 4; ++j)
        hlnt[row][lane + 64 * j] = (bf16)((x[j] - mean) * rstd * gn[j] + bn[j]);
    }
  }
  __syncthreads();

  // q = hln@Wq + bq (dbuf)
  {
    f32x4 acc[4];
#pragma unroll
    for (int nt = 0; nt < 4; ++nt) { f32x4 z = {0.f, 0.f, 0.f, 0.f}; acc[nt] = z; }
    const bf16* base = Wq_p + (size_t)w * 8 * 2048 + lane * 8;
    bf16x8 bw[2][4];
#pragma unroll
    for (int nt = 0; nt < 4; ++nt) bw[0][nt] = *(const bf16x8*)(base + nt * 512);
    for (int ks = 0; ks < 8; ++ks) {
      const int cur = ks & 1;
      if (ks < 7) {
#pragma unroll
        for (int nt = 0; nt < 4; ++nt)
          bw[cur ^ 1][nt] = *(const bf16x8*)(base + (ks + 1) * 2048 + nt * 512);
      }
      bf16x8 a = *(const bf16x8*)(&hlnt[mrow][ks * 32 + koff]);
#pragma unroll
      for (int nt = 0; nt < 4; ++nt) acc[nt] = MFMA_B16(a, bw[cur][nt], acc[nt]);
    }
    if (quad < 2) {
#pragma unroll
      for (int nt = 0; nt < 4; ++nt) {
        int col = w * 64 + nt * 16 + l16;
        float bb = bq[col];
#pragma unroll
        for (int r = 0; r < 4; ++r)
          qt[quad * 4 + r][col] = (bf16)(acc[nt][r] + bb);
      }
    }
  }
  __syncthreads();

  // bkq[b,h] = bk_h . q_h
  {
    const int pair = tid >> 2;
    const int row = pair >> 2, h = pair & 3, sub = tid & 3;
    if (row < 8) {
      float p = 0.f;
#pragma unroll
      for (int j = 0; j < 16; ++j) {
        int e = sub * 16 + j;
        p += (float)qt[row][h * 64 + e] * bk[h * 64 + e];
      }
      p += __shfl_xor(p, 1, 64);
      p += __shfl_xor(p, 2, 64);
      if (sub == 0) bkq_out[(size_t)(b0 + row) * 4 + h] = p;
    }
  }

  // kq per head
  for (int h = 0; h < 4; ++h) {
    f32x4 acc[4];
#pragma unroll
    for (int nt = 0; nt < 4; ++nt) { f32x4 z = {0.f, 0.f, 0.f, 0.f}; acc[nt] = z; }
    const bf16* base = Wk_p + (size_t)w * 8 * 2048 + lane * 8;
#pragma unroll
    for (int ks = 0; ks < 2; ++ks) {
      bf16x8 a = *(const bf16x8*)(&qt[mrow][h * 64 + ks * 32 + koff]);
#pragma unroll
      for (int nt = 0; nt < 4; ++nt) {
        bf16x8 bw = *(const bf16x8*)(base + (h * 2 + ks) * 2048 + nt * 512);
        acc[nt] = MFMA_B16(a, bw, acc[nt]);
      }
    }
    if (quad < 2) {
#pragma unroll
      for (int nt = 0; nt < 4; ++nt)
#pragma unroll
        for (int r = 0; r < 4; ++r)
          kq_out[(size_t)(b0 + quad * 4 + r) * 1024 + h * 256 + w * 64 + nt * 16 + l16] =
              (bf16)acc[nt][r];
    }
  }
}

// ---------------------------------------------------------------------------
// fused: per-batch chain s..c. grid 4096 x 256 thr, 4 blocks/CU.
// ---------------------------------------------------------------------------
__launch_bounds__(256, 4)
__global__ void fused_kernel(
    const float* __restrict__ x_stat, const float* __restrict__ b_stat,
    const float* __restrict__ g_nstat, const float* __restrict__ b_nstat,
    const float* __restrict__ bv, const float* __restrict__ g_mlp,
    const float* __restrict__ b_mlp, const float* __restrict__ b1,
    const float* __restrict__ bo, const float* __restrict__ res_scale_p,
    const float* __restrict__ h0g, const float* __restrict__ bkq_g,
    const float* __restrict__ b2o_g,
    const bf16* __restrict__ Wstat_p, const bf16* __restrict__ Wv_p,
    const bf16* __restrict__ W1_p, const bf16* __restrict__ W2o_p,
    const bf16* __restrict__ kq_g,
    float* __restrict__ out_c, float* __restrict__ out_wm) {

  __shared__ bf16 buf[64 * SROW];       // 33792 B; first 64*72 doubles as xs
  __shared__ float part_s[4][64];
  __shared__ float part_ss[4][64];
  __shared__ float watt[4][64];
  __shared__ float swh[4];

  const int b = blockIdx.x;
  const int tid = threadIdx.x;
  const int w = tid >> 6, lane = tid & 63, quad = lane >> 4, l16 = lane & 15;
  const int koff = quad * 8;

  // ---- P0: stage x fp32 -> bf16 LDS (alias over buf), fully coalesced ----
  bf16* xs = buf;
  {
    const float* xb = x_stat + (size_t)b * 4096;
#pragma unroll
    for (int j = 0; j < 4; ++j) {
      int idx = j * 1024 + tid * 4;
      float4 v = *(const float4*)(xb + idx);
      bf16x4 o;
      o[0] = (bf16)v.x; o[1] = (bf16)v.y; o[2] = (bf16)v.z; o[3] = (bf16)v.w;
      *(bf16x4*)(xs + (idx >> 6) * XROW + (idx & 63)) = o;
    }
  }
  __syncthreads();

  // ---- P1: s = x @ W_stat + b_stat (swapped; K=64) + fused LN(g_nstat) ----
  {
    f32x4 acc[4][4];
    zero_acc(acc);
    const bf16* wsb = Wstat_p + (size_t)w * 2 * 2048 + lane * 8;
    bf16x8 aw[2][4];
#pragma unroll
    for (int ks = 0; ks < 2; ++ks)
#pragma unroll
      for (int dt = 0; dt < 4; ++dt)
        aw[ks][dt] = *(const bf16x8*)(wsb + ks * 2048 + dt * 512);
#pragma unroll
    for (int ks = 0; ks < 2; ++ks)
#pragma unroll
      for (int tt = 0; tt < 4; ++tt) {
        bf16x8 bfrag = *(const bf16x8*)(xs + (tt * 16 + l16) * XROW + ks * 32 + koff);
#pragma unroll
        for (int dt = 0; dt < 4; ++dt) acc[dt][tt] = MFMA_B16(aw[ks][dt], bfrag, acc[dt][tt]);
      }
    bias_stats(acc, b_stat, w, quad, l16, part_s, part_ss);
    __syncthreads();  // xs reads done + partials visible
    ln_apply_store(acc, g_nstat, b_nstat, buf, part_s, part_ss, w, quad, l16);
  }
  __syncthreads();

  // ---- P3a: logits via kq (wave w -> tokens 16w..; head = l16 < 4) ----
  {
    const bf16* kq_b = kq_g + (size_t)b * 1024;
    f32x4 accL = {0.f, 0.f, 0.f, 0.f};
#pragma unroll
    for (int ks = 0; ks < 8; ++ks) {
      bf16x8 a = *(const bf16x8*)(buf + (w * 16 + l16) * SROW + ks * 32 + koff);
      bf16x8 kf = zero8();
      if (l16 < 4) kf = *(const bf16x8*)(kq_b + l16 * 256 + ks * 32 + koff);
      accL = MFMA_B16(a, kf, accL);
    }
    float bkqv = (l16 < 4) ? bkq_g[(size_t)b * 4 + l16] : 0.f;
#pragma unroll
    for (int r = 0; r < 4; ++r) {
      float lg = (accL[r] + bkqv) * 0.125f;
      float sig = RCP(1.f + __expf(-lg));
      if (l16 < 4) watt[l16][w * 16 + quad * 4 + r] = sig;  // un-normalized
    }
  }

  // ---- P3b: v = s_ln @ Wv + bv (swapped) + fused LN(g_mlp), in-place ----
  {
    f32x4 acc[4][4];
    zero_acc(acc);
    gemm_swapped_p(buf, Wv_p, w, lane, l16, koff, acc);
    bias_stats(acc, bv, w, quad, l16, part_s, part_ss);
    __syncthreads();  // all s reads done; partials + watt(sig) visible
    {
      float v = watt[w][lane];
      float den = wave_sum(v);
      float dinv = RCP(den + 1e-6f);
      watt[w][lane] = v * dinv;
      if (lane == 0) swh[w] = den * dinv;
    }
    ln_apply_store(acc, g_mlp, b_mlp, buf, part_s, part_ss, w, quad, l16);
  }
  __syncthreads();

  // ---- w_mean output (normalized watt visible after barrier) ----
  if (tid < 64)
    out_wm[(size_t)b * 64 + tid] =
        0.25f * ((watt[0][tid] + watt[1][tid]) + (watt[2][tid] + watt[3][tid]));

  // ---- P5: t1 = gelu(t_ln@W1 + b1) (swapped), in-place ----
  {
    f32x4 acc[4][4];
    zero_acc(acc);
    gemm_swapped_p(buf, W1_p, w, lane, l16, koff, acc);
    __syncthreads();  // all t_ln reads done before overwrite
#pragma unroll
    for (int dt = 0; dt < 4; ++dt) {
      const float4 bb = *(const float4*)(b1 + w * 64 + dt * 16 + quad * 4);
#pragma unroll
      for (int tt = 0; tt < 4; ++tt) {
        float v0 = acc[dt][tt][0] + bb.x;
        float v1 = acc[dt][tt][1] + bb.y;
        float v2 = acc[dt][tt][2] + bb.z;
        float v3 = acc[dt][tt][3] + bb.w;
        bf16x4 o;
        o[0] = (bf16)(v0 * RCP(1.f + __expf(-1.702f * v0)));
        o[1] = (bf16)(v1 * RCP(1.f + __expf(-1.702f * v1)));
        o[2] = (bf16)(v2 * RCP(1.f + __expf(-1.702f * v2)));
        o[3] = (bf16)(v3 * RCP(1.f + __expf(-1.702f * v3)));
        *(bf16x4*)(buf + (tt * 16 + l16) * SROW + w * 64 + dt * 16 + quad * 4) = o;
      }
    }
  }
  __syncthreads();

  // ---- P6: t1 @ W2o (orig); z = watt . rows; c written ----
  {
    f32x4 acc[4][4];
    zero_acc(acc);
    gemm_orig_p(buf, W2o_p, w, lane, l16, koff, acc);
    float zacc[4] = {0.f, 0.f, 0.f, 0.f};
#pragma unroll
    for (int mt = 0; mt < 4; ++mt)
#pragma unroll
      for (int r = 0; r < 4; ++r) {
        float wt = watt[w][mt * 16 + quad * 4 + r];
#pragma unroll
        for (int nt = 0; nt < 4; ++nt) zacc[nt] += wt * acc[mt][nt][r];
      }
#pragma unroll
    for (int nt = 0; nt < 4; ++nt) {
      zacc[nt] += __shfl_xor(zacc[nt], 16, 64);
      zacc[nt] += __shfl_xor(zacc[nt], 32, 64);
    }
    if (quad == 0) {
      float rs = *res_scale_p;
#pragma unroll
      for (int nt = 0; nt < 4; ++nt) {
        int col = w * 64 + nt * 16 + l16;
        float res = zacc[nt] + swh[w] * b2o_g[col] + bo[col];
        out_c[(size_t)b * 256 + col] = h0g[(size_t)b * 256 + col] + rs * res;
      }
    }
  }
}

extern "C" void kernel_launch(void* const* d_in, const int* in_sizes, int n_in,
                              void* d_out, int out_size, void* d_ws, size_t ws_size,
                              hipStream_t stream) {
  const float* h_dyn   = (const float*)d_in[0];
  const float* x_stat  = (const float*)d_in[1];
  const float* W_dyn   = (const float*)d_in[2];
  const float* b_dyn   = (const float*)d_in[3];
  const float* W_stat  = (const float*)d_in[4];
  const float* b_stat  = (const float*)d_in[5];
  const float* g_ndyn  = (const float*)d_in[6];
  const float* b_ndyn  = (const float*)d_in[7];
  const float* g_nstat = (const float*)d_in[8];
  const float* b_nstat = (const float*)d_in[9];
  const float* Wq = (const float*)d_in[10];
  const float* bq = (const float*)d_in[11];
  const float* Wk = (const float*)d_in[12];
  const float* bk = (const float*)d_in[13];
  const float* Wv = (const float*)d_in[14];
  const float* bv = (const float*)d_in[15];
  const float* g_mlp = (const float*)d_in[16];
  const float* b_mlp = (const float*)d_in[17];
  const float* W1 = (const float*)d_in[18];
  const float* b1 = (const float*)d_in[19];
  const float* W2 = (const float*)d_in[20];
  const float* b2 = (const float*)d_in[21];
  const float* Wo = (const float*)d_in[22];
  const float* bo = (const float*)d_in[23];
  const float* rs = (const float*)d_in[24];

  bf16* ws = (bf16*)d_ws;
  float* wsf = (float*)d_ws;

  prep1_kernel<<<232, 256, 0, stream>>>(W_dyn, W_stat, Wq, Wk, Wv, W1, W2, Wo, b2, ws, wsf);
  prep2_kernel<<<32, 256, 0, stream>>>(wsf + W2OS_F, ws);

  pre_kernel<<<512, 256, 0, stream>>>(h_dyn, b_dyn, g_ndyn, b_ndyn, bq, bk,
                                      ws + WDYN_P, ws + WQ_P, ws + WK_P,
                                      wsf + H0_F, ws + KQ_BF, wsf + BKQ_F);

  float* out_c = (float*)d_out;
  float* out_wm = out_c + (size_t)4096 * 256;
  fused_kernel<<<4096, 256, 0, stream>>>(
      x_stat, b_stat, g_nstat, b_nstat, bv, g_mlp, b_mlp, b1, bo, rs,
      wsf + H0_F, wsf + BKQ_F, wsf + B2O_F,
      ws + WSTAT_P, ws + WV_P, ws + W1_P, ws + W2O_P, ws + KQ_BF,
      out_c, out_wm);
}